// Round 5
// baseline (364.574 us; speedup 1.0000x reference)
//
#include <hip/hip_runtime.h>
#include <stdint.h>
#include <math.h>

typedef unsigned long long u64;
typedef unsigned int u32;
typedef unsigned short u16;

// ---- problem constants ----
#define C_P 32
#define C_S 16
#define C_D 64
#define C_N 2048

// ---- ws layout (offsets in doubles) ----
#define R_OFF      0        // float[4096]
#define CTAB_OFF   4160     // double[64]
#define KEYS_OFF   4224     // u32[4]
#define PROBS_OFF  4232     // float[131072]
#define GROW_OFF   135304   // u64[32768] row masks
#define GCOL_OFF   168072   // u64[32768] col masks
#define NS_OFF     200840   // double[32768]; later grow2 u64[2048]
#define W_OFF      233608   // double[512]
#define GF_OFF     234120   // float[262144]; chol-phase: tier worklists (u32)
#define KM_OFF     365192   // float[1024]
#define ZN_OFF     365704   // float[262144]
#define NS2_OFF    496776   // double[2048]

// worklist layout (u32 indices into GF region):
//   wl[0..4] = counts tier0(m<=29)/1(<=32)/2(<=35)/3(<=40)/heavy(>40)
//   wl[16 + tier*32768 + i] = task ids   (5*32768+16 u32 < 262144 u32 budget)
#define WL_LIST0 16

// merged chol kernel block ranges
#define TB0 1792
#define TB1 2304
#define TB2 2176
#define TB3 1728
#define HBLK 384
#define S1 (TB0)
#define S2 (TB0+TB1)
#define S3 (TB0+TB1+TB2)
#define SH (TB0+TB1+TB2+TB3)
#define NBLK_ALL (SH+HBLK)

// ---- out layout (FLOAT32 elements) ----
#define O_REC   0
#define O_LOGP  4096
#define O_QZ    4128
#define O_QMU   6176
#define O_QLV   8224
#define O_GH    10272
#define O_ZN    141344
#define O_TOTAL 403488

__device__ __forceinline__ void tf2x32(u32 k0, u32 k1, u32 x0, u32 x1,
                                       u32& o0, u32& o1) {
  u32 ks2 = k0 ^ k1 ^ 0x1BD11BDAu;
  x0 += k0; x1 += k1;
#define TFR(r) { x0 += x1; x1 = (x1 << r) | (x1 >> (32 - r)); x1 ^= x0; }
  TFR(13) TFR(15) TFR(26) TFR(6)   x0 += k1;  x1 += ks2 + 1u;
  TFR(17) TFR(29) TFR(16) TFR(24)  x0 += ks2; x1 += k0 + 2u;
  TFR(13) TFR(15) TFR(26) TFR(6)   x0 += k0;  x1 += k1 + 3u;
  TFR(17) TFR(29) TFR(16) TFR(24)  x0 += k1;  x1 += ks2 + 4u;
  TFR(13) TFR(15) TFR(26) TFR(6)   x0 += ks2; x1 += k0 + 5u;
#undef TFR
  o0 = x0; o1 = x1;
}

__device__ __forceinline__ double d_erfinv(double x) {
  double w = -log1p(-x * x);
  double p;
  if (w < 5.0) {
    w -= 2.5;
    p = 2.81022636e-08;
    p = 3.43273939e-07  + p * w;
    p = -3.5233877e-06  + p * w;
    p = -4.39150654e-06 + p * w;
    p = 0.00021858087   + p * w;
    p = -0.00125372503  + p * w;
    p = -0.00417768164  + p * w;
    p = 0.246640727     + p * w;
    p = 1.50140941      + p * w;
  } else {
    w = sqrt(w) - 3.0;
    p = -0.000200214257;
    p = 0.000100950558  + p * w;
    p = 0.00134934322   + p * w;
    p = -0.00367342844  + p * w;
    p = 0.00573950773   + p * w;
    p = -0.0076224613   + p * w;
    p = 0.00943887047   + p * w;
    p = 1.00167406      + p * w;
    p = 2.83297682      + p * w;
  }
  return p * x;
}

// Stirling lgamma for large z (z ~ 1026: abs err ~1e-12, plenty for f32 out)
__device__ __forceinline__ double stirl(double z) {
  double zi = 1.0 / z;
  double zi2 = zi * zi;
  double s = (z - 0.5) * log(z) - z + 0.9189385332046727;  // 0.5*ln(2*pi)
  s += zi * (1.0 / 12.0 - zi2 * (1.0 / 360.0 - zi2 * (1.0 / 1260.0)));
  return s;
}

// R (with fused setup on block 0): one pass Sx/Sxx, combine analytically.
// ctab via recurrence ctab[l] = ctab[l-2] + log((2049+l)/(4(1+l))):
// per-lane log + parity prefix scan + 2 Stirling seeds replaces 128 serial
// f64 softfloat lgamma calls (round-4 theory: that single wave was ~all of
// k_R's wall time).
__global__ void k_R(const float* x, double* ws, const int* seedp) {
  __shared__ double pS[8][64], pX[8][64];
  __shared__ double xbar[64];
  int j = blockIdx.x, t = threadIdx.x;   // 512 threads
  int i = t & 63, c = t >> 6;
  if (j == 0) {                          // fused k_setup
    if (t < 64) {
      int l = t;
      double term = (l >= 2) ? log((2049.0 + (double)l) / (4.0 * (1.0 + (double)l)))
                             : 0.0;
      double v = term;
#pragma unroll
      for (int off = 2; off <= 32; off <<= 1) {
        double o = __shfl_up(v, off, 64);
        if (l >= off) v += o;
      }
      const double LOG_HALF = -0.6931471805599453;
      double c0 = -0.5 * log(2049.0)
                - 1024.0 * log(3.14159265358979323846);
      double seed = (l & 1)
        ? c0 + stirl(1026.0) + 2.5 * LOG_HALF                       // -lgamma(2)=0
        : c0 + stirl(1025.5) + 0.12078223763524522235 + 1.5 * LOG_HALF; // -lgamma(1.5)
      ws[CTAB_OFF + l] = seed + v;
    }
    if (t < 8) ((u32*)(ws + GF_OFF))[t] = 0;   // zero worklist counters
    if (t == 0) {
      u32 kk0 = 0u, kk1 = (u32)seedp[0];
      u32 a0, a1, s0, s1, r0, r1, d0, d1;
      tf2x32(kk0, kk1, 0u, 0u, a0, a1);
      tf2x32(kk0, kk1, 0u, 1u, s0, s1);   // sk (bernoulli)
      tf2x32(a0, a1, 0u, 0u, d0, d1); (void)d0; (void)d1;
      tf2x32(a0, a1, 0u, 1u, r0, r1);     // rk (normal eps)
      u32* keys = (u32*)(ws + KEYS_OFF);
      keys[0] = s0; keys[1] = s1; keys[2] = r0; keys[3] = r1;
    }
  }
  double sx = 0.0, sxx = 0.0;
  for (int n = c * 256; n < (c + 1) * 256; n++) {
    double xi = (double)x[n * 64 + i];
    double xj = (double)x[n * 64 + j];
    sx += xi; sxx += xi * xj;
  }
  pS[c][i] = sx; pX[c][i] = sxx;
  __syncthreads();
  if (t < 64) {
    double S = 0.0, X = 0.0;
    for (int cc = 0; cc < 8; cc++) { S += pS[cc][i]; X += pX[cc][i]; }
    xbar[i] = S / 2048.0;
    pX[0][i] = X;
  }
  __syncthreads();
  if (t < 64) {
    double xbi = xbar[i], xbj = xbar[j];
    double s = pX[0][i] - 2048.0 * xbi * xbj + (2048.0 / 2049.0) * xbi * xbj;
    if (i == j) s += 0.5;
    ((float*)(ws + R_OFF))[i * 64 + j] = (float)s;
  }
}

// probs[p,i,j] = sigmoid(alpha * u_i . v_j) * (i!=j), stored f32
__global__ __launch_bounds__(64) void k_probs(const float* z, double* ws) {
  float* probs = (float*)(ws + PROBS_OFF);
  int b = blockIdx.x; int p = b >> 6, i = b & 63;
  int j = threadIdx.x;
  __shared__ float V[64 * 65];
  __shared__ float us[64];
  int k = j;
  us[k] = z[((p * 64 + i) * 64 + k) * 2 + 0];
  for (int jj = 0; jj < 64; jj++)
    V[jj * 65 + k] = z[((p * 64 + jj) * 64 + k) * 2 + 1];
  __syncthreads();
  float s = 0.f;
  for (int kk = 0; kk < 64; kk++)
    s += us[kk] * V[j * 65 + kk];
  float pr = (i == j) ? 0.f : 1.f / (1.f + expf(-0.2f * s));
  probs[(p * 64 + i) * 64 + j] = pr;
}

// sample graphs AND bucket tasks into the 5 chol tiers (wave-aggregated
// atomics: one atomicAdd per wave per tier).
__global__ void k_sample(double* ws) {
  const float* probs = (const float*)(ws + PROBS_OFF);
  const u32* keys = (const u32*)(ws + KEYS_OFF);
  u64* grow = (u64*)(ws + GROW_OFF);
  u64* gcol = (u64*)(ws + GCOL_OFF);
  u32* wl = (u32*)(ws + GF_OFF);
  int ps = blockIdx.x;
  int p = ps >> 4;
  int j = threadIdx.x;
  u32 k0 = keys[0], k1 = keys[1];
  u64 colmask = 0;
  for (int i = 0; i < 64; i++) {
    u32 lin = (u32)(ps * 4096 + i * 64 + j);
    u32 o0, o1; tf2x32(k0, k1, 0u, lin, o0, o1);
    u32 bits = o0 ^ o1;
    float f = __uint_as_float((bits >> 9) | 0x3f800000u) - 1.0f;
    bool bit = (f < probs[(p * 64 + i) * 64 + j]);
    u64 rm = __ballot(bit);
    if (j == 0) grow[ps * 64 + i] = rm;
    if (bit) colmask |= (1ull << i);
  }
  gcol[ps * 64 + j] = colmask;
  // tier bucketing: task (ps, col j), m = popc+1
  int m = (int)__popcll(colmask) + 1;
  int tier = (m <= 29) ? 0 : (m <= 32) ? 1 : (m <= 35) ? 2 : (m <= 40) ? 3 : 4;
#pragma unroll
  for (int t = 0; t < 5; t++) {
    u64 b = __ballot(tier == t);
    if (tier == t) {
      int leader = (int)__builtin_ctzll(b);
      u32 off = (u32)__popcll(b & ((1ull << j) - 1ull));
      u32 base = 0;
      if (j == leader) base = atomicAdd(&wl[t], (u32)__popcll(b));
      base = (u32)__shfl((int)base, leader, 64);
      wl[WL_LIST0 + t * 32768 + base + off] = (u32)(ps * 64 + j);
    }
  }
}

__device__ __forceinline__ float rdlane(float x, int l) {
  return __uint_as_float(__builtin_amdgcn_readlane(__float_as_uint(x), (u32)l));
}

// Per-wave register LDL for one tier. Direct global loads via R symmetry;
// f32 __logf epilogue (sampled-graph scores only feed softmax weights).
// All LDS traffic intra-wave -> wave_barrier only; grid-strides its tier list.
template<int MMAX>
__device__ __forceinline__ void tier_body(const float* Rf, const double* ctab,
                                          const u64* masks, double* nodescore,
                                          const u32* wl, int tier,
                                          u32 brel, u32 nb, int (*idx)[64]) {
  int w = threadIdx.x >> 6;
  int lane = threadIdx.x & 63;
  u32 cnt = wl[tier];
  const u32* list = wl + WL_LIST0 + tier * 32768;
  for (u32 ti = brel * 4 + (u32)w; ti < cnt; ti += nb * 4) {
    int task = (int)list[ti];
    int j = task & 63;
    u64 mask = masks[task];
    int P = (int)__popcll(mask);
    int m = P + 1;
    idx[w][lane] = 0;                       // sanitize (dead slots -> row 0)
    __builtin_amdgcn_wave_barrier();
    u64 below = mask & ((1ull << lane) - 1ull);
    if ((mask >> lane) & 1ull) idx[w][(int)__popcll(below)] = lane;
    if (lane == 0) idx[w][P] = j;
    __builtin_amdgcn_wave_barrier();
    int myrow = idx[w][lane];               // my node id (0 for dead lanes)
    float v[MMAX];
#pragma unroll
    for (int c = 0; c < MMAX; c++)
      v[c] = Rf[idx[w][c] * 64 + myrow];    // A[lane][c] via symmetry
    float mypiv = 1.0f;
#pragma unroll
    for (int k = 0; k < MMAX; k++) {
      if (k < m) {                          // uniform guard (keeps full unroll)
        float dk = rdlane(v[k], k);
        if (lane == k) mypiv = dk;
        float ns = -v[k] * __builtin_amdgcn_rcpf(dk);
#pragma unroll
        for (int b = k + 1; b < MMAX; b++)
          v[b] += ns * rdlane(v[k], b);     // garbage slots never read back
      }
    }
    float lastd = __shfl(mypiv, P, 64);     // final pivot d_{m-1} (lane P)
    float lv = (lane < m) ? __logf(mypiv) : 0.f;
    for (int off = 32; off > 0; off >>= 1) lv += __shfl_down(lv, off, 64);
    if (lane == 0) {
      double l = (double)P;
      nodescore[task] = ctab[P]
                      - 0.5 * (2050.0 + l) * (double)__logf(lastd)
                      - 0.5 * (double)lv;
    }
    __builtin_amdgcn_wave_barrier();        // order idx reuse across iterations
  }
}

#define WB() __builtin_amdgcn_wave_barrier()

// Heavy path (m>40, ~1%): wave 0 of the block only; full hybrid path with
// LDS triangle. Single-wave semantics -> wave_barrier suffices (in-order
// per-wave LDS ops; compiler inserts lgkmcnt waits).
__device__ void heavy_body(const float* Rf, const double* ctab,
                           const u64* masks, double* nodescore,
                           const u32* wl, u32 brel, u32 nb,
                           float* T, int* idx) {
  if (threadIdx.x >= 64) return;
  int lane = threadIdx.x;
  u32 cnt = wl[4];
  const u32* list = wl + WL_LIST0 + 4 * 32768;
  for (u32 ii = brel; ii < cnt; ii += nb) {
    WB();
    int task = (int)list[ii];
    int j = task & 63;
    u64 mask = masks[task];
    int P = (int)__popcll(mask);
    int m = P + 1;
    u64 below = mask & ((1ull << lane) - 1ull);
    if ((mask >> lane) & 1ull) idx[(int)__popcll(below)] = lane;
    if (lane == 0) idx[P] = j;
    WB();
    int trLane = (lane * (lane + 1)) >> 1;
    if (lane < m) {
      int cidx = idx[lane];
      int tr = 0;
      for (int r = 0; r < m; r++) {
        if (lane <= r) T[tr + lane] = Rf[idx[r] * 64 + cidx];
        tr += r + 1;
      }
    }
    WB();
    float mypiv = 1.0f, lastd = 1.0f;
    float v[40];
#pragma unroll
    for (int c = 0; c < 40; c++)
      v[c] = T[trLane + c];
#pragma unroll
    for (int k = 0; k < 40; k++) {
      if (k < m) {
        float dk = rdlane(v[k], k);
        if (lane == k) mypiv = dk;
        lastd = dk;
        float ns = -v[k] * __builtin_amdgcn_rcpf(dk);
#pragma unroll
        for (int b = k + 1; b < 40; b++)
          v[b] += ns * rdlane(v[k], b);
      }
    }
    if (m > 40) {
      for (int b = 40; b < m; b++) {
        float acc = 0.f;
#pragma unroll
        for (int k = 0; k < 40; k++) {
          float dk = rdlane(v[k], k);
          float abk = rdlane(v[k], b);
          acc += v[k] * abk * __builtin_amdgcn_rcpf(dk);
        }
        if (lane >= b) T[trLane + b] -= acc;
      }
      WB();
      for (int k = 40; k < m; k++) {
        float dk = T[((k * (k + 1)) >> 1) + k];
        if (lane == k) mypiv = dk;
        lastd = dk;
        float sk = T[trLane + k] * __builtin_amdgcn_rcpf(dk);
        for (int b = k + 1; b < m; b++) {
          float abk = T[((b * (b + 1)) >> 1) + k];
          if (lane >= b) T[trLane + b] -= sk * abk;
        }
        WB();
      }
    }
    double vv = (lane < m) ? log((double)mypiv) : 0.0;
    for (int off = 32; off > 0; off >>= 1) vv += __shfl_down(vv, off, 64);
    if (lane == 0) {
      double logB = vv;
      double logA = logB - log((double)lastd);
      double l = (double)P;
      nodescore[task] = ctab[P]
                      + 0.5 * (2050.0 + l) * logA
                      - 0.5 * (2051.0 + l) * logB;
    }
  }
}

// ONE launch for all 32768 sampled-graph cholesky tasks: 4 light tiers
// (29/32/35/40) + heavy, dispatched by block range. Merging removes 2
// launch gaps and lets tier tails overlap across CUs. No min-waves
// launch_bounds cap (round-1 lesson: caps + big v[] => scratch spill).
__global__ __launch_bounds__(256) void k_chol_all(const float* Rf, const double* ctab,
                                                  const u64* masks, double* nodescore,
                                                  const u32* wl) {
  __shared__ int idx4[4][64];
  __shared__ float T[2080];
  __shared__ int idxh[64];
  u32 b = blockIdx.x;
  if (b < TB0)     tier_body<29>(Rf, ctab, masks, nodescore, wl, 0, b,      TB0, idx4);
  else if (b < S2) tier_body<32>(Rf, ctab, masks, nodescore, wl, 1, b - S1, TB1, idx4);
  else if (b < S3) tier_body<35>(Rf, ctab, masks, nodescore, wl, 2, b - S2, TB2, idx4);
  else if (b < SH) tier_body<40>(Rf, ctab, masks, nodescore, wl, 3, b - S3, TB3, idx4);
  else             heavy_body(Rf, ctab, masks, nodescore, wl, b - SH, HBLK, T, idxh);
}

// Merged hybrid f32 LDL Cholesky (transpose variant for the 2048 hard-graph
// tasks). UNCHANGED and kept f64: its scores feed the log_p OUTPUT, where
// absmax is already at 1 f32 ulp of |logp|~4000.
template<bool TRANSPOSE>
__global__ __launch_bounds__(64) void k_chol(const float* Rf, const double* ctab,
                                             const u64* masks, double* nodescore) {
  __shared__ float T[2080];
  __shared__ int idx[64];
  int task = blockIdx.x;
  int j = task & 63;
  int lane = threadIdx.x;
  u64 mask;
  if (TRANSPOSE) {
    int p = task >> 6;
    u64 rm = masks[p * 64 + lane];       // row mask of row `lane`
    mask = __ballot((rm >> j) & 1ull);   // column j mask
  } else {
    mask = masks[task];
  }
  int P = (int)__popcll(mask);
  int m = P + 1;
  u64 below = mask & ((1ull << lane) - 1ull);
  if ((mask >> lane) & 1ull) idx[(int)__popcll(below)] = lane;
  if (lane == 0) idx[P] = j;
  __syncthreads();
  int trLane = (lane * (lane + 1)) >> 1;
  if (lane < m) {
    int cidx = idx[lane];
    int tr = 0;
    for (int r = 0; r < m; r++) {
      if (lane <= r) T[tr + lane] = Rf[idx[r] * 64 + cidx];
      tr += r + 1;
    }
  }
  __syncthreads();
  float mypiv = 1.0f, lastd = 1.0f;
  float v[40];
#pragma unroll
  for (int c = 0; c < 40; c++)
    v[c] = T[trLane + c];                // in-bounds garbage for c>lane
#pragma unroll
  for (int k = 0; k < 40; k++) {
    if (k < m) {                         // uniform guard (keeps full unroll)
      float dk = rdlane(v[k], k);
      if (lane == k) mypiv = dk;
      lastd = dk;
      float ns = -v[k] * __builtin_amdgcn_rcpf(dk);
#pragma unroll
      for (int b = k + 1; b < 40; b++)
        v[b] += ns * rdlane(v[k], b);    // garbage slots harmless
    }
  }
  if (m > 40) {                          // heavy tasks only (block-uniform)
    for (int b = 40; b < m; b++) {
      float acc = 0.f;
#pragma unroll
      for (int k = 0; k < 40; k++) {
        float dk = rdlane(v[k], k);                  // final pivot k
        float abk = rdlane(v[k], b);                 // final A[b][k]
        acc += v[k] * abk * __builtin_amdgcn_rcpf(dk);
      }
      if (lane >= b) T[trLane + b] -= acc;           // own-row, no conflict
    }
    __syncthreads();
    for (int k = 40; k < m; k++) {
      float dk = T[((k * (k + 1)) >> 1) + k];        // broadcast
      if (lane == k) mypiv = dk;
      lastd = dk;
      float sk = T[trLane + k] * __builtin_amdgcn_rcpf(dk);
      for (int b = k + 1; b < m; b++) {
        float abk = T[((b * (b + 1)) >> 1) + k];     // broadcast
        if (lane >= b) T[trLane + b] -= sk * abk;
      }
      __syncthreads();
    }
  }
  double vv = (lane < m) ? log((double)mypiv) : 0.0;
  for (int off = 32; off > 0; off >>= 1) vv += __shfl_down(vv, off, 64);
  if (lane == 0) {
    double logB = vv;
    double logA = logB - log((double)lastd);
    double l = (double)P;
    nodescore[task] = ctab[P]
                    + 0.5 * (2050.0 + l) * logA
                    - 0.5 * (2051.0 + l) * logB;
  }
}

__global__ void k_logpw(const double* ns, double* w) {
  int p = blockIdx.x, t = threadIdx.x;
  __shared__ double part[64];
  int s = t & 15, c = t >> 4;            // 4 chunks x 16 samples
  double acc = 0.0;
  for (int j = c * 16; j < (c + 1) * 16; j++)
    acc += ns[(p * 16 + s) * 64 + j];
  part[t] = acc;
  __syncthreads();
  if (t < 16) part[t] = part[t] + part[t + 16] + part[t + 32] + part[t + 48];
  __syncthreads();
  if (t == 0) {
    double m = part[0];
    for (int s2 = 1; s2 < 16; s2++) m = fmax(m, part[s2]);
    double e[16], sum = 0.0;
    for (int s2 = 0; s2 < 16; s2++) { e[s2] = exp(part[s2] - m); sum += e[s2]; }
    for (int s2 = 0; s2 < 16; s2++) w[p * 16 + s2] = e[s2] / sum;
  }
}

// fused A-construction + grad dot + kmat.
// blocks 0..2047: grad_u; 2048..4095: grad_v; 4096..5119: Kmat (z0-only).
__global__ void k_grad(double* ws, const float* z) {
  const float* probs = (const float*)(ws + PROBS_OFF);
  const double* w = ws + W_OFF;
  const u64* grow = (const u64*)(ws + GROW_OFF);
  const u64* gcol = (const u64*)(ws + GCOL_OFF);
  float* gf = (float*)(ws + GF_OFF);
  const float LOGIT = -2.6903717578966254f;  // log(4/63)-log1p(-4/63)
  int bb = blockIdx.x;
  int k = threadIdx.x;
  __shared__ float acc[64];
  if (bb < 2048) {
    int p = bb >> 6, i = bb & 63;
    float gb = 0.f, wsum = 0.f;
    for (int s = 0; s < 16; s++) {
      float wv = (float)w[p * 16 + s];
      wsum += wv;
      gb += wv * (float)((grow[(p * 16 + s) * 64 + i] >> k) & 1ull);
    }
    float pr = probs[(p * 64 + i) * 64 + k];   // coalesced
    float od = (i == k) ? 0.f : 1.f;
    acc[k] = (0.2f * (gb - pr * wsum) + 0.2f * pr * (1.f - pr) * LOGIT) * od;
    __syncthreads();
    float s = 0.f;
    for (int j = 0; j < 64; j++)
      s += acc[j] * z[((p * 64 + j) * 64 + k) * 2 + 1];
    s -= 64.f * z[((p * 64 + i) * 64 + k) * 2 + 0];
    gf[p * 8192 + (i * 64 + k) * 2 + 0] = s;
  } else if (bb < 4096) {
    int b = bb - 2048;
    int p = b >> 6, j = b & 63;
    float gb = 0.f, wsum = 0.f;
    for (int s = 0; s < 16; s++) {
      float wv = (float)w[p * 16 + s];
      wsum += wv;
      gb += wv * (float)((gcol[(p * 16 + s) * 64 + j] >> k) & 1ull);
    }
    float pr = probs[(p * 64 + k) * 64 + j];   // one 64-lane gather
    float od = (k == j) ? 0.f : 1.f;
    acc[k] = (0.2f * (gb - pr * wsum) + 0.2f * pr * (1.f - pr) * LOGIT) * od;
    __syncthreads();
    float s = 0.f;
    for (int i = 0; i < 64; i++)
      s += acc[i] * z[((p * 64 + i) * 64 + k) * 2 + 0];
    s -= 64.f * z[((p * 64 + j) * 64 + k) * 2 + 1];
    gf[p * 8192 + (j * 64 + k) * 2 + 1] = s;
  } else {
    float* Km = (float*)(ws + KM_OFF);
    int b = bb - 4096;
    int a = b >> 5, b2 = b & 31;
    float accf = 0.f;
    for (int d0 = k; d0 < 8192; d0 += 64) {
      float diff = z[a * 8192 + d0] - z[b2 * 8192 + d0];
      accf += diff * diff;
    }
    for (int off = 32; off > 0; off >>= 1) accf += __shfl_down(accf, off, 64);
    if (k == 0) Km[a * 32 + b2] = expf(-accf / 5.0f);
  }
}

__global__ void k_znew(const float* z, double* ws, float* out) {
  const float* Km = (const float*)(ws + KM_OFF);
  const float* gf = (const float*)(ws + GF_OFF);
  float* zn = (float*)(ws + ZN_OFF);
  int gid = blockIdx.x * 64 + threadIdx.x;
  int p = gid >> 13, t = gid & 8191;
  float zp = z[p * 8192 + t];
  float accg = 0.f, accz = 0.f, ks = 0.f;
  for (int b = 0; b < 32; b++) {
    float kv = Km[p * 32 + b];
    accg += kv * gf[b * 8192 + t];
    accz += kv * z[b * 8192 + t];
    ks += kv;
  }
  float rep = -0.4f * (accz - zp * ks);
  float v = zp + 0.005f * ((accg + rep) / 32.f);
  zn[p * 8192 + t] = v;
  out[O_ZN + p * 8192 + t] = v;
}

__global__ __launch_bounds__(64) void k_s2col(double* ws, float* out) {
  const float* zn = (const float*)(ws + ZN_OFF);
  u64* grow2 = (u64*)(ws + NS_OFF);
  int b = blockIdx.x; int p = b >> 6, i = b & 63;
  int j = threadIdx.x;
  __shared__ float V[64 * 65];
  __shared__ float us[64];
  int k = j;
  us[k] = zn[p * 8192 + (i * 64 + k) * 2 + 0];
  for (int jj = 0; jj < 64; jj++)
    V[jj * 65 + k] = zn[p * 8192 + (jj * 64 + k) * 2 + 1];
  __syncthreads();
  float s = 0.f;
  for (int kk = 0; kk < 64; kk++)
    s += us[kk] * V[j * 65 + kk];
  bool bit = (i != j) && (s > 0.0f);
  out[O_GH + (p * 64 + i) * 64 + j] = bit ? 1.0f : 0.0f;
  u64 m = __ballot(bit);
  if (j == 0) grow2[p * 64 + i] = m;    // row masks; k_chol<true> transposes
}

// encoder/decoder MLP; also writes log_p (fused reduction).
// v4: e0 uses float4 weight loads + mask-multiply (replaces 320 scalar loads
// under divergent per-lane branches with 80 vector loads, no divergence).
__global__ __launch_bounds__(256) void k_mlp(double* ws, float* out, const double* ns2,
    const float* ew0, const float* eb0, const float* ew1, const float* eb1,
    const float* ew2, const float* eb2,
    const float* mw0, const float* mb0, const float* mw1, const float* mb1,
    const float* lw0, const float* lb0, const float* lw1, const float* lb1,
    const float* dw0, const float* db0, const float* dw1, const float* db1,
    const float* dw2, const float* db2) {
  int p = blockIdx.x, t = threadIdx.x;
  int w = t >> 6, lane = t & 63;
  const u64* grow2 = (const u64*)(ws + NS_OFF);
  const u32* keys = (const u32*)(ws + KEYS_OFF);
  __shared__ float pt[4][64];
  __shared__ float e0p[4][20];
  __shared__ float h0[20], h1[64], h2[64], hm[64], hl[64];
  __shared__ float qmu[64], qlv[64], qz[64], h3[10], h4[128];

  // ---- logp reduction (wave 0) ----
  if (w == 0) {
    double vv = ns2[p * 64 + lane];
    for (int off = 32; off > 0; off >>= 1) vv += __shfl_down(vv, off, 64);
    if (lane == 0) out[O_LOGP + p] = (float)vv;
  }

  // ---- e0: h0[20] = relu(eb0 + sum over set bits of ew0 rows) ----
  // thread t owns 16 consecutive flat inputs f = t*16+q (all in row i=t>>2).
  // rows are 20 floats = 5 aligned float4 (80B stride keeps 16B alignment).
  {
    int i = t >> 2;
    int jb = (t & 3) * 16;
    u32 m16 = (u32)((grow2[p * 64 + i] >> jb) & 0xFFFFull);
    float acc[20];
#pragma unroll
    for (int o = 0; o < 20; o++) acc[o] = 0.f;
    const float4* wb = (const float4*)(ew0 + (size_t)(t * 16) * 20);
#pragma unroll
    for (int q = 0; q < 16; q++) {
      float mq = (float)((m16 >> q) & 1u);
      float4 r0 = wb[q * 5 + 0], r1 = wb[q * 5 + 1], r2 = wb[q * 5 + 2];
      float4 r3 = wb[q * 5 + 3], r4 = wb[q * 5 + 4];
      acc[0]  += mq * r0.x; acc[1]  += mq * r0.y; acc[2]  += mq * r0.z; acc[3]  += mq * r0.w;
      acc[4]  += mq * r1.x; acc[5]  += mq * r1.y; acc[6]  += mq * r1.z; acc[7]  += mq * r1.w;
      acc[8]  += mq * r2.x; acc[9]  += mq * r2.y; acc[10] += mq * r2.z; acc[11] += mq * r2.w;
      acc[12] += mq * r3.x; acc[13] += mq * r3.y; acc[14] += mq * r3.z; acc[15] += mq * r3.w;
      acc[16] += mq * r4.x; acc[17] += mq * r4.y; acc[18] += mq * r4.z; acc[19] += mq * r4.w;
    }
#pragma unroll
    for (int o = 0; o < 20; o++) {
      float v = acc[o];
      for (int off = 32; off > 0; off >>= 1) v += __shfl_down(v, off, 64);
      if (lane == 0) e0p[w][o] = v;
    }
  }
  __syncthreads();
  if (t < 20)
    h0[t] = fmaxf(eb0[t] + e0p[0][t] + e0p[1][t] + e0p[2][t] + e0p[3][t], 0.f);
  __syncthreads();

  // ---- h1[64] = relu(eb1 + h0 @ ew1), fan-in 20 split 5/wave ----
  {
    float s = 0.f;
#pragma unroll
    for (int q = 0; q < 5; q++) s += h0[w * 5 + q] * ew1[(w * 5 + q) * 64 + lane];
    pt[w][lane] = s;
  }
  __syncthreads();
  if (w == 0)
    h1[lane] = fmaxf(eb1[lane] + pt[0][lane] + pt[1][lane] + pt[2][lane] + pt[3][lane], 0.f);
  __syncthreads();

  // ---- h2[64] = relu(eb2 + h1 @ ew2), fan-in 64 split 16/wave ----
  {
    float s = 0.f;
#pragma unroll
    for (int q = 0; q < 16; q++) s += h1[w * 16 + q] * ew2[(w * 16 + q) * 64 + lane];
    pt[w][lane] = s;
  }
  __syncthreads();
  if (w == 0)
    h2[lane] = fmaxf(eb2[lane] + pt[0][lane] + pt[1][lane] + pt[2][lane] + pt[3][lane], 0.f);
  __syncthreads();

  // ---- hm/hl in parallel: waves 0,1 -> hm; waves 2,3 -> hl ----
  {
    const float* W = (w < 2) ? mw0 : lw0;
    int qb = (w & 1) * 32;
    float s = 0.f;
#pragma unroll
    for (int q = 0; q < 32; q++) s += h2[qb + q] * W[(qb + q) * 64 + lane];
    pt[w][lane] = s;
  }
  __syncthreads();
  if (w == 0) hm[lane] = fmaxf(mb0[lane] + pt[0][lane] + pt[1][lane], 0.f);
  if (w == 1) hl[lane] = fmaxf(lb0[lane] + pt[2][lane] + pt[3][lane], 0.f);
  __syncthreads();

  // ---- qmu/qlv in parallel (no relu) ----
  {
    const float* W = (w < 2) ? mw1 : lw1;
    const float* src = (w < 2) ? hm : hl;
    int qb = (w & 1) * 32;
    float s = 0.f;
#pragma unroll
    for (int q = 0; q < 32; q++) s += src[qb + q] * W[(qb + q) * 64 + lane];
    pt[w][lane] = s;
  }
  __syncthreads();
  if (w == 0) qmu[lane] = mb1[lane] + pt[0][lane] + pt[1][lane];
  if (w == 1) qlv[lane] = lb1[lane] + pt[2][lane] + pt[3][lane];
  __syncthreads();

  // ---- reparameterize (wave 0) + output qz/qmu/qlv ----
  if (w == 0) {
    u32 o0, o1;
    tf2x32(keys[2], keys[3], 0u, (u32)(p * 64 + lane), o0, o1);
    u32 bits = o0 ^ o1;
    float f = __uint_as_float((bits >> 9) | 0x3f800000u) - 1.0f;
    float LOF = __uint_as_float(0xBF7FFFFFu);
    float uu = fmaxf(LOF, f * 2.0f + LOF);
    float eps = (float)(1.4142135623730951 * d_erfinv((double)uu));
    float qzv = qmu[lane] + eps * expf(0.5f * qlv[lane]);
    qz[lane] = qzv;
    out[O_QZ  + p * 64 + lane] = qzv;
    out[O_QMU + p * 64 + lane] = qmu[lane];
    out[O_QLV + p * 64 + lane] = qlv[lane];
  }
  __syncthreads();

  // ---- d0: h3[10] = relu(db0 + qz @ dw0), fan-in 64 split 16/wave ----
  {
    float s = 0.f;
    if (lane < 10) {
#pragma unroll
      for (int q = 0; q < 16; q++) s += qz[w * 16 + q] * dw0[(w * 16 + q) * 10 + lane];
    }
    pt[w][lane] = s;
  }
  __syncthreads();
  if (w == 0 && lane < 10)
    h3[lane] = fmaxf(db0[lane] + pt[0][lane] + pt[1][lane] + pt[2][lane] + pt[3][lane], 0.f);
  __syncthreads();

  // ---- d1: h4[128] = relu(db1 + h3 @ dw1); wave pairs split outputs,
  //      wave parity splits fan-in 5/5 ----
  {
    int o = (w >> 1) * 64 + lane;
    int qb = (w & 1) * 5;
    float s = 0.f;
#pragma unroll
    for (int q = 0; q < 5; q++) s += h3[qb + q] * dw1[(qb + q) * 128 + o];
    pt[w][lane] = s;
  }
  __syncthreads();
  if (w == 0) h4[lane]      = fmaxf(db1[lane]      + pt[0][lane] + pt[1][lane], 0.f);
  if (w == 1) h4[64 + lane] = fmaxf(db1[64 + lane] + pt[2][lane] + pt[3][lane], 0.f);
  __syncthreads();

  // ---- d2: recons[128] = db2 + h4 @ dw2; outputs split by wave pair,
  //      fan-in 128 split 64/64 by wave parity ----
  {
    int o = (w >> 1) * 64 + lane;
    int qb = (w & 1) * 64;
    float s = 0.f;
#pragma unroll
    for (int q = 0; q < 64; q++) s += h4[qb + q] * dw2[(qb + q) * 128 + o];
    pt[w][lane] = s;
  }
  __syncthreads();
  if (w == 0) out[O_REC + p * 128 + lane]      = db2[lane]      + pt[0][lane] + pt[1][lane];
  if (w == 1) out[O_REC + p * 128 + 64 + lane] = db2[64 + lane] + pt[2][lane] + pt[3][lane];
}

extern "C" void kernel_launch(void* const* d_in, const int* in_sizes, int n_in,
                              void* d_out, int out_size, void* d_ws, size_t ws_size,
                              hipStream_t stream) {
  (void)in_sizes; (void)n_in; (void)out_size; (void)ws_size;
  const float* z_gt = (const float*)d_in[0];
  const float* z0   = (const float*)d_in[1];
  const float* ew0 = (const float*)d_in[2];  const float* eb0 = (const float*)d_in[3];
  const float* ew1 = (const float*)d_in[4];  const float* eb1 = (const float*)d_in[5];
  const float* ew2 = (const float*)d_in[6];  const float* eb2 = (const float*)d_in[7];
  const float* mw0 = (const float*)d_in[8];  const float* mb0 = (const float*)d_in[9];
  const float* mw1 = (const float*)d_in[10]; const float* mb1 = (const float*)d_in[11];
  const float* lw0 = (const float*)d_in[12]; const float* lb0 = (const float*)d_in[13];
  const float* lw1 = (const float*)d_in[14]; const float* lb1 = (const float*)d_in[15];
  const float* dw0 = (const float*)d_in[16]; const float* db0 = (const float*)d_in[17];
  const float* dw1 = (const float*)d_in[18]; const float* db1 = (const float*)d_in[19];
  const float* dw2 = (const float*)d_in[20]; const float* db2 = (const float*)d_in[21];
  const int* seed = (const int*)d_in[22];
  double* ws = (double*)d_ws;
  float* out = (float*)d_out;
  const float* Rf = (const float*)(ws + R_OFF);
  const u32* wl = (const u32*)(ws + GF_OFF);  // tier worklists (chol phase only;
                                              // region is reused by k_grad later)

  k_R<<<64, 512, 0, stream>>>(z_gt, ws, seed);
  k_probs<<<C_P * C_D, 64, 0, stream>>>(z0, ws);
  k_sample<<<C_P * C_S, 64, 0, stream>>>(ws);
  k_chol_all<<<NBLK_ALL, 256, 0, stream>>>(Rf, ws + CTAB_OFF,
      (const u64*)(ws + GCOL_OFF), ws + NS_OFF, wl);
  k_logpw<<<C_P, 64, 0, stream>>>(ws + NS_OFF, ws + W_OFF);
  k_grad<<<2 * C_P * C_D + C_P * C_P, 64, 0, stream>>>(ws, z0);
  k_znew<<<(C_P * 8192) / 64, 64, 0, stream>>>(z0, ws, out);
  k_s2col<<<C_P * C_D, 64, 0, stream>>>(ws, out);
  k_chol<true><<<C_P * C_D, 64, 0, stream>>>(Rf, ws + CTAB_OFF,
      (const u64*)(ws + NS_OFF), ws + NS2_OFF);
  k_mlp<<<C_P, 256, 0, stream>>>(ws, out, ws + NS2_OFF,
      ew0, eb0, ew1, eb1, ew2, eb2,
      mw0, mb0, mw1, mb1, lw0, lb0, lw1, lb1,
      dw0, db0, dw1, db1, dw2, db2);
}

// Round 6
// 350.255 us; speedup vs baseline: 1.0409x; 1.0409x over previous
//
#include <hip/hip_runtime.h>
#include <stdint.h>
#include <math.h>

typedef unsigned long long u64;
typedef unsigned int u32;
typedef unsigned short u16;

// ---- problem constants ----
#define C_P 32
#define C_S 16
#define C_D 64
#define C_N 2048

// ---- ws layout (offsets in doubles) ----
#define R_OFF      0        // float[4096]
#define CTAB_OFF   4160     // double[64]
#define KEYS_OFF   4224     // u32[4]
#define PROBS_OFF  4232     // float[131072]
#define GROW_OFF   135304   // u64[32768] row masks
#define GCOL_OFF   168072   // u64[32768] col masks
#define NS_OFF     200840   // double[32768]; later grow2 u64[2048]
#define W_OFF      233608   // double[512]
#define GF_OFF     234120   // float[262144]; chol-phase: tier worklists (u32)
#define KM_OFF     365192   // float[1024]
#define ZN_OFF     365704   // float[262144]
#define NS2_OFF    496776   // double[2048]

// worklist layout (u32 indices into GF region):
//   wl[0..4] = counts tier0(m<=29)/1(<=32)/2(<=35)/3(<=40)/heavy(>40)
//   wl[16 + tier*32768 + i] = task ids   (5*32768+16 u32 < 262144 u32 budget)
#define WL_LIST0 16

// merged chol kernel block ranges — HEAVY FIRST, then tiers by descending
// cost (round-5 lesson: heavy-last = low-occupancy tail, 131us vs ~100).
// Counts sized for ~1 task per wave (expected populations 650/6900/8800/8800/7500).
#define HBLK 768
#define TB3 1728
#define TB2 2208
#define TB1 2208
#define TB0 1920
#define E3 (HBLK + TB3)
#define E2 (E3 + TB2)
#define E1 (E2 + TB1)
#define NBLK_ALL (E1 + TB0)

// ---- out layout (FLOAT32 elements) ----
#define O_REC   0
#define O_LOGP  4096
#define O_QZ    4128
#define O_QMU   6176
#define O_QLV   8224
#define O_GH    10272
#define O_ZN    141344
#define O_TOTAL 403488

__device__ __forceinline__ void tf2x32(u32 k0, u32 k1, u32 x0, u32 x1,
                                       u32& o0, u32& o1) {
  u32 ks2 = k0 ^ k1 ^ 0x1BD11BDAu;
  x0 += k0; x1 += k1;
#define TFR(r) { x0 += x1; x1 = (x1 << r) | (x1 >> (32 - r)); x1 ^= x0; }
  TFR(13) TFR(15) TFR(26) TFR(6)   x0 += k1;  x1 += ks2 + 1u;
  TFR(17) TFR(29) TFR(16) TFR(24)  x0 += ks2; x1 += k0 + 2u;
  TFR(13) TFR(15) TFR(26) TFR(6)   x0 += k0;  x1 += k1 + 3u;
  TFR(17) TFR(29) TFR(16) TFR(24)  x0 += k1;  x1 += ks2 + 4u;
  TFR(13) TFR(15) TFR(26) TFR(6)   x0 += ks2; x1 += k0 + 5u;
#undef TFR
  o0 = x0; o1 = x1;
}

__device__ __forceinline__ double d_erfinv(double x) {
  double w = -log1p(-x * x);
  double p;
  if (w < 5.0) {
    w -= 2.5;
    p = 2.81022636e-08;
    p = 3.43273939e-07  + p * w;
    p = -3.5233877e-06  + p * w;
    p = -4.39150654e-06 + p * w;
    p = 0.00021858087   + p * w;
    p = -0.00125372503  + p * w;
    p = -0.00417768164  + p * w;
    p = 0.246640727     + p * w;
    p = 1.50140941      + p * w;
  } else {
    w = sqrt(w) - 3.0;
    p = -0.000200214257;
    p = 0.000100950558  + p * w;
    p = 0.00134934322   + p * w;
    p = -0.00367342844  + p * w;
    p = 0.00573950773   + p * w;
    p = -0.0076224613   + p * w;
    p = 0.00943887047   + p * w;
    p = 1.00167406      + p * w;
    p = 2.83297682      + p * w;
  }
  return p * x;
}

// Stirling lgamma for large z (z ~ 1026: abs err ~1e-12, plenty for f32 out)
__device__ __forceinline__ double stirl(double z) {
  double zi = 1.0 / z;
  double zi2 = zi * zi;
  double s = (z - 0.5) * log(z) - z + 0.9189385332046727;  // 0.5*ln(2*pi)
  s += zi * (1.0 / 12.0 - zi2 * (1.0 / 360.0 - zi2 * (1.0 / 1260.0)));
  return s;
}

// R (with fused setup on block 0): one pass Sx/Sxx, combine analytically.
// ctab via recurrence ctab[l] = ctab[l-2] + log((2049+l)/(4(1+l))):
// per-lane log + parity prefix scan + 2 Stirling seeds.
__global__ void k_R(const float* x, double* ws, const int* seedp) {
  __shared__ double pS[8][64], pX[8][64];
  __shared__ double xbar[64];
  int j = blockIdx.x, t = threadIdx.x;   // 512 threads
  int i = t & 63, c = t >> 6;
  if (j == 0) {                          // fused k_setup
    if (t < 64) {
      int l = t;
      double term = (l >= 2) ? log((2049.0 + (double)l) / (4.0 * (1.0 + (double)l)))
                             : 0.0;
      double v = term;
#pragma unroll
      for (int off = 2; off <= 32; off <<= 1) {
        double o = __shfl_up(v, off, 64);
        if (l >= off) v += o;
      }
      const double LOG_HALF = -0.6931471805599453;
      double c0 = -0.5 * log(2049.0)
                - 1024.0 * log(3.14159265358979323846);
      double seed = (l & 1)
        ? c0 + stirl(1026.0) + 2.5 * LOG_HALF                       // -lgamma(2)=0
        : c0 + stirl(1025.5) + 0.12078223763524522235 + 1.5 * LOG_HALF; // -lgamma(1.5)
      ws[CTAB_OFF + l] = seed + v;
    }
    if (t < 8) ((u32*)(ws + GF_OFF))[t] = 0;   // zero worklist counters
    if (t == 0) {
      u32 kk0 = 0u, kk1 = (u32)seedp[0];
      u32 a0, a1, s0, s1, r0, r1, d0, d1;
      tf2x32(kk0, kk1, 0u, 0u, a0, a1);
      tf2x32(kk0, kk1, 0u, 1u, s0, s1);   // sk (bernoulli)
      tf2x32(a0, a1, 0u, 0u, d0, d1); (void)d0; (void)d1;
      tf2x32(a0, a1, 0u, 1u, r0, r1);     // rk (normal eps)
      u32* keys = (u32*)(ws + KEYS_OFF);
      keys[0] = s0; keys[1] = s1; keys[2] = r0; keys[3] = r1;
    }
  }
  double sx = 0.0, sxx = 0.0;
  for (int n = c * 256; n < (c + 1) * 256; n++) {
    double xi = (double)x[n * 64 + i];
    double xj = (double)x[n * 64 + j];
    sx += xi; sxx += xi * xj;
  }
  pS[c][i] = sx; pX[c][i] = sxx;
  __syncthreads();
  if (t < 64) {
    double S = 0.0, X = 0.0;
    for (int cc = 0; cc < 8; cc++) { S += pS[cc][i]; X += pX[cc][i]; }
    xbar[i] = S / 2048.0;
    pX[0][i] = X;
  }
  __syncthreads();
  if (t < 64) {
    double xbi = xbar[i], xbj = xbar[j];
    double s = pX[0][i] - 2048.0 * xbi * xbj + (2048.0 / 2049.0) * xbi * xbj;
    if (i == j) s += 0.5;
    ((float*)(ws + R_OFF))[i * 64 + j] = (float)s;
  }
}

// probs[p,i,j] = sigmoid(alpha * u_i . v_j) * (i!=j), stored f32
__global__ __launch_bounds__(64) void k_probs(const float* z, double* ws) {
  float* probs = (float*)(ws + PROBS_OFF);
  int b = blockIdx.x; int p = b >> 6, i = b & 63;
  int j = threadIdx.x;
  __shared__ float V[64 * 65];
  __shared__ float us[64];
  int k = j;
  us[k] = z[((p * 64 + i) * 64 + k) * 2 + 0];
  for (int jj = 0; jj < 64; jj++)
    V[jj * 65 + k] = z[((p * 64 + jj) * 64 + k) * 2 + 1];
  __syncthreads();
  float s = 0.f;
  for (int kk = 0; kk < 64; kk++)
    s += us[kk] * V[j * 65 + kk];
  float pr = (i == j) ? 0.f : 1.f / (1.f + expf(-0.2f * s));
  probs[(p * 64 + i) * 64 + j] = pr;
}

// sample graphs AND bucket tasks into the 5 chol tiers (wave-aggregated
// atomics: one atomicAdd per wave per tier).
__global__ void k_sample(double* ws) {
  const float* probs = (const float*)(ws + PROBS_OFF);
  const u32* keys = (const u32*)(ws + KEYS_OFF);
  u64* grow = (u64*)(ws + GROW_OFF);
  u64* gcol = (u64*)(ws + GCOL_OFF);
  u32* wl = (u32*)(ws + GF_OFF);
  int ps = blockIdx.x;
  int p = ps >> 4;
  int j = threadIdx.x;
  u32 k0 = keys[0], k1 = keys[1];
  u64 colmask = 0;
  for (int i = 0; i < 64; i++) {
    u32 lin = (u32)(ps * 4096 + i * 64 + j);
    u32 o0, o1; tf2x32(k0, k1, 0u, lin, o0, o1);
    u32 bits = o0 ^ o1;
    float f = __uint_as_float((bits >> 9) | 0x3f800000u) - 1.0f;
    bool bit = (f < probs[(p * 64 + i) * 64 + j]);
    u64 rm = __ballot(bit);
    if (j == 0) grow[ps * 64 + i] = rm;
    if (bit) colmask |= (1ull << i);
  }
  gcol[ps * 64 + j] = colmask;
  // tier bucketing: task (ps, col j), m = popc+1
  int m = (int)__popcll(colmask) + 1;
  int tier = (m <= 29) ? 0 : (m <= 32) ? 1 : (m <= 35) ? 2 : (m <= 40) ? 3 : 4;
#pragma unroll
  for (int t = 0; t < 5; t++) {
    u64 b = __ballot(tier == t);
    if (tier == t) {
      int leader = (int)__builtin_ctzll(b);
      u32 off = (u32)__popcll(b & ((1ull << j) - 1ull));
      u32 base = 0;
      if (j == leader) base = atomicAdd(&wl[t], (u32)__popcll(b));
      base = (u32)__shfl((int)base, leader, 64);
      wl[WL_LIST0 + t * 32768 + base + off] = (u32)(ps * 64 + j);
    }
  }
}

__device__ __forceinline__ float rdlane(float x, int l) {
  return __uint_as_float(__builtin_amdgcn_readlane(__float_as_uint(x), (u32)l));
}

// Per-wave register LDL for one tier. Direct global loads via R symmetry;
// f32 __logf epilogue (sampled-graph scores only feed softmax weights).
// All LDS traffic intra-wave -> wave_barrier only; grid-strides its tier list.
template<int MMAX>
__device__ __forceinline__ void tier_body(const float* Rf, const double* ctab,
                                          const u64* masks, double* nodescore,
                                          const u32* wl, int tier,
                                          u32 brel, u32 nb, int (*idx)[64]) {
  int w = threadIdx.x >> 6;
  int lane = threadIdx.x & 63;
  u32 cnt = wl[tier];
  const u32* list = wl + WL_LIST0 + tier * 32768;
  for (u32 ti = brel * 4 + (u32)w; ti < cnt; ti += nb * 4) {
    int task = (int)list[ti];
    int j = task & 63;
    u64 mask = masks[task];
    int P = (int)__popcll(mask);
    int m = P + 1;
    idx[w][lane] = 0;                       // sanitize (dead slots -> row 0)
    __builtin_amdgcn_wave_barrier();
    u64 below = mask & ((1ull << lane) - 1ull);
    if ((mask >> lane) & 1ull) idx[w][(int)__popcll(below)] = lane;
    if (lane == 0) idx[w][P] = j;
    __builtin_amdgcn_wave_barrier();
    int myrow = idx[w][lane];               // my node id (0 for dead lanes)
    float v[MMAX];
#pragma unroll
    for (int c = 0; c < MMAX; c++)
      v[c] = Rf[idx[w][c] * 64 + myrow];    // A[lane][c] via symmetry
    float mypiv = 1.0f;
#pragma unroll
    for (int k = 0; k < MMAX; k++) {
      if (k < m) {                          // uniform guard (keeps full unroll)
        float dk = rdlane(v[k], k);
        if (lane == k) mypiv = dk;
        float ns = -v[k] * __builtin_amdgcn_rcpf(dk);
#pragma unroll
        for (int b = k + 1; b < MMAX; b++)
          v[b] += ns * rdlane(v[k], b);     // garbage slots never read back
      }
    }
    float lastd = __shfl(mypiv, P, 64);     // final pivot d_{m-1} (lane P)
    float lv = (lane < m) ? __logf(mypiv) : 0.f;
    for (int off = 32; off > 0; off >>= 1) lv += __shfl_down(lv, off, 64);
    if (lane == 0) {
      double l = (double)P;
      nodescore[task] = ctab[P]
                      - 0.5 * (2050.0 + l) * (double)__logf(lastd)
                      - 0.5 * (double)lv;
    }
    __builtin_amdgcn_wave_barrier();        // order idx reuse across iterations
  }
}

#define WB() __builtin_amdgcn_wave_barrier()

// Heavy path (m>40, ~1%): wave 0 of the block only; full hybrid path with
// LDS triangle. Single-wave semantics -> wave_barrier suffices (in-order
// per-wave LDS ops; compiler inserts lgkmcnt waits).
__device__ void heavy_body(const float* Rf, const double* ctab,
                           const u64* masks, double* nodescore,
                           const u32* wl, u32 brel, u32 nb,
                           float* T, int* idx) {
  if (threadIdx.x >= 64) return;
  int lane = threadIdx.x;
  u32 cnt = wl[4];
  const u32* list = wl + WL_LIST0 + 4 * 32768;
  for (u32 ii = brel; ii < cnt; ii += nb) {
    WB();
    int task = (int)list[ii];
    int j = task & 63;
    u64 mask = masks[task];
    int P = (int)__popcll(mask);
    int m = P + 1;
    u64 below = mask & ((1ull << lane) - 1ull);
    if ((mask >> lane) & 1ull) idx[(int)__popcll(below)] = lane;
    if (lane == 0) idx[P] = j;
    WB();
    int trLane = (lane * (lane + 1)) >> 1;
    if (lane < m) {
      int cidx = idx[lane];
      int tr = 0;
      for (int r = 0; r < m; r++) {
        if (lane <= r) T[tr + lane] = Rf[idx[r] * 64 + cidx];
        tr += r + 1;
      }
    }
    WB();
    float mypiv = 1.0f, lastd = 1.0f;
    float v[40];
#pragma unroll
    for (int c = 0; c < 40; c++)
      v[c] = T[trLane + c];
#pragma unroll
    for (int k = 0; k < 40; k++) {
      if (k < m) {
        float dk = rdlane(v[k], k);
        if (lane == k) mypiv = dk;
        lastd = dk;
        float ns = -v[k] * __builtin_amdgcn_rcpf(dk);
#pragma unroll
        for (int b = k + 1; b < 40; b++)
          v[b] += ns * rdlane(v[k], b);
      }
    }
    if (m > 40) {
      for (int b = 40; b < m; b++) {
        float acc = 0.f;
#pragma unroll
        for (int k = 0; k < 40; k++) {
          float dk = rdlane(v[k], k);
          float abk = rdlane(v[k], b);
          acc += v[k] * abk * __builtin_amdgcn_rcpf(dk);
        }
        if (lane >= b) T[trLane + b] -= acc;
      }
      WB();
      for (int k = 40; k < m; k++) {
        float dk = T[((k * (k + 1)) >> 1) + k];
        if (lane == k) mypiv = dk;
        lastd = dk;
        float sk = T[trLane + k] * __builtin_amdgcn_rcpf(dk);
        for (int b = k + 1; b < m; b++) {
          float abk = T[((b * (b + 1)) >> 1) + k];
          if (lane >= b) T[trLane + b] -= sk * abk;
        }
        WB();
      }
    }
    double vv = (lane < m) ? log((double)mypiv) : 0.0;
    for (int off = 32; off > 0; off >>= 1) vv += __shfl_down(vv, off, 64);
    if (lane == 0) {
      double logB = vv;
      double logA = logB - log((double)lastd);
      double l = (double)P;
      nodescore[task] = ctab[P]
                      + 0.5 * (2050.0 + l) * logA
                      - 0.5 * (2051.0 + l) * logB;
    }
  }
}

// ONE launch for all 32768 sampled-graph cholesky tasks. HEAVY blocks first
// (longest tasks start at t=0 and hide under the light flood), then tiers in
// descending cost order; block counts sized to ~1 task/wave. No min-waves
// launch_bounds cap (round-1 lesson: caps + big v[] => scratch spill).
__global__ __launch_bounds__(256) void k_chol_all(const float* Rf, const double* ctab,
                                                  const u64* masks, double* nodescore,
                                                  const u32* wl) {
  __shared__ int idx4[4][64];
  __shared__ float T[2080];
  __shared__ int idxh[64];
  u32 b = blockIdx.x;
  if (b < HBLK)    heavy_body(Rf, ctab, masks, nodescore, wl, b, HBLK, T, idxh);
  else if (b < E3) tier_body<40>(Rf, ctab, masks, nodescore, wl, 3, b - HBLK, TB3, idx4);
  else if (b < E2) tier_body<35>(Rf, ctab, masks, nodescore, wl, 2, b - E3, TB2, idx4);
  else if (b < E1) tier_body<32>(Rf, ctab, masks, nodescore, wl, 1, b - E2, TB1, idx4);
  else             tier_body<29>(Rf, ctab, masks, nodescore, wl, 0, b - E1, TB0, idx4);
}

// Merged hybrid f32 LDL Cholesky (transpose variant for the 2048 hard-graph
// tasks). UNCHANGED and kept f64: its scores feed the log_p OUTPUT, where
// absmax is already at 1 f32 ulp of |logp|~4000.
template<bool TRANSPOSE>
__global__ __launch_bounds__(64) void k_chol(const float* Rf, const double* ctab,
                                             const u64* masks, double* nodescore) {
  __shared__ float T[2080];
  __shared__ int idx[64];
  int task = blockIdx.x;
  int j = task & 63;
  int lane = threadIdx.x;
  u64 mask;
  if (TRANSPOSE) {
    int p = task >> 6;
    u64 rm = masks[p * 64 + lane];       // row mask of row `lane`
    mask = __ballot((rm >> j) & 1ull);   // column j mask
  } else {
    mask = masks[task];
  }
  int P = (int)__popcll(mask);
  int m = P + 1;
  u64 below = mask & ((1ull << lane) - 1ull);
  if ((mask >> lane) & 1ull) idx[(int)__popcll(below)] = lane;
  if (lane == 0) idx[P] = j;
  __syncthreads();
  int trLane = (lane * (lane + 1)) >> 1;
  if (lane < m) {
    int cidx = idx[lane];
    int tr = 0;
    for (int r = 0; r < m; r++) {
      if (lane <= r) T[tr + lane] = Rf[idx[r] * 64 + cidx];
      tr += r + 1;
    }
  }
  __syncthreads();
  float mypiv = 1.0f, lastd = 1.0f;
  float v[40];
#pragma unroll
  for (int c = 0; c < 40; c++)
    v[c] = T[trLane + c];                // in-bounds garbage for c>lane
#pragma unroll
  for (int k = 0; k < 40; k++) {
    if (k < m) {                         // uniform guard (keeps full unroll)
      float dk = rdlane(v[k], k);
      if (lane == k) mypiv = dk;
      lastd = dk;
      float ns = -v[k] * __builtin_amdgcn_rcpf(dk);
#pragma unroll
      for (int b = k + 1; b < 40; b++)
        v[b] += ns * rdlane(v[k], b);    // garbage slots harmless
    }
  }
  if (m > 40) {                          // heavy tasks only (block-uniform)
    for (int b = 40; b < m; b++) {
      float acc = 0.f;
#pragma unroll
      for (int k = 0; k < 40; k++) {
        float dk = rdlane(v[k], k);                  // final pivot k
        float abk = rdlane(v[k], b);                 // final A[b][k]
        acc += v[k] * abk * __builtin_amdgcn_rcpf(dk);
      }
      if (lane >= b) T[trLane + b] -= acc;           // own-row, no conflict
    }
    __syncthreads();
    for (int k = 40; k < m; k++) {
      float dk = T[((k * (k + 1)) >> 1) + k];        // broadcast
      if (lane == k) mypiv = dk;
      lastd = dk;
      float sk = T[trLane + k] * __builtin_amdgcn_rcpf(dk);
      for (int b = k + 1; b < m; b++) {
        float abk = T[((b * (b + 1)) >> 1) + k];     // broadcast
        if (lane >= b) T[trLane + b] -= sk * abk;
      }
      __syncthreads();
    }
  }
  double vv = (lane < m) ? log((double)mypiv) : 0.0;
  for (int off = 32; off > 0; off >>= 1) vv += __shfl_down(vv, off, 64);
  if (lane == 0) {
    double logB = vv;
    double logA = logB - log((double)lastd);
    double l = (double)P;
    nodescore[task] = ctab[P]
                    + 0.5 * (2050.0 + l) * logA
                    - 0.5 * (2051.0 + l) * logB;
  }
}

__global__ void k_logpw(const double* ns, double* w) {
  int p = blockIdx.x, t = threadIdx.x;
  __shared__ double part[64];
  int s = t & 15, c = t >> 4;            // 4 chunks x 16 samples
  double acc = 0.0;
  for (int j = c * 16; j < (c + 1) * 16; j++)
    acc += ns[(p * 16 + s) * 64 + j];
  part[t] = acc;
  __syncthreads();
  if (t < 16) part[t] = part[t] + part[t + 16] + part[t + 32] + part[t + 48];
  __syncthreads();
  if (t == 0) {
    double m = part[0];
    for (int s2 = 1; s2 < 16; s2++) m = fmax(m, part[s2]);
    double e[16], sum = 0.0;
    for (int s2 = 0; s2 < 16; s2++) { e[s2] = exp(part[s2] - m); sum += e[s2]; }
    for (int s2 = 0; s2 < 16; s2++) w[p * 16 + s2] = e[s2] / sum;
  }
}

// fused A-construction + grad dot + kmat.
// blocks 0..2047: grad_u; 2048..4095: grad_v; 4096..5119: Kmat (z0-only).
__global__ void k_grad(double* ws, const float* z) {
  const float* probs = (const float*)(ws + PROBS_OFF);
  const double* w = ws + W_OFF;
  const u64* grow = (const u64*)(ws + GROW_OFF);
  const u64* gcol = (const u64*)(ws + GCOL_OFF);
  float* gf = (float*)(ws + GF_OFF);
  const float LOGIT = -2.6903717578966254f;  // log(4/63)-log1p(-4/63)
  int bb = blockIdx.x;
  int k = threadIdx.x;
  __shared__ float acc[64];
  if (bb < 2048) {
    int p = bb >> 6, i = bb & 63;
    float gb = 0.f, wsum = 0.f;
    for (int s = 0; s < 16; s++) {
      float wv = (float)w[p * 16 + s];
      wsum += wv;
      gb += wv * (float)((grow[(p * 16 + s) * 64 + i] >> k) & 1ull);
    }
    float pr = probs[(p * 64 + i) * 64 + k];   // coalesced
    float od = (i == k) ? 0.f : 1.f;
    acc[k] = (0.2f * (gb - pr * wsum) + 0.2f * pr * (1.f - pr) * LOGIT) * od;
    __syncthreads();
    float s = 0.f;
    for (int j = 0; j < 64; j++)
      s += acc[j] * z[((p * 64 + j) * 64 + k) * 2 + 1];
    s -= 64.f * z[((p * 64 + i) * 64 + k) * 2 + 0];
    gf[p * 8192 + (i * 64 + k) * 2 + 0] = s;
  } else if (bb < 4096) {
    int b = bb - 2048;
    int p = b >> 6, j = b & 63;
    float gb = 0.f, wsum = 0.f;
    for (int s = 0; s < 16; s++) {
      float wv = (float)w[p * 16 + s];
      wsum += wv;
      gb += wv * (float)((gcol[(p * 16 + s) * 64 + j] >> k) & 1ull);
    }
    float pr = probs[(p * 64 + k) * 64 + j];   // one 64-lane gather
    float od = (k == j) ? 0.f : 1.f;
    acc[k] = (0.2f * (gb - pr * wsum) + 0.2f * pr * (1.f - pr) * LOGIT) * od;
    __syncthreads();
    float s = 0.f;
    for (int i = 0; i < 64; i++)
      s += acc[i] * z[((p * 64 + i) * 64 + k) * 2 + 0];
    s -= 64.f * z[((p * 64 + j) * 64 + k) * 2 + 1];
    gf[p * 8192 + (j * 64 + k) * 2 + 1] = s;
  } else {
    float* Km = (float*)(ws + KM_OFF);
    int b = bb - 4096;
    int a = b >> 5, b2 = b & 31;
    float accf = 0.f;
    for (int d0 = k; d0 < 8192; d0 += 64) {
      float diff = z[a * 8192 + d0] - z[b2 * 8192 + d0];
      accf += diff * diff;
    }
    for (int off = 32; off > 0; off >>= 1) accf += __shfl_down(accf, off, 64);
    if (k == 0) Km[a * 32 + b2] = expf(-accf / 5.0f);
  }
}

__global__ void k_znew(const float* z, double* ws, float* out) {
  const float* Km = (const float*)(ws + KM_OFF);
  const float* gf = (const float*)(ws + GF_OFF);
  float* zn = (float*)(ws + ZN_OFF);
  int gid = blockIdx.x * 64 + threadIdx.x;
  int p = gid >> 13, t = gid & 8191;
  float zp = z[p * 8192 + t];
  float accg = 0.f, accz = 0.f, ks = 0.f;
  for (int b = 0; b < 32; b++) {
    float kv = Km[p * 32 + b];
    accg += kv * gf[b * 8192 + t];
    accz += kv * z[b * 8192 + t];
    ks += kv;
  }
  float rep = -0.4f * (accz - zp * ks);
  float v = zp + 0.005f * ((accg + rep) / 32.f);
  zn[p * 8192 + t] = v;
  out[O_ZN + p * 8192 + t] = v;
}

__global__ __launch_bounds__(64) void k_s2col(double* ws, float* out) {
  const float* zn = (const float*)(ws + ZN_OFF);
  u64* grow2 = (u64*)(ws + NS_OFF);
  int b = blockIdx.x; int p = b >> 6, i = b & 63;
  int j = threadIdx.x;
  __shared__ float V[64 * 65];
  __shared__ float us[64];
  int k = j;
  us[k] = zn[p * 8192 + (i * 64 + k) * 2 + 0];
  for (int jj = 0; jj < 64; jj++)
    V[jj * 65 + k] = zn[p * 8192 + (jj * 64 + k) * 2 + 1];
  __syncthreads();
  float s = 0.f;
  for (int kk = 0; kk < 64; kk++)
    s += us[kk] * V[j * 65 + kk];
  bool bit = (i != j) && (s > 0.0f);
  out[O_GH + (p * 64 + i) * 64 + j] = bit ? 1.0f : 0.0f;
  u64 m = __ballot(bit);
  if (j == 0) grow2[p * 64 + i] = m;    // row masks; k_chol<true> transposes
}

// encoder/decoder MLP; also writes log_p (fused reduction).
// 256 threads (4 waves) per particle; fan-in split across waves; e0 via
// float4 weight loads + mask-multiply.
__global__ __launch_bounds__(256) void k_mlp(double* ws, float* out, const double* ns2,
    const float* ew0, const float* eb0, const float* ew1, const float* eb1,
    const float* ew2, const float* eb2,
    const float* mw0, const float* mb0, const float* mw1, const float* mb1,
    const float* lw0, const float* lb0, const float* lw1, const float* lb1,
    const float* dw0, const float* db0, const float* dw1, const float* db1,
    const float* dw2, const float* db2) {
  int p = blockIdx.x, t = threadIdx.x;
  int w = t >> 6, lane = t & 63;
  const u64* grow2 = (const u64*)(ws + NS_OFF);
  const u32* keys = (const u32*)(ws + KEYS_OFF);
  __shared__ float pt[4][64];
  __shared__ float e0p[4][20];
  __shared__ float h0[20], h1[64], h2[64], hm[64], hl[64];
  __shared__ float qmu[64], qlv[64], qz[64], h3[10], h4[128];

  // ---- logp reduction (wave 0) ----
  if (w == 0) {
    double vv = ns2[p * 64 + lane];
    for (int off = 32; off > 0; off >>= 1) vv += __shfl_down(vv, off, 64);
    if (lane == 0) out[O_LOGP + p] = (float)vv;
  }

  // ---- e0: h0[20] = relu(eb0 + sum over set bits of ew0 rows) ----
  {
    int i = t >> 2;
    int jb = (t & 3) * 16;
    u32 m16 = (u32)((grow2[p * 64 + i] >> jb) & 0xFFFFull);
    float acc[20];
#pragma unroll
    for (int o = 0; o < 20; o++) acc[o] = 0.f;
    const float4* wb = (const float4*)(ew0 + (size_t)(t * 16) * 20);
#pragma unroll
    for (int q = 0; q < 16; q++) {
      float mq = (float)((m16 >> q) & 1u);
      float4 r0 = wb[q * 5 + 0], r1 = wb[q * 5 + 1], r2 = wb[q * 5 + 2];
      float4 r3 = wb[q * 5 + 3], r4 = wb[q * 5 + 4];
      acc[0]  += mq * r0.x; acc[1]  += mq * r0.y; acc[2]  += mq * r0.z; acc[3]  += mq * r0.w;
      acc[4]  += mq * r1.x; acc[5]  += mq * r1.y; acc[6]  += mq * r1.z; acc[7]  += mq * r1.w;
      acc[8]  += mq * r2.x; acc[9]  += mq * r2.y; acc[10] += mq * r2.z; acc[11] += mq * r2.w;
      acc[12] += mq * r3.x; acc[13] += mq * r3.y; acc[14] += mq * r3.z; acc[15] += mq * r3.w;
      acc[16] += mq * r4.x; acc[17] += mq * r4.y; acc[18] += mq * r4.z; acc[19] += mq * r4.w;
    }
#pragma unroll
    for (int o = 0; o < 20; o++) {
      float v = acc[o];
      for (int off = 32; off > 0; off >>= 1) v += __shfl_down(v, off, 64);
      if (lane == 0) e0p[w][o] = v;
    }
  }
  __syncthreads();
  if (t < 20)
    h0[t] = fmaxf(eb0[t] + e0p[0][t] + e0p[1][t] + e0p[2][t] + e0p[3][t], 0.f);
  __syncthreads();

  // ---- h1[64] = relu(eb1 + h0 @ ew1), fan-in 20 split 5/wave ----
  {
    float s = 0.f;
#pragma unroll
    for (int q = 0; q < 5; q++) s += h0[w * 5 + q] * ew1[(w * 5 + q) * 64 + lane];
    pt[w][lane] = s;
  }
  __syncthreads();
  if (w == 0)
    h1[lane] = fmaxf(eb1[lane] + pt[0][lane] + pt[1][lane] + pt[2][lane] + pt[3][lane], 0.f);
  __syncthreads();

  // ---- h2[64] = relu(eb2 + h1 @ ew2), fan-in 64 split 16/wave ----
  {
    float s = 0.f;
#pragma unroll
    for (int q = 0; q < 16; q++) s += h1[w * 16 + q] * ew2[(w * 16 + q) * 64 + lane];
    pt[w][lane] = s;
  }
  __syncthreads();
  if (w == 0)
    h2[lane] = fmaxf(eb2[lane] + pt[0][lane] + pt[1][lane] + pt[2][lane] + pt[3][lane], 0.f);
  __syncthreads();

  // ---- hm/hl in parallel: waves 0,1 -> hm; waves 2,3 -> hl ----
  {
    const float* W = (w < 2) ? mw0 : lw0;
    int qb = (w & 1) * 32;
    float s = 0.f;
#pragma unroll
    for (int q = 0; q < 32; q++) s += h2[qb + q] * W[(qb + q) * 64 + lane];
    pt[w][lane] = s;
  }
  __syncthreads();
  if (w == 0) hm[lane] = fmaxf(mb0[lane] + pt[0][lane] + pt[1][lane], 0.f);
  if (w == 1) hl[lane] = fmaxf(lb0[lane] + pt[2][lane] + pt[3][lane], 0.f);
  __syncthreads();

  // ---- qmu/qlv in parallel (no relu) ----
  {
    const float* W = (w < 2) ? mw1 : lw1;
    const float* src = (w < 2) ? hm : hl;
    int qb = (w & 1) * 32;
    float s = 0.f;
#pragma unroll
    for (int q = 0; q < 32; q++) s += src[qb + q] * W[(qb + q) * 64 + lane];
    pt[w][lane] = s;
  }
  __syncthreads();
  if (w == 0) qmu[lane] = mb1[lane] + pt[0][lane] + pt[1][lane];
  if (w == 1) qlv[lane] = lb1[lane] + pt[2][lane] + pt[3][lane];
  __syncthreads();

  // ---- reparameterize (wave 0) + output qz/qmu/qlv ----
  if (w == 0) {
    u32 o0, o1;
    tf2x32(keys[2], keys[3], 0u, (u32)(p * 64 + lane), o0, o1);
    u32 bits = o0 ^ o1;
    float f = __uint_as_float((bits >> 9) | 0x3f800000u) - 1.0f;
    float LOF = __uint_as_float(0xBF7FFFFFu);
    float uu = fmaxf(LOF, f * 2.0f + LOF);
    float eps = (float)(1.4142135623730951 * d_erfinv((double)uu));
    float qzv = qmu[lane] + eps * expf(0.5f * qlv[lane]);
    qz[lane] = qzv;
    out[O_QZ  + p * 64 + lane] = qzv;
    out[O_QMU + p * 64 + lane] = qmu[lane];
    out[O_QLV + p * 64 + lane] = qlv[lane];
  }
  __syncthreads();

  // ---- d0: h3[10] = relu(db0 + qz @ dw0), fan-in 64 split 16/wave ----
  {
    float s = 0.f;
    if (lane < 10) {
#pragma unroll
      for (int q = 0; q < 16; q++) s += qz[w * 16 + q] * dw0[(w * 16 + q) * 10 + lane];
    }
    pt[w][lane] = s;
  }
  __syncthreads();
  if (w == 0 && lane < 10)
    h3[lane] = fmaxf(db0[lane] + pt[0][lane] + pt[1][lane] + pt[2][lane] + pt[3][lane], 0.f);
  __syncthreads();

  // ---- d1: h4[128] = relu(db1 + h3 @ dw1); wave pairs split outputs,
  //      wave parity splits fan-in 5/5 ----
  {
    int o = (w >> 1) * 64 + lane;
    int qb = (w & 1) * 5;
    float s = 0.f;
#pragma unroll
    for (int q = 0; q < 5; q++) s += h3[qb + q] * dw1[(qb + q) * 128 + o];
    pt[w][lane] = s;
  }
  __syncthreads();
  if (w == 0) h4[lane]      = fmaxf(db1[lane]      + pt[0][lane] + pt[1][lane], 0.f);
  if (w == 1) h4[64 + lane] = fmaxf(db1[64 + lane] + pt[2][lane] + pt[3][lane], 0.f);
  __syncthreads();

  // ---- d2: recons[128] = db2 + h4 @ dw2; outputs split by wave pair,
  //      fan-in 128 split 64/64 by wave parity ----
  {
    int o = (w >> 1) * 64 + lane;
    int qb = (w & 1) * 64;
    float s = 0.f;
#pragma unroll
    for (int q = 0; q < 64; q++) s += h4[qb + q] * dw2[(qb + q) * 128 + o];
    pt[w][lane] = s;
  }
  __syncthreads();
  if (w == 0) out[O_REC + p * 128 + lane]      = db2[lane]      + pt[0][lane] + pt[1][lane];
  if (w == 1) out[O_REC + p * 128 + 64 + lane] = db2[64 + lane] + pt[2][lane] + pt[3][lane];
}

extern "C" void kernel_launch(void* const* d_in, const int* in_sizes, int n_in,
                              void* d_out, int out_size, void* d_ws, size_t ws_size,
                              hipStream_t stream) {
  (void)in_sizes; (void)n_in; (void)out_size; (void)ws_size;
  const float* z_gt = (const float*)d_in[0];
  const float* z0   = (const float*)d_in[1];
  const float* ew0 = (const float*)d_in[2];  const float* eb0 = (const float*)d_in[3];
  const float* ew1 = (const float*)d_in[4];  const float* eb1 = (const float*)d_in[5];
  const float* ew2 = (const float*)d_in[6];  const float* eb2 = (const float*)d_in[7];
  const float* mw0 = (const float*)d_in[8];  const float* mb0 = (const float*)d_in[9];
  const float* mw1 = (const float*)d_in[10]; const float* mb1 = (const float*)d_in[11];
  const float* lw0 = (const float*)d_in[12]; const float* lb0 = (const float*)d_in[13];
  const float* lw1 = (const float*)d_in[14]; const float* lb1 = (const float*)d_in[15];
  const float* dw0 = (const float*)d_in[16]; const float* db0 = (const float*)d_in[17];
  const float* dw1 = (const float*)d_in[18]; const float* db1 = (const float*)d_in[19];
  const float* dw2 = (const float*)d_in[20]; const float* db2 = (const float*)d_in[21];
  const int* seed = (const int*)d_in[22];
  double* ws = (double*)d_ws;
  float* out = (float*)d_out;
  const float* Rf = (const float*)(ws + R_OFF);
  const u32* wl = (const u32*)(ws + GF_OFF);  // tier worklists (chol phase only;
                                              // region is reused by k_grad later)

  k_R<<<64, 512, 0, stream>>>(z_gt, ws, seed);
  k_probs<<<C_P * C_D, 64, 0, stream>>>(z0, ws);
  k_sample<<<C_P * C_S, 64, 0, stream>>>(ws);
  k_chol_all<<<NBLK_ALL, 256, 0, stream>>>(Rf, ws + CTAB_OFF,
      (const u64*)(ws + GCOL_OFF), ws + NS_OFF, wl);
  k_logpw<<<C_P, 64, 0, stream>>>(ws + NS_OFF, ws + W_OFF);
  k_grad<<<2 * C_P * C_D + C_P * C_P, 64, 0, stream>>>(ws, z0);
  k_znew<<<(C_P * 8192) / 64, 64, 0, stream>>>(z0, ws, out);
  k_s2col<<<C_P * C_D, 64, 0, stream>>>(ws, out);
  k_chol<true><<<C_P * C_D, 64, 0, stream>>>(Rf, ws + CTAB_OFF,
      (const u64*)(ws + NS_OFF), ws + NS2_OFF);
  k_mlp<<<C_P, 256, 0, stream>>>(ws, out, ws + NS2_OFF,
      ew0, eb0, ew1, eb1, ew2, eb2,
      mw0, mb0, mw1, mb1, lw0, lb0, lw1, lb1,
      dw0, db0, dw1, db1, dw2, db2);
}

// Round 8
// 336.946 us; speedup vs baseline: 1.0820x; 1.0395x over previous
//
#include <hip/hip_runtime.h>
#include <stdint.h>
#include <math.h>

typedef unsigned long long u64;
typedef unsigned int u32;
typedef unsigned short u16;

// ---- problem constants ----
#define C_P 32
#define C_S 16
#define C_D 64
#define C_N 2048

// ---- ws layout (offsets in doubles) ----
#define R_OFF      0        // float[4096]
#define CTAB_OFF   4160     // double[64]
#define KEYS_OFF   4224     // u32[4]
#define PROBS_OFF  4232     // float[131072]
#define GROW_OFF   135304   // u64[32768] row masks
#define GCOL_OFF   168072   // u64[32768] col masks
#define NS_OFF     200840   // double[32768]; later grow2 u64[2048]
#define W_OFF      233608   // double[512]
#define GF_OFF     234120   // float[262144]; chol-phase: tier worklists (u32)
#define KM_OFF     365192   // float[1024]
#define ZN_OFF     365704   // float[262144]
#define NS2_OFF    496776   // double[2048]

// worklist layout (u32 indices into GF region):
//   wl[0..3] = counts tier0(packed m<=32)/1(33-35)/2(36-40)/3(heavy >40)
//   wl[16 + tier*32768 + i] = task ids   (4*32768+16 u32 < 262144 u32 budget)
#define WL_LIST0 16

// merged chol kernel block ranges — HEAVY FIRST, then tiers by descending
// per-wave cost (round-5/6 lesson: longest tasks must start at t=0).
#define HBLK 768
#define TB2 1664    // tier 2: m 36..40 (readlane core, MMAX=40)
#define TB1 2176    // tier 1: m 33..35 (readlane core, MMAX=35)
#define TPK 2048    // tier 0: m<=32 PACKED 2 tasks/wave (ds_bpermute core)
#define E_H  (HBLK)
#define E_2  (E_H + TB2)
#define E_1  (E_2 + TB1)
#define NBLK_ALL (E_1 + TPK)

// ---- out layout (FLOAT32 elements) ----
#define O_REC   0
#define O_LOGP  4096
#define O_QZ    4128
#define O_QMU   6176
#define O_QLV   8224
#define O_GH    10272
#define O_ZN    141344
#define O_TOTAL 403488

__device__ __forceinline__ void tf2x32(u32 k0, u32 k1, u32 x0, u32 x1,
                                       u32& o0, u32& o1) {
  u32 ks2 = k0 ^ k1 ^ 0x1BD11BDAu;
  x0 += k0; x1 += k1;
#define TFR(r) { x0 += x1; x1 = (x1 << r) | (x1 >> (32 - r)); x1 ^= x0; }
  TFR(13) TFR(15) TFR(26) TFR(6)   x0 += k1;  x1 += ks2 + 1u;
  TFR(17) TFR(29) TFR(16) TFR(24)  x0 += ks2; x1 += k0 + 2u;
  TFR(13) TFR(15) TFR(26) TFR(6)   x0 += k0;  x1 += k1 + 3u;
  TFR(17) TFR(29) TFR(16) TFR(24)  x0 += k1;  x1 += ks2 + 4u;
  TFR(13) TFR(15) TFR(26) TFR(6)   x0 += ks2; x1 += k0 + 5u;
#undef TFR
  o0 = x0; o1 = x1;
}

__device__ __forceinline__ double d_erfinv(double x) {
  double w = -log1p(-x * x);
  double p;
  if (w < 5.0) {
    w -= 2.5;
    p = 2.81022636e-08;
    p = 3.43273939e-07  + p * w;
    p = -3.5233877e-06  + p * w;
    p = -4.39150654e-06 + p * w;
    p = 0.00021858087   + p * w;
    p = -0.00125372503  + p * w;
    p = -0.00417768164  + p * w;
    p = 0.246640727     + p * w;
    p = 1.50140941      + p * w;
  } else {
    w = sqrt(w) - 3.0;
    p = -0.000200214257;
    p = 0.000100950558  + p * w;
    p = 0.00134934322   + p * w;
    p = -0.00367342844  + p * w;
    p = 0.00573950773   + p * w;
    p = -0.0076224613   + p * w;
    p = 0.00943887047   + p * w;
    p = 1.00167406      + p * w;
    p = 2.83297682      + p * w;
  }
  return p * x;
}

// Stirling lgamma for large z (z ~ 1026: abs err ~1e-12, plenty for f32 out)
__device__ __forceinline__ double stirl(double z) {
  double zi = 1.0 / z;
  double zi2 = zi * zi;
  double s = (z - 0.5) * log(z) - z + 0.9189385332046727;  // 0.5*ln(2*pi)
  s += zi * (1.0 / 12.0 - zi2 * (1.0 / 360.0 - zi2 * (1.0 / 1260.0)));
  return s;
}

// R (with fused setup on block 0): one pass Sx/Sxx, combine analytically.
// ctab via recurrence ctab[l] = ctab[l-2] + log((2049+l)/(4(1+l))).
__global__ void k_R(const float* x, double* ws, const int* seedp) {
  __shared__ double pS[8][64], pX[8][64];
  __shared__ double xbar[64];
  int j = blockIdx.x, t = threadIdx.x;   // 512 threads
  int i = t & 63, c = t >> 6;
  if (j == 0) {                          // fused k_setup
    if (t < 64) {
      int l = t;
      double term = (l >= 2) ? log((2049.0 + (double)l) / (4.0 * (1.0 + (double)l)))
                             : 0.0;
      double v = term;
#pragma unroll
      for (int off = 2; off <= 32; off <<= 1) {
        double o = __shfl_up(v, off, 64);
        if (l >= off) v += o;
      }
      const double LOG_HALF = -0.6931471805599453;
      double c0 = -0.5 * log(2049.0)
                - 1024.0 * log(3.14159265358979323846);
      double seed = (l & 1)
        ? c0 + stirl(1026.0) + 2.5 * LOG_HALF                       // -lgamma(2)=0
        : c0 + stirl(1025.5) + 0.12078223763524522235 + 1.5 * LOG_HALF; // -lgamma(1.5)
      ws[CTAB_OFF + l] = seed + v;
    }
    if (t < 8) ((u32*)(ws + GF_OFF))[t] = 0;   // zero worklist counters
    if (t == 0) {
      u32 kk0 = 0u, kk1 = (u32)seedp[0];
      u32 a0, a1, s0, s1, r0, r1, d0, d1;
      tf2x32(kk0, kk1, 0u, 0u, a0, a1);
      tf2x32(kk0, kk1, 0u, 1u, s0, s1);   // sk (bernoulli)
      tf2x32(a0, a1, 0u, 0u, d0, d1); (void)d0; (void)d1;
      tf2x32(a0, a1, 0u, 1u, r0, r1);     // rk (normal eps)
      u32* keys = (u32*)(ws + KEYS_OFF);
      keys[0] = s0; keys[1] = s1; keys[2] = r0; keys[3] = r1;
    }
  }
  double sx = 0.0, sxx = 0.0;
  for (int n = c * 256; n < (c + 1) * 256; n++) {
    double xi = (double)x[n * 64 + i];
    double xj = (double)x[n * 64 + j];
    sx += xi; sxx += xi * xj;
  }
  pS[c][i] = sx; pX[c][i] = sxx;
  __syncthreads();
  if (t < 64) {
    double S = 0.0, X = 0.0;
    for (int cc = 0; cc < 8; cc++) { S += pS[cc][i]; X += pX[cc][i]; }
    xbar[i] = S / 2048.0;
    pX[0][i] = X;
  }
  __syncthreads();
  if (t < 64) {
    double xbi = xbar[i], xbj = xbar[j];
    double s = pX[0][i] - 2048.0 * xbi * xbj + (2048.0 / 2049.0) * xbi * xbj;
    if (i == j) s += 0.5;
    ((float*)(ws + R_OFF))[i * 64 + j] = (float)s;
  }
}

// probs[p,i,j] = sigmoid(alpha * u_i . v_j) * (i!=j), stored f32
__global__ __launch_bounds__(64) void k_probs(const float* z, double* ws) {
  float* probs = (float*)(ws + PROBS_OFF);
  int b = blockIdx.x; int p = b >> 6, i = b & 63;
  int j = threadIdx.x;
  __shared__ float V[64 * 65];
  __shared__ float us[64];
  int k = j;
  us[k] = z[((p * 64 + i) * 64 + k) * 2 + 0];
  for (int jj = 0; jj < 64; jj++)
    V[jj * 65 + k] = z[((p * 64 + jj) * 64 + k) * 2 + 1];
  __syncthreads();
  float s = 0.f;
  for (int kk = 0; kk < 64; kk++)
    s += us[kk] * V[j * 65 + kk];
  float pr = (i == j) ? 0.f : 1.f / (1.f + expf(-0.2f * s));
  probs[(p * 64 + i) * 64 + j] = pr;
}

// sample graphs AND bucket tasks into the 4 chol tiers (wave-aggregated
// atomics: one atomicAdd per wave per tier).
__global__ void k_sample(double* ws) {
  const float* probs = (const float*)(ws + PROBS_OFF);
  const u32* keys = (const u32*)(ws + KEYS_OFF);
  u64* grow = (u64*)(ws + GROW_OFF);
  u64* gcol = (u64*)(ws + GCOL_OFF);
  u32* wl = (u32*)(ws + GF_OFF);
  int ps = blockIdx.x;
  int p = ps >> 4;
  int j = threadIdx.x;
  u32 k0 = keys[0], k1 = keys[1];
  u64 colmask = 0;
  for (int i = 0; i < 64; i++) {
    u32 lin = (u32)(ps * 4096 + i * 64 + j);
    u32 o0, o1; tf2x32(k0, k1, 0u, lin, o0, o1);
    u32 bits = o0 ^ o1;
    float f = __uint_as_float((bits >> 9) | 0x3f800000u) - 1.0f;
    bool bit = (f < probs[(p * 64 + i) * 64 + j]);
    u64 rm = __ballot(bit);
    if (j == 0) grow[ps * 64 + i] = rm;
    if (bit) colmask |= (1ull << i);
  }
  gcol[ps * 64 + j] = colmask;
  // tier bucketing: task (ps, col j), m = popc+1
  int m = (int)__popcll(colmask) + 1;
  int tier = (m <= 32) ? 0 : (m <= 35) ? 1 : (m <= 40) ? 2 : 3;
#pragma unroll
  for (int t = 0; t < 4; t++) {
    u64 b = __ballot(tier == t);
    if (tier == t) {
      int leader = (int)__builtin_ctzll(b);
      u32 off = (u32)__popcll(b & ((1ull << j) - 1ull));
      u32 base = 0;
      if (j == leader) base = atomicAdd(&wl[t], (u32)__popcll(b));
      base = (u32)__shfl((int)base, leader, 64);
      wl[WL_LIST0 + t * 32768 + base + off] = (u32)(ps * 64 + j);
    }
  }
}

__device__ __forceinline__ float rdlane(float x, int l) {
  return __uint_as_float(__builtin_amdgcn_readlane(__float_as_uint(x), (u32)l));
}

// DS-pipe broadcast via ds_bpermute (runtime byte address allowed, unlike
// ds_swizzle whose pattern must be an ICE — round-7 compile failure).
// Source lane = addr>>2. For a per-half broadcast of lane b: addr =
// ((lane&32)<<2) + (b<<2); after unroll, b<<2 is an immediate the backend
// folds into the DS offset field (no extra VALU).
__device__ __forceinline__ float bperm(int byteaddr, float x) {
  return __uint_as_float(__builtin_amdgcn_ds_bpermute(byteaddr, __float_as_uint(x)));
}

// PACKED tier (m<=32, ~50% of tasks): TWO tasks per wave, task A on lanes
// 0-31, task B on lanes 32-63. Symmetric-Schur invariant per half:
// v[c] = A_task[lane&31][c]. The rank-1 update's row broadcast A[k][b]
// (= lane b's v[k], by symmetry) comes from a ds_bpermute per-half
// broadcast on the DS pipe — frees the VALU (round-6: VALUBusy 90%, DS
// idle). k-loop runs a fixed 32 steps unguarded: for k >= m_half the
// update only corrupts never-read garbage slots; each lane's pivot is
// captured at k = l5 < m_half, before any corruption.
__device__ __forceinline__ void packed_body(const float* Rf, const double* ctab,
                                            const u64* masks, double* nodescore,
                                            const u32* wl, u32 brel, u32 nb,
                                            int (*idx)[2][32]) {
  int w = threadIdx.x >> 6;
  int lane = threadIdx.x & 63;
  int half = lane >> 5, l5 = lane & 31;
  int ab = (lane & 32) << 2;               // per-half bpermute base address
  u32 cnt = wl[0];
  const u32* list = wl + WL_LIST0;         // tier 0 list
  u32 npair = (cnt + 1) >> 1;
  for (u32 ti = brel * 4 + (u32)w; ti < npair; ti += nb * 4) {
    u32 iA = 2 * ti, iB = iA + 1;
    bool hasB = (iB < cnt);
    int task = (int)list[(half && hasB) ? iB : iA];  // dup A if odd tail
    int j = task & 63;
    u64 mask = masks[task];
    int P = (int)__popcll(mask);
    int m = P + 1;                          // <= 32
    idx[w][half][l5] = 0;                   // sanitize (dead slots -> row 0)
    __builtin_amdgcn_wave_barrier();
    {
      u64 below = mask & ((1ull << l5) - 1ull);
      if ((mask >> l5) & 1ull) idx[w][half][(int)__popcll(below)] = l5;
      int b2 = l5 + 32;
      u64 below2 = mask & ((1ull << b2) - 1ull);
      if ((mask >> b2) & 1ull) idx[w][half][(int)__popcll(below2)] = b2;
      if (l5 == 0) idx[w][half][P] = j;
    }
    __builtin_amdgcn_wave_barrier();
    int myrow = idx[w][half][l5];
    float v[32];
#pragma unroll
    for (int c = 0; c < 32; c++)
      v[c] = Rf[idx[w][half][c] * 64 + myrow];   // A[l5][c] via symmetry
    float mypiv = 1.0f;
#pragma unroll
    for (int k = 0; k < 32; k++) {
      float dk = bperm(ab + (k << 2), v[k]);     // per-half pivot broadcast
      mypiv = (l5 == k) ? dk : mypiv;
      float ns = -v[k] * __builtin_amdgcn_rcpf(dk);
#pragma unroll
      for (int b = k + 1; b < 32; b++)
        v[b] += ns * bperm(ab + (b << 2), v[k]); // A[k][b] via symmetry, DS pipe
    }
    // lastd: pivot d_{m-1} of my half = mypiv on lane half*32+P (runtime idx)
    float lastd = bperm(ab + (P << 2), mypiv);
    float lv = (l5 < m) ? __logf(mypiv) : 0.f;
#pragma unroll
    for (int off = 16; off > 0; off >>= 1) lv += __shfl_down(lv, off, 32);
    if (l5 == 0 && (half == 0 || hasB)) {
      double l = (double)P;
      nodescore[task] = ctab[P]
                      - 0.5 * (2050.0 + l) * (double)__logf(lastd)
                      - 0.5 * (double)lv;
    }
    __builtin_amdgcn_wave_barrier();            // order idx reuse across iters
  }
}

// Per-wave register LDL for one unpacked tier (m 33..40). Direct global
// loads via R symmetry; readlane broadcast; f32 __logf epilogue.
template<int MMAX>
__device__ __forceinline__ void tier_body(const float* Rf, const double* ctab,
                                          const u64* masks, double* nodescore,
                                          const u32* wl, int tier,
                                          u32 brel, u32 nb, int (*idx)[64]) {
  int w = threadIdx.x >> 6;
  int lane = threadIdx.x & 63;
  u32 cnt = wl[tier];
  const u32* list = wl + WL_LIST0 + tier * 32768;
  for (u32 ti = brel * 4 + (u32)w; ti < cnt; ti += nb * 4) {
    int task = (int)list[ti];
    int j = task & 63;
    u64 mask = masks[task];
    int P = (int)__popcll(mask);
    int m = P + 1;
    idx[w][lane] = 0;                       // sanitize (dead slots -> row 0)
    __builtin_amdgcn_wave_barrier();
    u64 below = mask & ((1ull << lane) - 1ull);
    if ((mask >> lane) & 1ull) idx[w][(int)__popcll(below)] = lane;
    if (lane == 0) idx[w][P] = j;
    __builtin_amdgcn_wave_barrier();
    int myrow = idx[w][lane];               // my node id (0 for dead lanes)
    float v[MMAX];
#pragma unroll
    for (int c = 0; c < MMAX; c++)
      v[c] = Rf[idx[w][c] * 64 + myrow];    // A[lane][c] via symmetry
    float mypiv = 1.0f;
#pragma unroll
    for (int k = 0; k < MMAX; k++) {
      if (k < m) {                          // uniform guard (keeps full unroll)
        float dk = rdlane(v[k], k);
        if (lane == k) mypiv = dk;
        float ns = -v[k] * __builtin_amdgcn_rcpf(dk);
#pragma unroll
        for (int b = k + 1; b < MMAX; b++)
          v[b] += ns * rdlane(v[k], b);     // garbage slots never read back
      }
    }
    float lastd = __shfl(mypiv, P, 64);     // final pivot d_{m-1} (lane P)
    float lv = (lane < m) ? __logf(mypiv) : 0.f;
    for (int off = 32; off > 0; off >>= 1) lv += __shfl_down(lv, off, 64);
    if (lane == 0) {
      double l = (double)P;
      nodescore[task] = ctab[P]
                      - 0.5 * (2050.0 + l) * (double)__logf(lastd)
                      - 0.5 * (double)lv;
    }
    __builtin_amdgcn_wave_barrier();        // order idx reuse across iterations
  }
}

#define WB() __builtin_amdgcn_wave_barrier()

// Heavy path (m>40, ~1%): wave 0 of the block only; full hybrid path with
// LDS triangle.
__device__ void heavy_body(const float* Rf, const double* ctab,
                           const u64* masks, double* nodescore,
                           const u32* wl, u32 brel, u32 nb,
                           float* T, int* idx) {
  if (threadIdx.x >= 64) return;
  int lane = threadIdx.x;
  u32 cnt = wl[3];
  const u32* list = wl + WL_LIST0 + 3 * 32768;
  for (u32 ii = brel; ii < cnt; ii += nb) {
    WB();
    int task = (int)list[ii];
    int j = task & 63;
    u64 mask = masks[task];
    int P = (int)__popcll(mask);
    int m = P + 1;
    u64 below = mask & ((1ull << lane) - 1ull);
    if ((mask >> lane) & 1ull) idx[(int)__popcll(below)] = lane;
    if (lane == 0) idx[P] = j;
    WB();
    int trLane = (lane * (lane + 1)) >> 1;
    if (lane < m) {
      int cidx = idx[lane];
      int tr = 0;
      for (int r = 0; r < m; r++) {
        if (lane <= r) T[tr + lane] = Rf[idx[r] * 64 + cidx];
        tr += r + 1;
      }
    }
    WB();
    float mypiv = 1.0f, lastd = 1.0f;
    float v[40];
#pragma unroll
    for (int c = 0; c < 40; c++)
      v[c] = T[trLane + c];
#pragma unroll
    for (int k = 0; k < 40; k++) {
      if (k < m) {
        float dk = rdlane(v[k], k);
        if (lane == k) mypiv = dk;
        lastd = dk;
        float ns = -v[k] * __builtin_amdgcn_rcpf(dk);
#pragma unroll
        for (int b = k + 1; b < 40; b++)
          v[b] += ns * rdlane(v[k], b);
      }
    }
    if (m > 40) {
      for (int b = 40; b < m; b++) {
        float acc = 0.f;
#pragma unroll
        for (int k = 0; k < 40; k++) {
          float dk = rdlane(v[k], k);
          float abk = rdlane(v[k], b);
          acc += v[k] * abk * __builtin_amdgcn_rcpf(dk);
        }
        if (lane >= b) T[trLane + b] -= acc;
      }
      WB();
      for (int k = 40; k < m; k++) {
        float dk = T[((k * (k + 1)) >> 1) + k];
        if (lane == k) mypiv = dk;
        lastd = dk;
        float sk = T[trLane + k] * __builtin_amdgcn_rcpf(dk);
        for (int b = k + 1; b < m; b++) {
          float abk = T[((b * (b + 1)) >> 1) + k];
          if (lane >= b) T[trLane + b] -= sk * abk;
        }
        WB();
      }
    }
    double vv = (lane < m) ? log((double)mypiv) : 0.0;
    for (int off = 32; off > 0; off >>= 1) vv += __shfl_down(vv, off, 64);
    if (lane == 0) {
      double logB = vv;
      double logA = logB - log((double)lastd);
      double l = (double)P;
      nodescore[task] = ctab[P]
                      + 0.5 * (2050.0 + l) * logA
                      - 0.5 * (2051.0 + l) * logB;
    }
  }
}

// ONE launch for all 32768 sampled-graph cholesky tasks. Heavy first, then
// descending per-wave cost. No min-waves launch_bounds cap (round-1 lesson).
__global__ __launch_bounds__(256) void k_chol_all(const float* Rf, const double* ctab,
                                                  const u64* masks, double* nodescore,
                                                  const u32* wl) {
  __shared__ int idx4[4][64];
  __shared__ int idxp[4][2][32];
  __shared__ float T[2080];
  __shared__ int idxh[64];
  u32 b = blockIdx.x;
  if (b < E_H)      heavy_body(Rf, ctab, masks, nodescore, wl, b, HBLK, T, idxh);
  else if (b < E_2) tier_body<40>(Rf, ctab, masks, nodescore, wl, 2, b - E_H, TB2, idx4);
  else if (b < E_1) tier_body<35>(Rf, ctab, masks, nodescore, wl, 1, b - E_2, TB1, idx4);
  else              packed_body(Rf, ctab, masks, nodescore, wl, b - E_1, TPK, idxp);
}

// Merged hybrid f32 LDL Cholesky (transpose variant for the 2048 hard-graph
// tasks). UNCHANGED and kept f64: its scores feed the log_p OUTPUT, where
// absmax is already at 1 f32 ulp of |logp|~4000.
template<bool TRANSPOSE>
__global__ __launch_bounds__(64) void k_chol(const float* Rf, const double* ctab,
                                             const u64* masks, double* nodescore) {
  __shared__ float T[2080];
  __shared__ int idx[64];
  int task = blockIdx.x;
  int j = task & 63;
  int lane = threadIdx.x;
  u64 mask;
  if (TRANSPOSE) {
    int p = task >> 6;
    u64 rm = masks[p * 64 + lane];       // row mask of row `lane`
    mask = __ballot((rm >> j) & 1ull);   // column j mask
  } else {
    mask = masks[task];
  }
  int P = (int)__popcll(mask);
  int m = P + 1;
  u64 below = mask & ((1ull << lane) - 1ull);
  if ((mask >> lane) & 1ull) idx[(int)__popcll(below)] = lane;
  if (lane == 0) idx[P] = j;
  __syncthreads();
  int trLane = (lane * (lane + 1)) >> 1;
  if (lane < m) {
    int cidx = idx[lane];
    int tr = 0;
    for (int r = 0; r < m; r++) {
      if (lane <= r) T[tr + lane] = Rf[idx[r] * 64 + cidx];
      tr += r + 1;
    }
  }
  __syncthreads();
  float mypiv = 1.0f, lastd = 1.0f;
  float v[40];
#pragma unroll
  for (int c = 0; c < 40; c++)
    v[c] = T[trLane + c];                // in-bounds garbage for c>lane
#pragma unroll
  for (int k = 0; k < 40; k++) {
    if (k < m) {                         // uniform guard (keeps full unroll)
      float dk = rdlane(v[k], k);
      if (lane == k) mypiv = dk;
      lastd = dk;
      float ns = -v[k] * __builtin_amdgcn_rcpf(dk);
#pragma unroll
      for (int b = k + 1; b < 40; b++)
        v[b] += ns * rdlane(v[k], b);    // garbage slots harmless
    }
  }
  if (m > 40) {                          // heavy tasks only (block-uniform)
    for (int b = 40; b < m; b++) {
      float acc = 0.f;
#pragma unroll
      for (int k = 0; k < 40; k++) {
        float dk = rdlane(v[k], k);                  // final pivot k
        float abk = rdlane(v[k], b);                 // final A[b][k]
        acc += v[k] * abk * __builtin_amdgcn_rcpf(dk);
      }
      if (lane >= b) T[trLane + b] -= acc;           // own-row, no conflict
    }
    __syncthreads();
    for (int k = 40; k < m; k++) {
      float dk = T[((k * (k + 1)) >> 1) + k];        // broadcast
      if (lane == k) mypiv = dk;
      lastd = dk;
      float sk = T[trLane + k] * __builtin_amdgcn_rcpf(dk);
      for (int b = k + 1; b < m; b++) {
        float abk = T[((b * (b + 1)) >> 1) + k];     // broadcast
        if (lane >= b) T[trLane + b] -= sk * abk;
      }
      __syncthreads();
    }
  }
  double vv = (lane < m) ? log((double)mypiv) : 0.0;
  for (int off = 32; off > 0; off >>= 1) vv += __shfl_down(vv, off, 64);
  if (lane == 0) {
    double logB = vv;
    double logA = logB - log((double)lastd);
    double l = (double)P;
    nodescore[task] = ctab[P]
                    + 0.5 * (2050.0 + l) * logA
                    - 0.5 * (2051.0 + l) * logB;
  }
}

__global__ void k_logpw(const double* ns, double* w) {
  int p = blockIdx.x, t = threadIdx.x;
  __shared__ double part[64];
  int s = t & 15, c = t >> 4;            // 4 chunks x 16 samples
  double acc = 0.0;
  for (int j = c * 16; j < (c + 1) * 16; j++)
    acc += ns[(p * 16 + s) * 64 + j];
  part[t] = acc;
  __syncthreads();
  if (t < 16) part[t] = part[t] + part[t + 16] + part[t + 32] + part[t + 48];
  __syncthreads();
  if (t == 0) {
    double m = part[0];
    for (int s2 = 1; s2 < 16; s2++) m = fmax(m, part[s2]);
    double e[16], sum = 0.0;
    for (int s2 = 0; s2 < 16; s2++) { e[s2] = exp(part[s2] - m); sum += e[s2]; }
    for (int s2 = 0; s2 < 16; s2++) w[p * 16 + s2] = e[s2] / sum;
  }
}

// fused A-construction + grad dot + kmat.
// blocks 0..2047: grad_u; 2048..4095: grad_v; 4096..5119: Kmat (z0-only).
__global__ void k_grad(double* ws, const float* z) {
  const float* probs = (const float*)(ws + PROBS_OFF);
  const double* w = ws + W_OFF;
  const u64* grow = (const u64*)(ws + GROW_OFF);
  const u64* gcol = (const u64*)(ws + GCOL_OFF);
  float* gf = (float*)(ws + GF_OFF);
  const float LOGIT = -2.6903717578966254f;  // log(4/63)-log1p(-4/63)
  int bb = blockIdx.x;
  int k = threadIdx.x;
  __shared__ float acc[64];
  if (bb < 2048) {
    int p = bb >> 6, i = bb & 63;
    float gb = 0.f, wsum = 0.f;
    for (int s = 0; s < 16; s++) {
      float wv = (float)w[p * 16 + s];
      wsum += wv;
      gb += wv * (float)((grow[(p * 16 + s) * 64 + i] >> k) & 1ull);
    }
    float pr = probs[(p * 64 + i) * 64 + k];   // coalesced
    float od = (i == k) ? 0.f : 1.f;
    acc[k] = (0.2f * (gb - pr * wsum) + 0.2f * pr * (1.f - pr) * LOGIT) * od;
    __syncthreads();
    float s = 0.f;
    for (int j = 0; j < 64; j++)
      s += acc[j] * z[((p * 64 + j) * 64 + k) * 2 + 1];
    s -= 64.f * z[((p * 64 + i) * 64 + k) * 2 + 0];
    gf[p * 8192 + (i * 64 + k) * 2 + 0] = s;
  } else if (bb < 4096) {
    int b = bb - 2048;
    int p = b >> 6, j = b & 63;
    float gb = 0.f, wsum = 0.f;
    for (int s = 0; s < 16; s++) {
      float wv = (float)w[p * 16 + s];
      wsum += wv;
      gb += wv * (float)((gcol[(p * 16 + s) * 64 + j] >> k) & 1ull);
    }
    float pr = probs[(p * 64 + k) * 64 + j];   // one 64-lane gather
    float od = (k == j) ? 0.f : 1.f;
    acc[k] = (0.2f * (gb - pr * wsum) + 0.2f * pr * (1.f - pr) * LOGIT) * od;
    __syncthreads();
    float s = 0.f;
    for (int i = 0; i < 64; i++)
      s += acc[i] * z[((p * 64 + i) * 64 + k) * 2 + 0];
    s -= 64.f * z[((p * 64 + j) * 64 + k) * 2 + 1];
    gf[p * 8192 + (j * 64 + k) * 2 + 1] = s;
  } else {
    float* Km = (float*)(ws + KM_OFF);
    int b = bb - 4096;
    int a = b >> 5, b2 = b & 31;
    float accf = 0.f;
    for (int d0 = k; d0 < 8192; d0 += 64) {
      float diff = z[a * 8192 + d0] - z[b2 * 8192 + d0];
      accf += diff * diff;
    }
    for (int off = 32; off > 0; off >>= 1) accf += __shfl_down(accf, off, 64);
    if (k == 0) Km[a * 32 + b2] = expf(-accf / 5.0f);
  }
}

__global__ void k_znew(const float* z, double* ws, float* out) {
  const float* Km = (const float*)(ws + KM_OFF);
  const float* gf = (const float*)(ws + GF_OFF);
  float* zn = (float*)(ws + ZN_OFF);
  int gid = blockIdx.x * 64 + threadIdx.x;
  int p = gid >> 13, t = gid & 8191;
  float zp = z[p * 8192 + t];
  float accg = 0.f, accz = 0.f, ks = 0.f;
  for (int b = 0; b < 32; b++) {
    float kv = Km[p * 32 + b];
    accg += kv * gf[b * 8192 + t];
    accz += kv * z[b * 8192 + t];
    ks += kv;
  }
  float rep = -0.4f * (accz - zp * ks);
  float v = zp + 0.005f * ((accg + rep) / 32.f);
  zn[p * 8192 + t] = v;
  out[O_ZN + p * 8192 + t] = v;
}

__global__ __launch_bounds__(64) void k_s2col(double* ws, float* out) {
  const float* zn = (const float*)(ws + ZN_OFF);
  u64* grow2 = (u64*)(ws + NS_OFF);
  int b = blockIdx.x; int p = b >> 6, i = b & 63;
  int j = threadIdx.x;
  __shared__ float V[64 * 65];
  __shared__ float us[64];
  int k = j;
  us[k] = zn[p * 8192 + (i * 64 + k) * 2 + 0];
  for (int jj = 0; jj < 64; jj++)
    V[jj * 65 + k] = zn[p * 8192 + (jj * 64 + k) * 2 + 1];
  __syncthreads();
  float s = 0.f;
  for (int kk = 0; kk < 64; kk++)
    s += us[kk] * V[j * 65 + kk];
  bool bit = (i != j) && (s > 0.0f);
  out[O_GH + (p * 64 + i) * 64 + j] = bit ? 1.0f : 0.0f;
  u64 m = __ballot(bit);
  if (j == 0) grow2[p * 64 + i] = m;    // row masks; k_chol<true> transposes
}

// encoder/decoder MLP; also writes log_p (fused reduction).
__global__ __launch_bounds__(256) void k_mlp(double* ws, float* out, const double* ns2,
    const float* ew0, const float* eb0, const float* ew1, const float* eb1,
    const float* ew2, const float* eb2,
    const float* mw0, const float* mb0, const float* mw1, const float* mb1,
    const float* lw0, const float* lb0, const float* lw1, const float* lb1,
    const float* dw0, const float* db0, const float* dw1, const float* db1,
    const float* dw2, const float* db2) {
  int p = blockIdx.x, t = threadIdx.x;
  int w = t >> 6, lane = t & 63;
  const u64* grow2 = (const u64*)(ws + NS_OFF);
  const u32* keys = (const u32*)(ws + KEYS_OFF);
  __shared__ float pt[4][64];
  __shared__ float e0p[4][20];
  __shared__ float h0[20], h1[64], h2[64], hm[64], hl[64];
  __shared__ float qmu[64], qlv[64], qz[64], h3[10], h4[128];

  // ---- logp reduction (wave 0) ----
  if (w == 0) {
    double vv = ns2[p * 64 + lane];
    for (int off = 32; off > 0; off >>= 1) vv += __shfl_down(vv, off, 64);
    if (lane == 0) out[O_LOGP + p] = (float)vv;
  }

  // ---- e0: h0[20] = relu(eb0 + sum over set bits of ew0 rows) ----
  {
    int i = t >> 2;
    int jb = (t & 3) * 16;
    u32 m16 = (u32)((grow2[p * 64 + i] >> jb) & 0xFFFFull);
    float acc[20];
#pragma unroll
    for (int o = 0; o < 20; o++) acc[o] = 0.f;
    const float4* wb = (const float4*)(ew0 + (size_t)(t * 16) * 20);
#pragma unroll
    for (int q = 0; q < 16; q++) {
      float mq = (float)((m16 >> q) & 1u);
      float4 r0 = wb[q * 5 + 0], r1 = wb[q * 5 + 1], r2 = wb[q * 5 + 2];
      float4 r3 = wb[q * 5 + 3], r4 = wb[q * 5 + 4];
      acc[0]  += mq * r0.x; acc[1]  += mq * r0.y; acc[2]  += mq * r0.z; acc[3]  += mq * r0.w;
      acc[4]  += mq * r1.x; acc[5]  += mq * r1.y; acc[6]  += mq * r1.z; acc[7]  += mq * r1.w;
      acc[8]  += mq * r2.x; acc[9]  += mq * r2.y; acc[10] += mq * r2.z; acc[11] += mq * r2.w;
      acc[12] += mq * r3.x; acc[13] += mq * r3.y; acc[14] += mq * r3.z; acc[15] += mq * r3.w;
      acc[16] += mq * r4.x; acc[17] += mq * r4.y; acc[18] += mq * r4.z; acc[19] += mq * r4.w;
    }
#pragma unroll
    for (int o = 0; o < 20; o++) {
      float v = acc[o];
      for (int off = 32; off > 0; off >>= 1) v += __shfl_down(v, off, 64);
      if (lane == 0) e0p[w][o] = v;
    }
  }
  __syncthreads();
  if (t < 20)
    h0[t] = fmaxf(eb0[t] + e0p[0][t] + e0p[1][t] + e0p[2][t] + e0p[3][t], 0.f);
  __syncthreads();

  // ---- h1[64] = relu(eb1 + h0 @ ew1), fan-in 20 split 5/wave ----
  {
    float s = 0.f;
#pragma unroll
    for (int q = 0; q < 5; q++) s += h0[w * 5 + q] * ew1[(w * 5 + q) * 64 + lane];
    pt[w][lane] = s;
  }
  __syncthreads();
  if (w == 0)
    h1[lane] = fmaxf(eb1[lane] + pt[0][lane] + pt[1][lane] + pt[2][lane] + pt[3][lane], 0.f);
  __syncthreads();

  // ---- h2[64] = relu(eb2 + h1 @ ew2), fan-in 64 split 16/wave ----
  {
    float s = 0.f;
#pragma unroll
    for (int q = 0; q < 16; q++) s += h1[w * 16 + q] * ew2[(w * 16 + q) * 64 + lane];
    pt[w][lane] = s;
  }
  __syncthreads();
  if (w == 0)
    h2[lane] = fmaxf(eb2[lane] + pt[0][lane] + pt[1][lane] + pt[2][lane] + pt[3][lane], 0.f);
  __syncthreads();

  // ---- hm/hl in parallel: waves 0,1 -> hm; waves 2,3 -> hl ----
  {
    const float* W = (w < 2) ? mw0 : lw0;
    int qb = (w & 1) * 32;
    float s = 0.f;
#pragma unroll
    for (int q = 0; q < 32; q++) s += h2[qb + q] * W[(qb + q) * 64 + lane];
    pt[w][lane] = s;
  }
  __syncthreads();
  if (w == 0) hm[lane] = fmaxf(mb0[lane] + pt[0][lane] + pt[1][lane], 0.f);
  if (w == 1) hl[lane] = fmaxf(lb0[lane] + pt[2][lane] + pt[3][lane], 0.f);
  __syncthreads();

  // ---- qmu/qlv in parallel (no relu) ----
  {
    const float* W = (w < 2) ? mw1 : lw1;
    const float* src = (w < 2) ? hm : hl;
    int qb = (w & 1) * 32;
    float s = 0.f;
#pragma unroll
    for (int q = 0; q < 32; q++) s += src[qb + q] * W[(qb + q) * 64 + lane];
    pt[w][lane] = s;
  }
  __syncthreads();
  if (w == 0) qmu[lane] = mb1[lane] + pt[0][lane] + pt[1][lane];
  if (w == 1) qlv[lane] = lb1[lane] + pt[2][lane] + pt[3][lane];
  __syncthreads();

  // ---- reparameterize (wave 0) + output qz/qmu/qlv ----
  if (w == 0) {
    u32 o0, o1;
    tf2x32(keys[2], keys[3], 0u, (u32)(p * 64 + lane), o0, o1);
    u32 bits = o0 ^ o1;
    float f = __uint_as_float((bits >> 9) | 0x3f800000u) - 1.0f;
    float LOF = __uint_as_float(0xBF7FFFFFu);
    float uu = fmaxf(LOF, f * 2.0f + LOF);
    float eps = (float)(1.4142135623730951 * d_erfinv((double)uu));
    float qzv = qmu[lane] + eps * expf(0.5f * qlv[lane]);
    qz[lane] = qzv;
    out[O_QZ  + p * 64 + lane] = qzv;
    out[O_QMU + p * 64 + lane] = qmu[lane];
    out[O_QLV + p * 64 + lane] = qlv[lane];
  }
  __syncthreads();

  // ---- d0: h3[10] = relu(db0 + qz @ dw0), fan-in 64 split 16/wave ----
  {
    float s = 0.f;
    if (lane < 10) {
#pragma unroll
      for (int q = 0; q < 16; q++) s += qz[w * 16 + q] * dw0[(w * 16 + q) * 10 + lane];
    }
    pt[w][lane] = s;
  }
  __syncthreads();
  if (w == 0 && lane < 10)
    h3[lane] = fmaxf(db0[lane] + pt[0][lane] + pt[1][lane] + pt[2][lane] + pt[3][lane], 0.f);
  __syncthreads();

  // ---- d1: h4[128] = relu(db1 + h3 @ dw1) ----
  {
    int o = (w >> 1) * 64 + lane;
    int qb = (w & 1) * 5;
    float s = 0.f;
#pragma unroll
    for (int q = 0; q < 5; q++) s += h3[qb + q] * dw1[(qb + q) * 128 + o];
    pt[w][lane] = s;
  }
  __syncthreads();
  if (w == 0) h4[lane]      = fmaxf(db1[lane]      + pt[0][lane] + pt[1][lane], 0.f);
  if (w == 1) h4[64 + lane] = fmaxf(db1[64 + lane] + pt[2][lane] + pt[3][lane], 0.f);
  __syncthreads();

  // ---- d2: recons[128] = db2 + h4 @ dw2 ----
  {
    int o = (w >> 1) * 64 + lane;
    int qb = (w & 1) * 64;
    float s = 0.f;
#pragma unroll
    for (int q = 0; q < 64; q++) s += h4[qb + q] * dw2[(qb + q) * 128 + o];
    pt[w][lane] = s;
  }
  __syncthreads();
  if (w == 0) out[O_REC + p * 128 + lane]      = db2[lane]      + pt[0][lane] + pt[1][lane];
  if (w == 1) out[O_REC + p * 128 + 64 + lane] = db2[64 + lane] + pt[2][lane] + pt[3][lane];
}

extern "C" void kernel_launch(void* const* d_in, const int* in_sizes, int n_in,
                              void* d_out, int out_size, void* d_ws, size_t ws_size,
                              hipStream_t stream) {
  (void)in_sizes; (void)n_in; (void)out_size; (void)ws_size;
  const float* z_gt = (const float*)d_in[0];
  const float* z0   = (const float*)d_in[1];
  const float* ew0 = (const float*)d_in[2];  const float* eb0 = (const float*)d_in[3];
  const float* ew1 = (const float*)d_in[4];  const float* eb1 = (const float*)d_in[5];
  const float* ew2 = (const float*)d_in[6];  const float* eb2 = (const float*)d_in[7];
  const float* mw0 = (const float*)d_in[8];  const float* mb0 = (const float*)d_in[9];
  const float* mw1 = (const float*)d_in[10]; const float* mb1 = (const float*)d_in[11];
  const float* lw0 = (const float*)d_in[12]; const float* lb0 = (const float*)d_in[13];
  const float* lw1 = (const float*)d_in[14]; const float* lb1 = (const float*)d_in[15];
  const float* dw0 = (const float*)d_in[16]; const float* db0 = (const float*)d_in[17];
  const float* dw1 = (const float*)d_in[18]; const float* db1 = (const float*)d_in[19];
  const float* dw2 = (const float*)d_in[20]; const float* db2 = (const float*)d_in[21];
  const int* seed = (const int*)d_in[22];
  double* ws = (double*)d_ws;
  float* out = (float*)d_out;
  const float* Rf = (const float*)(ws + R_OFF);
  const u32* wl = (const u32*)(ws + GF_OFF);  // tier worklists (chol phase only;
                                              // region is reused by k_grad later)

  k_R<<<64, 512, 0, stream>>>(z_gt, ws, seed);
  k_probs<<<C_P * C_D, 64, 0, stream>>>(z0, ws);
  k_sample<<<C_P * C_S, 64, 0, stream>>>(ws);
  k_chol_all<<<NBLK_ALL, 256, 0, stream>>>(Rf, ws + CTAB_OFF,
      (const u64*)(ws + GCOL_OFF), ws + NS_OFF, wl);
  k_logpw<<<C_P, 64, 0, stream>>>(ws + NS_OFF, ws + W_OFF);
  k_grad<<<2 * C_P * C_D + C_P * C_P, 64, 0, stream>>>(ws, z0);
  k_znew<<<(C_P * 8192) / 64, 64, 0, stream>>>(z0, ws, out);
  k_s2col<<<C_P * C_D, 64, 0, stream>>>(ws, out);
  k_chol<true><<<C_P * C_D, 64, 0, stream>>>(Rf, ws + CTAB_OFF,
      (const u64*)(ws + NS_OFF), ws + NS2_OFF);
  k_mlp<<<C_P, 256, 0, stream>>>(ws, out, ws + NS2_OFF,
      ew0, eb0, ew1, eb1, ew2, eb2,
      mw0, mb0, mw1, mb1, lw0, lb0, lw1, lb1,
      dw0, db0, dw1, db1, dw2, db2);
}

// Round 9
// 336.483 us; speedup vs baseline: 1.0835x; 1.0014x over previous
//
#include <hip/hip_runtime.h>
#include <stdint.h>
#include <math.h>

typedef unsigned long long u64;
typedef unsigned int u32;
typedef unsigned short u16;

// ---- problem constants ----
#define C_P 32
#define C_S 16
#define C_D 64
#define C_N 2048

// ---- ws layout (offsets in doubles) ----
#define R_OFF      0        // float[4096]
#define CTAB_OFF   4160     // double[64]
#define KEYS_OFF   4224     // u32[4]
#define PROBS_OFF  4232     // float[131072]
#define GROW_OFF   135304   // u64[32768] row masks
#define GCOL_OFF   168072   // u64[32768] col masks
#define NS_OFF     200840   // double[32768]; later grow2 u64[2048]
#define W_OFF      233608   // double[512]
#define GF_OFF     234120   // float[262144]; chol-phase: tier worklists (u32)
#define KM_OFF     365192   // float[1024]
#define ZN_OFF     365704   // float[262144]
#define NS2_OFF    496776   // double[2048]

// worklist layout (u32 indices into GF region):
//   wl[0..3] = counts tier0(m<=32)/1(33-36)/2(37-40)/3(heavy >40)
//   wl[16 + tier*32768 + i] = task ids   (4*32768+16 u32 < 262144 u32 budget)
#define WL_LIST0 16

// merged chol kernel block ranges — HEAVY FIRST, then tiers by descending
// per-wave cost (round-5/6 lesson: longest tasks must start at t=0).
// t1/t0 are DUAL (2 tasks/wave, interleaved chains); t2 single (caps VGPR).
#define HBLK 768
#define TB1 1280    // tier 1: m 33..36, dual MMAX=36
#define TB0 2112    // tier 0: m <=32,  dual MMAX=32
#define TB2 1312    // tier 2: m 37..40, single MMAX=40
#define E_H  (HBLK)
#define E_1  (E_H + TB1)
#define E_0  (E_1 + TB0)
#define NBLK_ALL (E_0 + TB2)

// ---- out layout (FLOAT32 elements) ----
#define O_REC   0
#define O_LOGP  4096
#define O_QZ    4128
#define O_QMU   6176
#define O_QLV   8224
#define O_GH    10272
#define O_ZN    141344
#define O_TOTAL 403488

__device__ __forceinline__ void tf2x32(u32 k0, u32 k1, u32 x0, u32 x1,
                                       u32& o0, u32& o1) {
  u32 ks2 = k0 ^ k1 ^ 0x1BD11BDAu;
  x0 += k0; x1 += k1;
#define TFR(r) { x0 += x1; x1 = (x1 << r) | (x1 >> (32 - r)); x1 ^= x0; }
  TFR(13) TFR(15) TFR(26) TFR(6)   x0 += k1;  x1 += ks2 + 1u;
  TFR(17) TFR(29) TFR(16) TFR(24)  x0 += ks2; x1 += k0 + 2u;
  TFR(13) TFR(15) TFR(26) TFR(6)   x0 += k0;  x1 += k1 + 3u;
  TFR(17) TFR(29) TFR(16) TFR(24)  x0 += k1;  x1 += ks2 + 4u;
  TFR(13) TFR(15) TFR(26) TFR(6)   x0 += ks2; x1 += k0 + 5u;
#undef TFR
  o0 = x0; o1 = x1;
}

__device__ __forceinline__ double d_erfinv(double x) {
  double w = -log1p(-x * x);
  double p;
  if (w < 5.0) {
    w -= 2.5;
    p = 2.81022636e-08;
    p = 3.43273939e-07  + p * w;
    p = -3.5233877e-06  + p * w;
    p = -4.39150654e-06 + p * w;
    p = 0.00021858087   + p * w;
    p = -0.00125372503  + p * w;
    p = -0.00417768164  + p * w;
    p = 0.246640727     + p * w;
    p = 1.50140941      + p * w;
  } else {
    w = sqrt(w) - 3.0;
    p = -0.000200214257;
    p = 0.000100950558  + p * w;
    p = 0.00134934322   + p * w;
    p = -0.00367342844  + p * w;
    p = 0.00573950773   + p * w;
    p = -0.0076224613   + p * w;
    p = 0.00943887047   + p * w;
    p = 1.00167406      + p * w;
    p = 2.83297682      + p * w;
  }
  return p * x;
}

// Stirling lgamma for large z (z ~ 1026: abs err ~1e-12, plenty for f32 out)
__device__ __forceinline__ double stirl(double z) {
  double zi = 1.0 / z;
  double zi2 = zi * zi;
  double s = (z - 0.5) * log(z) - z + 0.9189385332046727;  // 0.5*ln(2*pi)
  s += zi * (1.0 / 12.0 - zi2 * (1.0 / 360.0 - zi2 * (1.0 / 1260.0)));
  return s;
}

// R (with fused setup on block 0): one pass Sx/Sxx, combine analytically.
// ctab via recurrence ctab[l] = ctab[l-2] + log((2049+l)/(4(1+l))).
__global__ void k_R(const float* x, double* ws, const int* seedp) {
  __shared__ double pS[8][64], pX[8][64];
  __shared__ double xbar[64];
  int j = blockIdx.x, t = threadIdx.x;   // 512 threads
  int i = t & 63, c = t >> 6;
  if (j == 0) {                          // fused k_setup
    if (t < 64) {
      int l = t;
      double term = (l >= 2) ? log((2049.0 + (double)l) / (4.0 * (1.0 + (double)l)))
                             : 0.0;
      double v = term;
#pragma unroll
      for (int off = 2; off <= 32; off <<= 1) {
        double o = __shfl_up(v, off, 64);
        if (l >= off) v += o;
      }
      const double LOG_HALF = -0.6931471805599453;
      double c0 = -0.5 * log(2049.0)
                - 1024.0 * log(3.14159265358979323846);
      double seed = (l & 1)
        ? c0 + stirl(1026.0) + 2.5 * LOG_HALF                       // -lgamma(2)=0
        : c0 + stirl(1025.5) + 0.12078223763524522235 + 1.5 * LOG_HALF; // -lgamma(1.5)
      ws[CTAB_OFF + l] = seed + v;
    }
    if (t < 8) ((u32*)(ws + GF_OFF))[t] = 0;   // zero worklist counters
    if (t == 0) {
      u32 kk0 = 0u, kk1 = (u32)seedp[0];
      u32 a0, a1, s0, s1, r0, r1, d0, d1;
      tf2x32(kk0, kk1, 0u, 0u, a0, a1);
      tf2x32(kk0, kk1, 0u, 1u, s0, s1);   // sk (bernoulli)
      tf2x32(a0, a1, 0u, 0u, d0, d1); (void)d0; (void)d1;
      tf2x32(a0, a1, 0u, 1u, r0, r1);     // rk (normal eps)
      u32* keys = (u32*)(ws + KEYS_OFF);
      keys[0] = s0; keys[1] = s1; keys[2] = r0; keys[3] = r1;
    }
  }
  double sx = 0.0, sxx = 0.0;
  for (int n = c * 256; n < (c + 1) * 256; n++) {
    double xi = (double)x[n * 64 + i];
    double xj = (double)x[n * 64 + j];
    sx += xi; sxx += xi * xj;
  }
  pS[c][i] = sx; pX[c][i] = sxx;
  __syncthreads();
  if (t < 64) {
    double S = 0.0, X = 0.0;
    for (int cc = 0; cc < 8; cc++) { S += pS[cc][i]; X += pX[cc][i]; }
    xbar[i] = S / 2048.0;
    pX[0][i] = X;
  }
  __syncthreads();
  if (t < 64) {
    double xbi = xbar[i], xbj = xbar[j];
    double s = pX[0][i] - 2048.0 * xbi * xbj + (2048.0 / 2049.0) * xbi * xbj;
    if (i == j) s += 0.5;
    ((float*)(ws + R_OFF))[i * 64 + j] = (float)s;
  }
}

// probs[p,i,j] = sigmoid(alpha * u_i . v_j) * (i!=j), stored f32
__global__ __launch_bounds__(64) void k_probs(const float* z, double* ws) {
  float* probs = (float*)(ws + PROBS_OFF);
  int b = blockIdx.x; int p = b >> 6, i = b & 63;
  int j = threadIdx.x;
  __shared__ float V[64 * 65];
  __shared__ float us[64];
  int k = j;
  us[k] = z[((p * 64 + i) * 64 + k) * 2 + 0];
  for (int jj = 0; jj < 64; jj++)
    V[jj * 65 + k] = z[((p * 64 + jj) * 64 + k) * 2 + 1];
  __syncthreads();
  float s = 0.f;
  for (int kk = 0; kk < 64; kk++)
    s += us[kk] * V[j * 65 + kk];
  float pr = (i == j) ? 0.f : 1.f / (1.f + expf(-0.2f * s));
  probs[(p * 64 + i) * 64 + j] = pr;
}

// sample graphs AND bucket tasks into the 4 chol tiers (wave-aggregated
// atomics: one atomicAdd per wave per tier).
__global__ void k_sample(double* ws) {
  const float* probs = (const float*)(ws + PROBS_OFF);
  const u32* keys = (const u32*)(ws + KEYS_OFF);
  u64* grow = (u64*)(ws + GROW_OFF);
  u64* gcol = (u64*)(ws + GCOL_OFF);
  u32* wl = (u32*)(ws + GF_OFF);
  int ps = blockIdx.x;
  int p = ps >> 4;
  int j = threadIdx.x;
  u32 k0 = keys[0], k1 = keys[1];
  u64 colmask = 0;
  for (int i = 0; i < 64; i++) {
    u32 lin = (u32)(ps * 4096 + i * 64 + j);
    u32 o0, o1; tf2x32(k0, k1, 0u, lin, o0, o1);
    u32 bits = o0 ^ o1;
    float f = __uint_as_float((bits >> 9) | 0x3f800000u) - 1.0f;
    bool bit = (f < probs[(p * 64 + i) * 64 + j]);
    u64 rm = __ballot(bit);
    if (j == 0) grow[ps * 64 + i] = rm;
    if (bit) colmask |= (1ull << i);
  }
  gcol[ps * 64 + j] = colmask;
  // tier bucketing: task (ps, col j), m = popc+1
  int m = (int)__popcll(colmask) + 1;
  int tier = (m <= 32) ? 0 : (m <= 36) ? 1 : (m <= 40) ? 2 : 3;
#pragma unroll
  for (int t = 0; t < 4; t++) {
    u64 b = __ballot(tier == t);
    if (tier == t) {
      int leader = (int)__builtin_ctzll(b);
      u32 off = (u32)__popcll(b & ((1ull << j) - 1ull));
      u32 base = 0;
      if (j == leader) base = atomicAdd(&wl[t], (u32)__popcll(b));
      base = (u32)__shfl((int)base, leader, 64);
      wl[WL_LIST0 + t * 32768 + base + off] = (u32)(ps * 64 + j);
    }
  }
}

__device__ __forceinline__ float rdlane(float x, int l) {
  return __uint_as_float(__builtin_amdgcn_readlane(__float_as_uint(x), (u32)l));
}

// DUAL-task tier: TWO independent full-wave LDL tasks per wave (va, vb).
// The two readlane->fmac dependency chains have zero data dependence, so
// the scheduler fills one chain's VALU/SGPR-hazard bubbles with the other
// chain's instructions (round-8 analysis: single-chain core ran ~2.5x above
// the 2-instr/element issue floor; DS-pipe broadcast was throughput-bound
// at 1 DS unit/CU vs 4 SIMDs). k-loop is unguarded fixed-MMAX: for k >= m
// the update only writes garbage slots (valid region is c < m); each
// lane's pivot is captured at k==lane < m before any corruption; lanes
// >= m are excluded from the log reduction.
template<int MMAX>
__device__ __forceinline__ void tier_body2(const float* Rf, const double* ctab,
                                           const u64* masks, double* nodescore,
                                           const u32* wl, int tier,
                                           u32 brel, u32 nb, int (*idx)[2][64]) {
  int w = threadIdx.x >> 6;
  int lane = threadIdx.x & 63;
  u32 cnt = wl[tier];
  const u32* list = wl + WL_LIST0 + tier * 32768;
  u32 npair = (cnt + 1) >> 1;
  for (u32 ti = brel * 4 + (u32)w; ti < npair; ti += nb * 4) {
    u32 iA = 2 * ti, iB = iA + 1;
    bool hasB = (iB < cnt);
    int taskA = (int)list[iA];
    int taskB = (int)list[hasB ? iB : iA];   // dup A on odd tail (idempotent)
    u64 maskA = masks[taskA];
    u64 maskB = masks[taskB];
    int PA = (int)__popcll(maskA), PB = (int)__popcll(maskB);
    idx[w][0][lane] = 0;                     // sanitize (dead slots -> row 0)
    idx[w][1][lane] = 0;
    __builtin_amdgcn_wave_barrier();
    {
      u64 belowA = maskA & ((1ull << lane) - 1ull);
      if ((maskA >> lane) & 1ull) idx[w][0][(int)__popcll(belowA)] = lane;
      if (lane == 0) idx[w][0][PA] = taskA & 63;
      u64 belowB = maskB & ((1ull << lane) - 1ull);
      if ((maskB >> lane) & 1ull) idx[w][1][(int)__popcll(belowB)] = lane;
      if (lane == 0) idx[w][1][PB] = taskB & 63;
    }
    __builtin_amdgcn_wave_barrier();
    int rowA = idx[w][0][lane];
    int rowB = idx[w][1][lane];
    float va[MMAX], vb[MMAX];
#pragma unroll
    for (int c = 0; c < MMAX; c++) {
      va[c] = Rf[idx[w][0][c] * 64 + rowA];  // A[lane][c] via R symmetry
      vb[c] = Rf[idx[w][1][c] * 64 + rowB];
    }
    float pivA = 1.0f, pivB = 1.0f;
#pragma unroll
    for (int k = 0; k < MMAX; k++) {
      float dkA = rdlane(va[k], k);
      float dkB = rdlane(vb[k], k);
      if (lane == k) { pivA = dkA; pivB = dkB; }
      float nsA = -va[k] * __builtin_amdgcn_rcpf(dkA);
      float nsB = -vb[k] * __builtin_amdgcn_rcpf(dkB);
#pragma unroll
      for (int b2 = k + 1; b2 < MMAX; b2++) {
        va[b2] += nsA * rdlane(va[k], b2);   // chain A
        vb[b2] += nsB * rdlane(vb[k], b2);   // chain B fills A's bubbles
      }
    }
    {
      int mA = PA + 1;
      float lastd = __shfl(pivA, PA, 64);
      float lv = (lane < mA) ? __logf(pivA) : 0.f;
      for (int off = 32; off > 0; off >>= 1) lv += __shfl_down(lv, off, 64);
      if (lane == 0) {
        double l = (double)PA;
        nodescore[taskA] = ctab[PA]
                         - 0.5 * (2050.0 + l) * (double)__logf(lastd)
                         - 0.5 * (double)lv;
      }
    }
    if (hasB) {
      int mB = PB + 1;
      float lastd = __shfl(pivB, PB, 64);
      float lv = (lane < mB) ? __logf(pivB) : 0.f;
      for (int off = 32; off > 0; off >>= 1) lv += __shfl_down(lv, off, 64);
      if (lane == 0) {
        double l = (double)PB;
        nodescore[taskB] = ctab[PB]
                         - 0.5 * (2050.0 + l) * (double)__logf(lastd)
                         - 0.5 * (double)lv;
      }
    }
    __builtin_amdgcn_wave_barrier();         // order idx reuse across iters
  }
}

// Single-task tier (m 37..40): proven readlane core, kept single so its
// 40-reg array doesn't stack with the dual bodies' VGPR budget.
template<int MMAX>
__device__ __forceinline__ void tier_body(const float* Rf, const double* ctab,
                                          const u64* masks, double* nodescore,
                                          const u32* wl, int tier,
                                          u32 brel, u32 nb, int (*idx)[64]) {
  int w = threadIdx.x >> 6;
  int lane = threadIdx.x & 63;
  u32 cnt = wl[tier];
  const u32* list = wl + WL_LIST0 + tier * 32768;
  for (u32 ti = brel * 4 + (u32)w; ti < cnt; ti += nb * 4) {
    int task = (int)list[ti];
    int j = task & 63;
    u64 mask = masks[task];
    int P = (int)__popcll(mask);
    int m = P + 1;
    idx[w][lane] = 0;                       // sanitize (dead slots -> row 0)
    __builtin_amdgcn_wave_barrier();
    u64 below = mask & ((1ull << lane) - 1ull);
    if ((mask >> lane) & 1ull) idx[w][(int)__popcll(below)] = lane;
    if (lane == 0) idx[w][P] = j;
    __builtin_amdgcn_wave_barrier();
    int myrow = idx[w][lane];               // my node id (0 for dead lanes)
    float v[MMAX];
#pragma unroll
    for (int c = 0; c < MMAX; c++)
      v[c] = Rf[idx[w][c] * 64 + myrow];    // A[lane][c] via symmetry
    float mypiv = 1.0f;
#pragma unroll
    for (int k = 0; k < MMAX; k++) {
      if (k < m) {                          // uniform guard (keeps full unroll)
        float dk = rdlane(v[k], k);
        if (lane == k) mypiv = dk;
        float ns = -v[k] * __builtin_amdgcn_rcpf(dk);
#pragma unroll
        for (int b = k + 1; b < MMAX; b++)
          v[b] += ns * rdlane(v[k], b);     // garbage slots never read back
      }
    }
    float lastd = __shfl(mypiv, P, 64);     // final pivot d_{m-1} (lane P)
    float lv = (lane < m) ? __logf(mypiv) : 0.f;
    for (int off = 32; off > 0; off >>= 1) lv += __shfl_down(lv, off, 64);
    if (lane == 0) {
      double l = (double)P;
      nodescore[task] = ctab[P]
                      - 0.5 * (2050.0 + l) * (double)__logf(lastd)
                      - 0.5 * (double)lv;
    }
    __builtin_amdgcn_wave_barrier();        // order idx reuse across iterations
  }
}

#define WB() __builtin_amdgcn_wave_barrier()

// Heavy path (m>40, ~3%): wave 0 of the block only; full hybrid path with
// LDS triangle.
__device__ void heavy_body(const float* Rf, const double* ctab,
                           const u64* masks, double* nodescore,
                           const u32* wl, u32 brel, u32 nb,
                           float* T, int* idx) {
  if (threadIdx.x >= 64) return;
  int lane = threadIdx.x;
  u32 cnt = wl[3];
  const u32* list = wl + WL_LIST0 + 3 * 32768;
  for (u32 ii = brel; ii < cnt; ii += nb) {
    WB();
    int task = (int)list[ii];
    int j = task & 63;
    u64 mask = masks[task];
    int P = (int)__popcll(mask);
    int m = P + 1;
    u64 below = mask & ((1ull << lane) - 1ull);
    if ((mask >> lane) & 1ull) idx[(int)__popcll(below)] = lane;
    if (lane == 0) idx[P] = j;
    WB();
    int trLane = (lane * (lane + 1)) >> 1;
    if (lane < m) {
      int cidx = idx[lane];
      int tr = 0;
      for (int r = 0; r < m; r++) {
        if (lane <= r) T[tr + lane] = Rf[idx[r] * 64 + cidx];
        tr += r + 1;
      }
    }
    WB();
    float mypiv = 1.0f, lastd = 1.0f;
    float v[40];
#pragma unroll
    for (int c = 0; c < 40; c++)
      v[c] = T[trLane + c];
#pragma unroll
    for (int k = 0; k < 40; k++) {
      if (k < m) {
        float dk = rdlane(v[k], k);
        if (lane == k) mypiv = dk;
        lastd = dk;
        float ns = -v[k] * __builtin_amdgcn_rcpf(dk);
#pragma unroll
        for (int b = k + 1; b < 40; b++)
          v[b] += ns * rdlane(v[k], b);
      }
    }
    if (m > 40) {
      for (int b = 40; b < m; b++) {
        float acc = 0.f;
#pragma unroll
        for (int k = 0; k < 40; k++) {
          float dk = rdlane(v[k], k);
          float abk = rdlane(v[k], b);
          acc += v[k] * abk * __builtin_amdgcn_rcpf(dk);
        }
        if (lane >= b) T[trLane + b] -= acc;
      }
      WB();
      for (int k = 40; k < m; k++) {
        float dk = T[((k * (k + 1)) >> 1) + k];
        if (lane == k) mypiv = dk;
        lastd = dk;
        float sk = T[trLane + k] * __builtin_amdgcn_rcpf(dk);
        for (int b = k + 1; b < m; b++) {
          float abk = T[((b * (b + 1)) >> 1) + k];
          if (lane >= b) T[trLane + b] -= sk * abk;
        }
        WB();
      }
    }
    double vv = (lane < m) ? log((double)mypiv) : 0.0;
    for (int off = 32; off > 0; off >>= 1) vv += __shfl_down(vv, off, 64);
    if (lane == 0) {
      double logB = vv;
      double logA = logB - log((double)lastd);
      double l = (double)P;
      nodescore[task] = ctab[P]
                      + 0.5 * (2050.0 + l) * logA
                      - 0.5 * (2051.0 + l) * logB;
    }
  }
}

// ONE launch for all 32768 sampled-graph cholesky tasks. Heavy first, then
// tiers by descending per-wave cost. No min-waves launch_bounds cap
// (round-1 lesson: caps + big v[] => scratch spill).
__global__ __launch_bounds__(256) void k_chol_all(const float* Rf, const double* ctab,
                                                  const u64* masks, double* nodescore,
                                                  const u32* wl) {
  __shared__ int idx2[4][2][64];
  __shared__ int idx4[4][64];
  __shared__ float T[2080];
  __shared__ int idxh[64];
  u32 b = blockIdx.x;
  if (b < E_H)      heavy_body(Rf, ctab, masks, nodescore, wl, b, HBLK, T, idxh);
  else if (b < E_1) tier_body2<36>(Rf, ctab, masks, nodescore, wl, 1, b - E_H, TB1, idx2);
  else if (b < E_0) tier_body2<32>(Rf, ctab, masks, nodescore, wl, 0, b - E_1, TB0, idx2);
  else              tier_body<40>(Rf, ctab, masks, nodescore, wl, 2, b - E_0, TB2, idx4);
}

// Merged hybrid f32 LDL Cholesky (transpose variant for the 2048 hard-graph
// tasks). UNCHANGED and kept f64: its scores feed the log_p OUTPUT, where
// absmax is already at 1 f32 ulp of |logp|~4000.
template<bool TRANSPOSE>
__global__ __launch_bounds__(64) void k_chol(const float* Rf, const double* ctab,
                                             const u64* masks, double* nodescore) {
  __shared__ float T[2080];
  __shared__ int idx[64];
  int task = blockIdx.x;
  int j = task & 63;
  int lane = threadIdx.x;
  u64 mask;
  if (TRANSPOSE) {
    int p = task >> 6;
    u64 rm = masks[p * 64 + lane];       // row mask of row `lane`
    mask = __ballot((rm >> j) & 1ull);   // column j mask
  } else {
    mask = masks[task];
  }
  int P = (int)__popcll(mask);
  int m = P + 1;
  u64 below = mask & ((1ull << lane) - 1ull);
  if ((mask >> lane) & 1ull) idx[(int)__popcll(below)] = lane;
  if (lane == 0) idx[P] = j;
  __syncthreads();
  int trLane = (lane * (lane + 1)) >> 1;
  if (lane < m) {
    int cidx = idx[lane];
    int tr = 0;
    for (int r = 0; r < m; r++) {
      if (lane <= r) T[tr + lane] = Rf[idx[r] * 64 + cidx];
      tr += r + 1;
    }
  }
  __syncthreads();
  float mypiv = 1.0f, lastd = 1.0f;
  float v[40];
#pragma unroll
  for (int c = 0; c < 40; c++)
    v[c] = T[trLane + c];                // in-bounds garbage for c>lane
#pragma unroll
  for (int k = 0; k < 40; k++) {
    if (k < m) {                         // uniform guard (keeps full unroll)
      float dk = rdlane(v[k], k);
      if (lane == k) mypiv = dk;
      lastd = dk;
      float ns = -v[k] * __builtin_amdgcn_rcpf(dk);
#pragma unroll
      for (int b = k + 1; b < 40; b++)
        v[b] += ns * rdlane(v[k], b);    // garbage slots harmless
    }
  }
  if (m > 40) {                          // heavy tasks only (block-uniform)
    for (int b = 40; b < m; b++) {
      float acc = 0.f;
#pragma unroll
      for (int k = 0; k < 40; k++) {
        float dk = rdlane(v[k], k);                  // final pivot k
        float abk = rdlane(v[k], b);                 // final A[b][k]
        acc += v[k] * abk * __builtin_amdgcn_rcpf(dk);
      }
      if (lane >= b) T[trLane + b] -= acc;           // own-row, no conflict
    }
    __syncthreads();
    for (int k = 40; k < m; k++) {
      float dk = T[((k * (k + 1)) >> 1) + k];        // broadcast
      if (lane == k) mypiv = dk;
      lastd = dk;
      float sk = T[trLane + k] * __builtin_amdgcn_rcpf(dk);
      for (int b = k + 1; b < m; b++) {
        float abk = T[((b * (b + 1)) >> 1) + k];     // broadcast
        if (lane >= b) T[trLane + b] -= sk * abk;
      }
      __syncthreads();
    }
  }
  double vv = (lane < m) ? log((double)mypiv) : 0.0;
  for (int off = 32; off > 0; off >>= 1) vv += __shfl_down(vv, off, 64);
  if (lane == 0) {
    double logB = vv;
    double logA = logB - log((double)lastd);
    double l = (double)P;
    nodescore[task] = ctab[P]
                    + 0.5 * (2050.0 + l) * logA
                    - 0.5 * (2051.0 + l) * logB;
  }
}

__global__ void k_logpw(const double* ns, double* w) {
  int p = blockIdx.x, t = threadIdx.x;
  __shared__ double part[64];
  int s = t & 15, c = t >> 4;            // 4 chunks x 16 samples
  double acc = 0.0;
  for (int j = c * 16; j < (c + 1) * 16; j++)
    acc += ns[(p * 16 + s) * 64 + j];
  part[t] = acc;
  __syncthreads();
  if (t < 16) part[t] = part[t] + part[t + 16] + part[t + 32] + part[t + 48];
  __syncthreads();
  if (t == 0) {
    double m = part[0];
    for (int s2 = 1; s2 < 16; s2++) m = fmax(m, part[s2]);
    double e[16], sum = 0.0;
    for (int s2 = 0; s2 < 16; s2++) { e[s2] = exp(part[s2] - m); sum += e[s2]; }
    for (int s2 = 0; s2 < 16; s2++) w[p * 16 + s2] = e[s2] / sum;
  }
}

// fused A-construction + grad dot + kmat.
// blocks 0..2047: grad_u; 2048..4095: grad_v; 4096..5119: Kmat (z0-only).
__global__ void k_grad(double* ws, const float* z) {
  const float* probs = (const float*)(ws + PROBS_OFF);
  const double* w = ws + W_OFF;
  const u64* grow = (const u64*)(ws + GROW_OFF);
  const u64* gcol = (const u64*)(ws + GCOL_OFF);
  float* gf = (float*)(ws + GF_OFF);
  const float LOGIT = -2.6903717578966254f;  // log(4/63)-log1p(-4/63)
  int bb = blockIdx.x;
  int k = threadIdx.x;
  __shared__ float acc[64];
  if (bb < 2048) {
    int p = bb >> 6, i = bb & 63;
    float gb = 0.f, wsum = 0.f;
    for (int s = 0; s < 16; s++) {
      float wv = (float)w[p * 16 + s];
      wsum += wv;
      gb += wv * (float)((grow[(p * 16 + s) * 64 + i] >> k) & 1ull);
    }
    float pr = probs[(p * 64 + i) * 64 + k];   // coalesced
    float od = (i == k) ? 0.f : 1.f;
    acc[k] = (0.2f * (gb - pr * wsum) + 0.2f * pr * (1.f - pr) * LOGIT) * od;
    __syncthreads();
    float s = 0.f;
    for (int j = 0; j < 64; j++)
      s += acc[j] * z[((p * 64 + j) * 64 + k) * 2 + 1];
    s -= 64.f * z[((p * 64 + i) * 64 + k) * 2 + 0];
    gf[p * 8192 + (i * 64 + k) * 2 + 0] = s;
  } else if (bb < 4096) {
    int b = bb - 2048;
    int p = b >> 6, j = b & 63;
    float gb = 0.f, wsum = 0.f;
    for (int s = 0; s < 16; s++) {
      float wv = (float)w[p * 16 + s];
      wsum += wv;
      gb += wv * (float)((gcol[(p * 16 + s) * 64 + j] >> k) & 1ull);
    }
    float pr = probs[(p * 64 + k) * 64 + j];   // one 64-lane gather
    float od = (k == j) ? 0.f : 1.f;
    acc[k] = (0.2f * (gb - pr * wsum) + 0.2f * pr * (1.f - pr) * LOGIT) * od;
    __syncthreads();
    float s = 0.f;
    for (int i = 0; i < 64; i++)
      s += acc[i] * z[((p * 64 + i) * 64 + k) * 2 + 0];
    s -= 64.f * z[((p * 64 + j) * 64 + k) * 2 + 1];
    gf[p * 8192 + (j * 64 + k) * 2 + 1] = s;
  } else {
    float* Km = (float*)(ws + KM_OFF);
    int b = bb - 4096;
    int a = b >> 5, b2 = b & 31;
    float accf = 0.f;
    for (int d0 = k; d0 < 8192; d0 += 64) {
      float diff = z[a * 8192 + d0] - z[b2 * 8192 + d0];
      accf += diff * diff;
    }
    for (int off = 32; off > 0; off >>= 1) accf += __shfl_down(accf, off, 64);
    if (k == 0) Km[a * 32 + b2] = expf(-accf / 5.0f);
  }
}

__global__ void k_znew(const float* z, double* ws, float* out) {
  const float* Km = (const float*)(ws + KM_OFF);
  const float* gf = (const float*)(ws + GF_OFF);
  float* zn = (float*)(ws + ZN_OFF);
  int gid = blockIdx.x * 64 + threadIdx.x;
  int p = gid >> 13, t = gid & 8191;
  float zp = z[p * 8192 + t];
  float accg = 0.f, accz = 0.f, ks = 0.f;
  for (int b = 0; b < 32; b++) {
    float kv = Km[p * 32 + b];
    accg += kv * gf[b * 8192 + t];
    accz += kv * z[b * 8192 + t];
    ks += kv;
  }
  float rep = -0.4f * (accz - zp * ks);
  float v = zp + 0.005f * ((accg + rep) / 32.f);
  zn[p * 8192 + t] = v;
  out[O_ZN + p * 8192 + t] = v;
}

__global__ __launch_bounds__(64) void k_s2col(double* ws, float* out) {
  const float* zn = (const float*)(ws + ZN_OFF);
  u64* grow2 = (u64*)(ws + NS_OFF);
  int b = blockIdx.x; int p = b >> 6, i = b & 63;
  int j = threadIdx.x;
  __shared__ float V[64 * 65];
  __shared__ float us[64];
  int k = j;
  us[k] = zn[p * 8192 + (i * 64 + k) * 2 + 0];
  for (int jj = 0; jj < 64; jj++)
    V[jj * 65 + k] = zn[p * 8192 + (jj * 64 + k) * 2 + 1];
  __syncthreads();
  float s = 0.f;
  for (int kk = 0; kk < 64; kk++)
    s += us[kk] * V[j * 65 + kk];
  bool bit = (i != j) && (s > 0.0f);
  out[O_GH + (p * 64 + i) * 64 + j] = bit ? 1.0f : 0.0f;
  u64 m = __ballot(bit);
  if (j == 0) grow2[p * 64 + i] = m;    // row masks; k_chol<true> transposes
}

// encoder/decoder MLP; also writes log_p (fused reduction).
__global__ __launch_bounds__(256) void k_mlp(double* ws, float* out, const double* ns2,
    const float* ew0, const float* eb0, const float* ew1, const float* eb1,
    const float* ew2, const float* eb2,
    const float* mw0, const float* mb0, const float* mw1, const float* mb1,
    const float* lw0, const float* lb0, const float* lw1, const float* lb1,
    const float* dw0, const float* db0, const float* dw1, const float* db1,
    const float* dw2, const float* db2) {
  int p = blockIdx.x, t = threadIdx.x;
  int w = t >> 6, lane = t & 63;
  const u64* grow2 = (const u64*)(ws + NS_OFF);
  const u32* keys = (const u32*)(ws + KEYS_OFF);
  __shared__ float pt[4][64];
  __shared__ float e0p[4][20];
  __shared__ float h0[20], h1[64], h2[64], hm[64], hl[64];
  __shared__ float qmu[64], qlv[64], qz[64], h3[10], h4[128];

  // ---- logp reduction (wave 0) ----
  if (w == 0) {
    double vv = ns2[p * 64 + lane];
    for (int off = 32; off > 0; off >>= 1) vv += __shfl_down(vv, off, 64);
    if (lane == 0) out[O_LOGP + p] = (float)vv;
  }

  // ---- e0: h0[20] = relu(eb0 + sum over set bits of ew0 rows) ----
  {
    int i = t >> 2;
    int jb = (t & 3) * 16;
    u32 m16 = (u32)((grow2[p * 64 + i] >> jb) & 0xFFFFull);
    float acc[20];
#pragma unroll
    for (int o = 0; o < 20; o++) acc[o] = 0.f;
    const float4* wb = (const float4*)(ew0 + (size_t)(t * 16) * 20);
#pragma unroll
    for (int q = 0; q < 16; q++) {
      float mq = (float)((m16 >> q) & 1u);
      float4 r0 = wb[q * 5 + 0], r1 = wb[q * 5 + 1], r2 = wb[q * 5 + 2];
      float4 r3 = wb[q * 5 + 3], r4 = wb[q * 5 + 4];
      acc[0]  += mq * r0.x; acc[1]  += mq * r0.y; acc[2]  += mq * r0.z; acc[3]  += mq * r0.w;
      acc[4]  += mq * r1.x; acc[5]  += mq * r1.y; acc[6]  += mq * r1.z; acc[7]  += mq * r1.w;
      acc[8]  += mq * r2.x; acc[9]  += mq * r2.y; acc[10] += mq * r2.z; acc[11] += mq * r2.w;
      acc[12] += mq * r3.x; acc[13] += mq * r3.y; acc[14] += mq * r3.z; acc[15] += mq * r3.w;
      acc[16] += mq * r4.x; acc[17] += mq * r4.y; acc[18] += mq * r4.z; acc[19] += mq * r4.w;
    }
#pragma unroll
    for (int o = 0; o < 20; o++) {
      float v = acc[o];
      for (int off = 32; off > 0; off >>= 1) v += __shfl_down(v, off, 64);
      if (lane == 0) e0p[w][o] = v;
    }
  }
  __syncthreads();
  if (t < 20)
    h0[t] = fmaxf(eb0[t] + e0p[0][t] + e0p[1][t] + e0p[2][t] + e0p[3][t], 0.f);
  __syncthreads();

  // ---- h1[64] = relu(eb1 + h0 @ ew1), fan-in 20 split 5/wave ----
  {
    float s = 0.f;
#pragma unroll
    for (int q = 0; q < 5; q++) s += h0[w * 5 + q] * ew1[(w * 5 + q) * 64 + lane];
    pt[w][lane] = s;
  }
  __syncthreads();
  if (w == 0)
    h1[lane] = fmaxf(eb1[lane] + pt[0][lane] + pt[1][lane] + pt[2][lane] + pt[3][lane], 0.f);
  __syncthreads();

  // ---- h2[64] = relu(eb2 + h1 @ ew2), fan-in 64 split 16/wave ----
  {
    float s = 0.f;
#pragma unroll
    for (int q = 0; q < 16; q++) s += h1[w * 16 + q] * ew2[(w * 16 + q) * 64 + lane];
    pt[w][lane] = s;
  }
  __syncthreads();
  if (w == 0)
    h2[lane] = fmaxf(eb2[lane] + pt[0][lane] + pt[1][lane] + pt[2][lane] + pt[3][lane], 0.f);
  __syncthreads();

  // ---- hm/hl in parallel: waves 0,1 -> hm; waves 2,3 -> hl ----
  {
    const float* W = (w < 2) ? mw0 : lw0;
    int qb = (w & 1) * 32;
    float s = 0.f;
#pragma unroll
    for (int q = 0; q < 32; q++) s += h2[qb + q] * W[(qb + q) * 64 + lane];
    pt[w][lane] = s;
  }
  __syncthreads();
  if (w == 0) hm[lane] = fmaxf(mb0[lane] + pt[0][lane] + pt[1][lane], 0.f);
  if (w == 1) hl[lane] = fmaxf(lb0[lane] + pt[2][lane] + pt[3][lane], 0.f);
  __syncthreads();

  // ---- qmu/qlv in parallel (no relu) ----
  {
    const float* W = (w < 2) ? mw1 : lw1;
    const float* src = (w < 2) ? hm : hl;
    int qb = (w & 1) * 32;
    float s = 0.f;
#pragma unroll
    for (int q = 0; q < 32; q++) s += src[qb + q] * W[(qb + q) * 64 + lane];
    pt[w][lane] = s;
  }
  __syncthreads();
  if (w == 0) qmu[lane] = mb1[lane] + pt[0][lane] + pt[1][lane];
  if (w == 1) qlv[lane] = lb1[lane] + pt[2][lane] + pt[3][lane];
  __syncthreads();

  // ---- reparameterize (wave 0) + output qz/qmu/qlv ----
  if (w == 0) {
    u32 o0, o1;
    tf2x32(keys[2], keys[3], 0u, (u32)(p * 64 + lane), o0, o1);
    u32 bits = o0 ^ o1;
    float f = __uint_as_float((bits >> 9) | 0x3f800000u) - 1.0f;
    float LOF = __uint_as_float(0xBF7FFFFFu);
    float uu = fmaxf(LOF, f * 2.0f + LOF);
    float eps = (float)(1.4142135623730951 * d_erfinv((double)uu));
    float qzv = qmu[lane] + eps * expf(0.5f * qlv[lane]);
    qz[lane] = qzv;
    out[O_QZ  + p * 64 + lane] = qzv;
    out[O_QMU + p * 64 + lane] = qmu[lane];
    out[O_QLV + p * 64 + lane] = qlv[lane];
  }
  __syncthreads();

  // ---- d0: h3[10] = relu(db0 + qz @ dw0), fan-in 64 split 16/wave ----
  {
    float s = 0.f;
    if (lane < 10) {
#pragma unroll
      for (int q = 0; q < 16; q++) s += qz[w * 16 + q] * dw0[(w * 16 + q) * 10 + lane];
    }
    pt[w][lane] = s;
  }
  __syncthreads();
  if (w == 0 && lane < 10)
    h3[lane] = fmaxf(db0[lane] + pt[0][lane] + pt[1][lane] + pt[2][lane] + pt[3][lane], 0.f);
  __syncthreads();

  // ---- d1: h4[128] = relu(db1 + h3 @ dw1) ----
  {
    int o = (w >> 1) * 64 + lane;
    int qb = (w & 1) * 5;
    float s = 0.f;
#pragma unroll
    for (int q = 0; q < 5; q++) s += h3[qb + q] * dw1[(qb + q) * 128 + o];
    pt[w][lane] = s;
  }
  __syncthreads();
  if (w == 0) h4[lane]      = fmaxf(db1[lane]      + pt[0][lane] + pt[1][lane], 0.f);
  if (w == 1) h4[64 + lane] = fmaxf(db1[64 + lane] + pt[2][lane] + pt[3][lane], 0.f);
  __syncthreads();

  // ---- d2: recons[128] = db2 + h4 @ dw2 ----
  {
    int o = (w >> 1) * 64 + lane;
    int qb = (w & 1) * 64;
    float s = 0.f;
#pragma unroll
    for (int q = 0; q < 64; q++) s += h4[qb + q] * dw2[(qb + q) * 128 + o];
    pt[w][lane] = s;
  }
  __syncthreads();
  if (w == 0) out[O_REC + p * 128 + lane]      = db2[lane]      + pt[0][lane] + pt[1][lane];
  if (w == 1) out[O_REC + p * 128 + 64 + lane] = db2[64 + lane] + pt[2][lane] + pt[3][lane];
}

extern "C" void kernel_launch(void* const* d_in, const int* in_sizes, int n_in,
                              void* d_out, int out_size, void* d_ws, size_t ws_size,
                              hipStream_t stream) {
  (void)in_sizes; (void)n_in; (void)out_size; (void)ws_size;
  const float* z_gt = (const float*)d_in[0];
  const float* z0   = (const float*)d_in[1];
  const float* ew0 = (const float*)d_in[2];  const float* eb0 = (const float*)d_in[3];
  const float* ew1 = (const float*)d_in[4];  const float* eb1 = (const float*)d_in[5];
  const float* ew2 = (const float*)d_in[6];  const float* eb2 = (const float*)d_in[7];
  const float* mw0 = (const float*)d_in[8];  const float* mb0 = (const float*)d_in[9];
  const float* mw1 = (const float*)d_in[10]; const float* mb1 = (const float*)d_in[11];
  const float* lw0 = (const float*)d_in[12]; const float* lb0 = (const float*)d_in[13];
  const float* lw1 = (const float*)d_in[14]; const float* lb1 = (const float*)d_in[15];
  const float* dw0 = (const float*)d_in[16]; const float* db0 = (const float*)d_in[17];
  const float* dw1 = (const float*)d_in[18]; const float* db1 = (const float*)d_in[19];
  const float* dw2 = (const float*)d_in[20]; const float* db2 = (const float*)d_in[21];
  const int* seed = (const int*)d_in[22];
  double* ws = (double*)d_ws;
  float* out = (float*)d_out;
  const float* Rf = (const float*)(ws + R_OFF);
  const u32* wl = (const u32*)(ws + GF_OFF);  // tier worklists (chol phase only;
                                              // region is reused by k_grad later)

  k_R<<<64, 512, 0, stream>>>(z_gt, ws, seed);
  k_probs<<<C_P * C_D, 64, 0, stream>>>(z0, ws);
  k_sample<<<C_P * C_S, 64, 0, stream>>>(ws);
  k_chol_all<<<NBLK_ALL, 256, 0, stream>>>(Rf, ws + CTAB_OFF,
      (const u64*)(ws + GCOL_OFF), ws + NS_OFF, wl);
  k_logpw<<<C_P, 64, 0, stream>>>(ws + NS_OFF, ws + W_OFF);
  k_grad<<<2 * C_P * C_D + C_P * C_P, 64, 0, stream>>>(ws, z0);
  k_znew<<<(C_P * 8192) / 64, 64, 0, stream>>>(z0, ws, out);
  k_s2col<<<C_P * C_D, 64, 0, stream>>>(ws, out);
  k_chol<true><<<C_P * C_D, 64, 0, stream>>>(Rf, ws + CTAB_OFF,
      (const u64*)(ws + NS_OFF), ws + NS2_OFF);
  k_mlp<<<C_P, 256, 0, stream>>>(ws, out, ws + NS2_OFF,
      ew0, eb0, ew1, eb1, ew2, eb2,
      mw0, mb0, mw1, mb1, lw0, lb0, lw1, lb1,
      dw0, db0, dw1, db1, dw2, db2);
}

// Round 10
// 329.324 us; speedup vs baseline: 1.1070x; 1.0217x over previous
//
#include <hip/hip_runtime.h>
#include <stdint.h>
#include <math.h>

typedef unsigned long long u64;
typedef unsigned int u32;
typedef unsigned short u16;

// ---- problem constants ----
#define C_P 32
#define C_S 16
#define C_D 64
#define C_N 2048

// ---- ws layout (offsets in doubles) ----
#define R_OFF      0        // float[4096]
#define CTAB_OFF   4160     // double[64]
#define KEYS_OFF   4224     // u32[4]
#define PROBS_OFF  4232     // float[131072]
#define GROW_OFF   135304   // u64[32768] row masks
#define GCOL_OFF   168072   // u64[32768] col masks
#define NS_OFF     200840   // double[32768]; later grow2 u64[2048]
#define W_OFF      233608   // double[512] (UNUSED since logpw fused into grad)
#define GF_OFF     234120   // float[262144]; chol-phase: tier worklists (u32)
#define KM_OFF     365192   // float[1024]
#define ZN_OFF     365704   // float[262144]
#define NS2_OFF    496776   // double[2048]

// worklist layout (u32 indices into GF region):
//   wl[0..3] = counts tier0(m<=32)/1(33-36)/2(37-40)/3(heavy >40)
//   wl[16 + tier*32768 + i] = task ids   (4*32768+16 u32 < 262144 u32 budget)
#define WL_LIST0 16

// merged chol kernel block ranges — HEAVY FIRST, then tiers by descending
// per-wave cost (round-5/6 lesson: longest tasks must start at t=0).
// t1/t0 are DUAL (2 tasks/wave, interleaved chains); t2 single (caps VGPR).
#define HBLK 768
#define TB1 1280    // tier 1: m 33..36, dual MMAX=36
#define TB0 2112    // tier 0: m <=32,  dual MMAX=32
#define TB2 1312    // tier 2: m 37..40, single MMAX=40
#define E_H  (HBLK)
#define E_1  (E_H + TB1)
#define E_0  (E_1 + TB0)
#define NBLK_ALL (E_0 + TB2)

// ---- out layout (FLOAT32 elements) ----
#define O_REC   0
#define O_LOGP  4096
#define O_QZ    4128
#define O_QMU   6176
#define O_QLV   8224
#define O_GH    10272
#define O_ZN    141344
#define O_TOTAL 403488

__device__ __forceinline__ void tf2x32(u32 k0, u32 k1, u32 x0, u32 x1,
                                       u32& o0, u32& o1) {
  u32 ks2 = k0 ^ k1 ^ 0x1BD11BDAu;
  x0 += k0; x1 += k1;
#define TFR(r) { x0 += x1; x1 = (x1 << r) | (x1 >> (32 - r)); x1 ^= x0; }
  TFR(13) TFR(15) TFR(26) TFR(6)   x0 += k1;  x1 += ks2 + 1u;
  TFR(17) TFR(29) TFR(16) TFR(24)  x0 += ks2; x1 += k0 + 2u;
  TFR(13) TFR(15) TFR(26) TFR(6)   x0 += k0;  x1 += k1 + 3u;
  TFR(17) TFR(29) TFR(16) TFR(24)  x0 += k1;  x1 += ks2 + 4u;
  TFR(13) TFR(15) TFR(26) TFR(6)   x0 += ks2; x1 += k0 + 5u;
#undef TFR
  o0 = x0; o1 = x1;
}

__device__ __forceinline__ double d_erfinv(double x) {
  double w = -log1p(-x * x);
  double p;
  if (w < 5.0) {
    w -= 2.5;
    p = 2.81022636e-08;
    p = 3.43273939e-07  + p * w;
    p = -3.5233877e-06  + p * w;
    p = -4.39150654e-06 + p * w;
    p = 0.00021858087   + p * w;
    p = -0.00125372503  + p * w;
    p = -0.00417768164  + p * w;
    p = 0.246640727     + p * w;
    p = 1.50140941      + p * w;
  } else {
    w = sqrt(w) - 3.0;
    p = -0.000200214257;
    p = 0.000100950558  + p * w;
    p = 0.00134934322   + p * w;
    p = -0.00367342844  + p * w;
    p = 0.00573950773   + p * w;
    p = -0.0076224613   + p * w;
    p = 0.00943887047   + p * w;
    p = 1.00167406      + p * w;
    p = 2.83297682      + p * w;
  }
  return p * x;
}

// Stirling lgamma for large z (z ~ 1026: abs err ~1e-12, plenty for f32 out)
__device__ __forceinline__ double stirl(double z) {
  double zi = 1.0 / z;
  double zi2 = zi * zi;
  double s = (z - 0.5) * log(z) - z + 0.9189385332046727;  // 0.5*ln(2*pi)
  s += zi * (1.0 / 12.0 - zi2 * (1.0 / 360.0 - zi2 * (1.0 / 1260.0)));
  return s;
}

// MERGED init kernel (launch-count reduction, round-10):
//   blocks 0..63   : R computation (+ fused setup on block 0)
//   blocks 64..319 : probs — 8 waves/block share ONE V staging per particle
//                    octant (previous k_probs re-staged V 8x per particle).
__global__ void k_init(const float* x, const float* z, double* ws, const int* seedp) {
  int t = threadIdx.x;                   // 512 threads
  if (blockIdx.x < 64) {
    __shared__ double pS[8][64], pX[8][64];
    __shared__ double xbar[64];
    int j = blockIdx.x;
    int i = t & 63, c = t >> 6;
    if (j == 0) {                        // fused k_setup
      if (t < 64) {
        int l = t;
        double term = (l >= 2) ? log((2049.0 + (double)l) / (4.0 * (1.0 + (double)l)))
                               : 0.0;
        double v = term;
#pragma unroll
        for (int off = 2; off <= 32; off <<= 1) {
          double o = __shfl_up(v, off, 64);
          if (l >= off) v += o;
        }
        const double LOG_HALF = -0.6931471805599453;
        double c0 = -0.5 * log(2049.0)
                  - 1024.0 * log(3.14159265358979323846);
        double seed = (l & 1)
          ? c0 + stirl(1026.0) + 2.5 * LOG_HALF                       // -lgamma(2)=0
          : c0 + stirl(1025.5) + 0.12078223763524522235 + 1.5 * LOG_HALF; // -lgamma(1.5)
        ws[CTAB_OFF + l] = seed + v;
      }
      if (t < 8) ((u32*)(ws + GF_OFF))[t] = 0;   // zero worklist counters
      if (t == 0) {
        u32 kk0 = 0u, kk1 = (u32)seedp[0];
        u32 a0, a1, s0, s1, r0, r1, d0, d1;
        tf2x32(kk0, kk1, 0u, 0u, a0, a1);
        tf2x32(kk0, kk1, 0u, 1u, s0, s1);   // sk (bernoulli)
        tf2x32(a0, a1, 0u, 0u, d0, d1); (void)d0; (void)d1;
        tf2x32(a0, a1, 0u, 1u, r0, r1);     // rk (normal eps)
        u32* keys = (u32*)(ws + KEYS_OFF);
        keys[0] = s0; keys[1] = s1; keys[2] = r0; keys[3] = r1;
      }
    }
    double sx = 0.0, sxx = 0.0;
    for (int n = c * 256; n < (c + 1) * 256; n++) {
      double xi = (double)x[n * 64 + i];
      double xj = (double)x[n * 64 + j];
      sx += xi; sxx += xi * xj;
    }
    pS[c][i] = sx; pX[c][i] = sxx;
    __syncthreads();
    if (t < 64) {
      double S = 0.0, X = 0.0;
      for (int cc = 0; cc < 8; cc++) { S += pS[cc][i]; X += pX[cc][i]; }
      xbar[i] = S / 2048.0;
      pX[0][i] = X;
    }
    __syncthreads();
    if (t < 64) {
      double xbi = xbar[i], xbj = xbar[j];
      double s = pX[0][i] - 2048.0 * xbi * xbj + (2048.0 / 2049.0) * xbi * xbj;
      if (i == j) s += 0.5;
      ((float*)(ws + R_OFF))[i * 64 + j] = (float)s;
    }
  } else {
    // probs[p,i,j] = sigmoid(alpha * u_i . v_j) * (i!=j)
    __shared__ float V[64 * 65];
    __shared__ float us[8][64];
    float* probs = (float*)(ws + PROBS_OFF);
    int b2 = blockIdx.x - 64;            // 0..255
    int p = b2 >> 3;
    int i = (b2 & 7) * 8 + (t >> 6);     // this wave's output row
    int j = t & 63, w = t >> 6;
    for (int jj = w; jj < 64; jj += 8)   // cooperative V staging (once/block)
      V[jj * 65 + j] = z[((p * 64 + jj) * 64 + j) * 2 + 1];
    us[w][j] = z[((p * 64 + i) * 64 + j) * 2 + 0];
    __syncthreads();
    float s = 0.f;
    for (int kk = 0; kk < 64; kk++)
      s += us[w][kk] * V[j * 65 + kk];
    float pr = (i == j) ? 0.f : 1.f / (1.f + expf(-0.2f * s));
    probs[(p * 64 + i) * 64 + j] = pr;
  }
}

// sample graphs AND bucket tasks into the 4 chol tiers (wave-aggregated
// atomics: one atomicAdd per wave per tier).
__global__ void k_sample(double* ws) {
  const float* probs = (const float*)(ws + PROBS_OFF);
  const u32* keys = (const u32*)(ws + KEYS_OFF);
  u64* grow = (u64*)(ws + GROW_OFF);
  u64* gcol = (u64*)(ws + GCOL_OFF);
  u32* wl = (u32*)(ws + GF_OFF);
  int ps = blockIdx.x;
  int p = ps >> 4;
  int j = threadIdx.x;
  u32 k0 = keys[0], k1 = keys[1];
  u64 colmask = 0;
  for (int i = 0; i < 64; i++) {
    u32 lin = (u32)(ps * 4096 + i * 64 + j);
    u32 o0, o1; tf2x32(k0, k1, 0u, lin, o0, o1);
    u32 bits = o0 ^ o1;
    float f = __uint_as_float((bits >> 9) | 0x3f800000u) - 1.0f;
    bool bit = (f < probs[(p * 64 + i) * 64 + j]);
    u64 rm = __ballot(bit);
    if (j == 0) grow[ps * 64 + i] = rm;
    if (bit) colmask |= (1ull << i);
  }
  gcol[ps * 64 + j] = colmask;
  // tier bucketing: task (ps, col j), m = popc+1
  int m = (int)__popcll(colmask) + 1;
  int tier = (m <= 32) ? 0 : (m <= 36) ? 1 : (m <= 40) ? 2 : 3;
#pragma unroll
  for (int t = 0; t < 4; t++) {
    u64 b = __ballot(tier == t);
    if (tier == t) {
      int leader = (int)__builtin_ctzll(b);
      u32 off = (u32)__popcll(b & ((1ull << j) - 1ull));
      u32 base = 0;
      if (j == leader) base = atomicAdd(&wl[t], (u32)__popcll(b));
      base = (u32)__shfl((int)base, leader, 64);
      wl[WL_LIST0 + t * 32768 + base + off] = (u32)(ps * 64 + j);
    }
  }
}

__device__ __forceinline__ float rdlane(float x, int l) {
  return __uint_as_float(__builtin_amdgcn_readlane(__float_as_uint(x), (u32)l));
}

// DUAL-task tier: TWO independent full-wave LDL tasks per wave (va, vb).
// Near issue-floor for the readlane-broadcast scheme (rounds 4-9 all land
// at ~35% of the 2-instr/element floor; readlane->fmac chain ~5-6 eff
// cycles/element is the residual). Kept as-is.
template<int MMAX>
__device__ __forceinline__ void tier_body2(const float* Rf, const double* ctab,
                                           const u64* masks, double* nodescore,
                                           const u32* wl, int tier,
                                           u32 brel, u32 nb, int (*idx)[2][64]) {
  int w = threadIdx.x >> 6;
  int lane = threadIdx.x & 63;
  u32 cnt = wl[tier];
  const u32* list = wl + WL_LIST0 + tier * 32768;
  u32 npair = (cnt + 1) >> 1;
  for (u32 ti = brel * 4 + (u32)w; ti < npair; ti += nb * 4) {
    u32 iA = 2 * ti, iB = iA + 1;
    bool hasB = (iB < cnt);
    int taskA = (int)list[iA];
    int taskB = (int)list[hasB ? iB : iA];   // dup A on odd tail (idempotent)
    u64 maskA = masks[taskA];
    u64 maskB = masks[taskB];
    int PA = (int)__popcll(maskA), PB = (int)__popcll(maskB);
    idx[w][0][lane] = 0;                     // sanitize (dead slots -> row 0)
    idx[w][1][lane] = 0;
    __builtin_amdgcn_wave_barrier();
    {
      u64 belowA = maskA & ((1ull << lane) - 1ull);
      if ((maskA >> lane) & 1ull) idx[w][0][(int)__popcll(belowA)] = lane;
      if (lane == 0) idx[w][0][PA] = taskA & 63;
      u64 belowB = maskB & ((1ull << lane) - 1ull);
      if ((maskB >> lane) & 1ull) idx[w][1][(int)__popcll(belowB)] = lane;
      if (lane == 0) idx[w][1][PB] = taskB & 63;
    }
    __builtin_amdgcn_wave_barrier();
    int rowA = idx[w][0][lane];
    int rowB = idx[w][1][lane];
    float va[MMAX], vb[MMAX];
#pragma unroll
    for (int c = 0; c < MMAX; c++) {
      va[c] = Rf[idx[w][0][c] * 64 + rowA];  // A[lane][c] via R symmetry
      vb[c] = Rf[idx[w][1][c] * 64 + rowB];
    }
    float pivA = 1.0f, pivB = 1.0f;
#pragma unroll
    for (int k = 0; k < MMAX; k++) {
      float dkA = rdlane(va[k], k);
      float dkB = rdlane(vb[k], k);
      if (lane == k) { pivA = dkA; pivB = dkB; }
      float nsA = -va[k] * __builtin_amdgcn_rcpf(dkA);
      float nsB = -vb[k] * __builtin_amdgcn_rcpf(dkB);
#pragma unroll
      for (int b2 = k + 1; b2 < MMAX; b2++) {
        va[b2] += nsA * rdlane(va[k], b2);   // chain A
        vb[b2] += nsB * rdlane(vb[k], b2);   // chain B fills A's bubbles
      }
    }
    {
      int mA = PA + 1;
      float lastd = __shfl(pivA, PA, 64);
      float lv = (lane < mA) ? __logf(pivA) : 0.f;
      for (int off = 32; off > 0; off >>= 1) lv += __shfl_down(lv, off, 64);
      if (lane == 0) {
        double l = (double)PA;
        nodescore[taskA] = ctab[PA]
                         - 0.5 * (2050.0 + l) * (double)__logf(lastd)
                         - 0.5 * (double)lv;
      }
    }
    if (hasB) {
      int mB = PB + 1;
      float lastd = __shfl(pivB, PB, 64);
      float lv = (lane < mB) ? __logf(pivB) : 0.f;
      for (int off = 32; off > 0; off >>= 1) lv += __shfl_down(lv, off, 64);
      if (lane == 0) {
        double l = (double)PB;
        nodescore[taskB] = ctab[PB]
                         - 0.5 * (2050.0 + l) * (double)__logf(lastd)
                         - 0.5 * (double)lv;
      }
    }
    __builtin_amdgcn_wave_barrier();         // order idx reuse across iters
  }
}

// Single-task tier (m 37..40): proven readlane core, kept single so its
// 40-reg array doesn't stack with the dual bodies' VGPR budget.
template<int MMAX>
__device__ __forceinline__ void tier_body(const float* Rf, const double* ctab,
                                          const u64* masks, double* nodescore,
                                          const u32* wl, int tier,
                                          u32 brel, u32 nb, int (*idx)[64]) {
  int w = threadIdx.x >> 6;
  int lane = threadIdx.x & 63;
  u32 cnt = wl[tier];
  const u32* list = wl + WL_LIST0 + tier * 32768;
  for (u32 ti = brel * 4 + (u32)w; ti < cnt; ti += nb * 4) {
    int task = (int)list[ti];
    int j = task & 63;
    u64 mask = masks[task];
    int P = (int)__popcll(mask);
    int m = P + 1;
    idx[w][lane] = 0;                       // sanitize (dead slots -> row 0)
    __builtin_amdgcn_wave_barrier();
    u64 below = mask & ((1ull << lane) - 1ull);
    if ((mask >> lane) & 1ull) idx[w][(int)__popcll(below)] = lane;
    if (lane == 0) idx[w][P] = j;
    __builtin_amdgcn_wave_barrier();
    int myrow = idx[w][lane];               // my node id (0 for dead lanes)
    float v[MMAX];
#pragma unroll
    for (int c = 0; c < MMAX; c++)
      v[c] = Rf[idx[w][c] * 64 + myrow];    // A[lane][c] via symmetry
    float mypiv = 1.0f;
#pragma unroll
    for (int k = 0; k < MMAX; k++) {
      if (k < m) {                          // uniform guard (keeps full unroll)
        float dk = rdlane(v[k], k);
        if (lane == k) mypiv = dk;
        float ns = -v[k] * __builtin_amdgcn_rcpf(dk);
#pragma unroll
        for (int b = k + 1; b < MMAX; b++)
          v[b] += ns * rdlane(v[k], b);     // garbage slots never read back
      }
    }
    float lastd = __shfl(mypiv, P, 64);     // final pivot d_{m-1} (lane P)
    float lv = (lane < m) ? __logf(mypiv) : 0.f;
    for (int off = 32; off > 0; off >>= 1) lv += __shfl_down(lv, off, 64);
    if (lane == 0) {
      double l = (double)P;
      nodescore[task] = ctab[P]
                      - 0.5 * (2050.0 + l) * (double)__logf(lastd)
                      - 0.5 * (double)lv;
    }
    __builtin_amdgcn_wave_barrier();        // order idx reuse across iterations
  }
}

#define WB() __builtin_amdgcn_wave_barrier()

// Heavy path (m>40, ~3%): wave 0 of the block only; full hybrid path with
// LDS triangle.
__device__ void heavy_body(const float* Rf, const double* ctab,
                           const u64* masks, double* nodescore,
                           const u32* wl, u32 brel, u32 nb,
                           float* T, int* idx) {
  if (threadIdx.x >= 64) return;
  int lane = threadIdx.x;
  u32 cnt = wl[3];
  const u32* list = wl + WL_LIST0 + 3 * 32768;
  for (u32 ii = brel; ii < cnt; ii += nb) {
    WB();
    int task = (int)list[ii];
    int j = task & 63;
    u64 mask = masks[task];
    int P = (int)__popcll(mask);
    int m = P + 1;
    u64 below = mask & ((1ull << lane) - 1ull);
    if ((mask >> lane) & 1ull) idx[(int)__popcll(below)] = lane;
    if (lane == 0) idx[P] = j;
    WB();
    int trLane = (lane * (lane + 1)) >> 1;
    if (lane < m) {
      int cidx = idx[lane];
      int tr = 0;
      for (int r = 0; r < m; r++) {
        if (lane <= r) T[tr + lane] = Rf[idx[r] * 64 + cidx];
        tr += r + 1;
      }
    }
    WB();
    float mypiv = 1.0f, lastd = 1.0f;
    float v[40];
#pragma unroll
    for (int c = 0; c < 40; c++)
      v[c] = T[trLane + c];
#pragma unroll
    for (int k = 0; k < 40; k++) {
      if (k < m) {
        float dk = rdlane(v[k], k);
        if (lane == k) mypiv = dk;
        lastd = dk;
        float ns = -v[k] * __builtin_amdgcn_rcpf(dk);
#pragma unroll
        for (int b = k + 1; b < 40; b++)
          v[b] += ns * rdlane(v[k], b);
      }
    }
    if (m > 40) {
      for (int b = 40; b < m; b++) {
        float acc = 0.f;
#pragma unroll
        for (int k = 0; k < 40; k++) {
          float dk = rdlane(v[k], k);
          float abk = rdlane(v[k], b);
          acc += v[k] * abk * __builtin_amdgcn_rcpf(dk);
        }
        if (lane >= b) T[trLane + b] -= acc;
      }
      WB();
      for (int k = 40; k < m; k++) {
        float dk = T[((k * (k + 1)) >> 1) + k];
        if (lane == k) mypiv = dk;
        lastd = dk;
        float sk = T[trLane + k] * __builtin_amdgcn_rcpf(dk);
        for (int b = k + 1; b < m; b++) {
          float abk = T[((b * (b + 1)) >> 1) + k];
          if (lane >= b) T[trLane + b] -= sk * abk;
        }
        WB();
      }
    }
    double vv = (lane < m) ? log((double)mypiv) : 0.0;
    for (int off = 32; off > 0; off >>= 1) vv += __shfl_down(vv, off, 64);
    if (lane == 0) {
      double logB = vv;
      double logA = logB - log((double)lastd);
      double l = (double)P;
      nodescore[task] = ctab[P]
                      + 0.5 * (2050.0 + l) * logA
                      - 0.5 * (2051.0 + l) * logB;
    }
  }
}

// ONE launch for all 32768 sampled-graph cholesky tasks. Heavy first, then
// tiers by descending per-wave cost. No min-waves launch_bounds cap
// (round-1 lesson: caps + big v[] => scratch spill).
__global__ __launch_bounds__(256) void k_chol_all(const float* Rf, const double* ctab,
                                                  const u64* masks, double* nodescore,
                                                  const u32* wl) {
  __shared__ int idx2[4][2][64];
  __shared__ int idx4[4][64];
  __shared__ float T[2080];
  __shared__ int idxh[64];
  u32 b = blockIdx.x;
  if (b < E_H)      heavy_body(Rf, ctab, masks, nodescore, wl, b, HBLK, T, idxh);
  else if (b < E_1) tier_body2<36>(Rf, ctab, masks, nodescore, wl, 1, b - E_H, TB1, idx2);
  else if (b < E_0) tier_body2<32>(Rf, ctab, masks, nodescore, wl, 0, b - E_1, TB0, idx2);
  else              tier_body<40>(Rf, ctab, masks, nodescore, wl, 2, b - E_0, TB2, idx4);
}

// Merged hybrid f32 LDL Cholesky (transpose variant for the 2048 hard-graph
// tasks). UNCHANGED and kept f64: its scores feed the log_p OUTPUT, where
// absmax is already at 1 f32 ulp of |logp|~4000.
template<bool TRANSPOSE>
__global__ __launch_bounds__(64) void k_chol(const float* Rf, const double* ctab,
                                             const u64* masks, double* nodescore) {
  __shared__ float T[2080];
  __shared__ int idx[64];
  int task = blockIdx.x;
  int j = task & 63;
  int lane = threadIdx.x;
  u64 mask;
  if (TRANSPOSE) {
    int p = task >> 6;
    u64 rm = masks[p * 64 + lane];       // row mask of row `lane`
    mask = __ballot((rm >> j) & 1ull);   // column j mask
  } else {
    mask = masks[task];
  }
  int P = (int)__popcll(mask);
  int m = P + 1;
  u64 below = mask & ((1ull << lane) - 1ull);
  if ((mask >> lane) & 1ull) idx[(int)__popcll(below)] = lane;
  if (lane == 0) idx[P] = j;
  __syncthreads();
  int trLane = (lane * (lane + 1)) >> 1;
  if (lane < m) {
    int cidx = idx[lane];
    int tr = 0;
    for (int r = 0; r < m; r++) {
      if (lane <= r) T[tr + lane] = Rf[idx[r] * 64 + cidx];
      tr += r + 1;
    }
  }
  __syncthreads();
  float mypiv = 1.0f, lastd = 1.0f;
  float v[40];
#pragma unroll
  for (int c = 0; c < 40; c++)
    v[c] = T[trLane + c];                // in-bounds garbage for c>lane
#pragma unroll
  for (int k = 0; k < 40; k++) {
    if (k < m) {                         // uniform guard (keeps full unroll)
      float dk = rdlane(v[k], k);
      if (lane == k) mypiv = dk;
      lastd = dk;
      float ns = -v[k] * __builtin_amdgcn_rcpf(dk);
#pragma unroll
      for (int b = k + 1; b < 40; b++)
        v[b] += ns * rdlane(v[k], b);    // garbage slots harmless
    }
  }
  if (m > 40) {                          // heavy tasks only (block-uniform)
    for (int b = 40; b < m; b++) {
      float acc = 0.f;
#pragma unroll
      for (int k = 0; k < 40; k++) {
        float dk = rdlane(v[k], k);                  // final pivot k
        float abk = rdlane(v[k], b);                 // final A[b][k]
        acc += v[k] * abk * __builtin_amdgcn_rcpf(dk);
      }
      if (lane >= b) T[trLane + b] -= acc;           // own-row, no conflict
    }
    __syncthreads();
    for (int k = 40; k < m; k++) {
      float dk = T[((k * (k + 1)) >> 1) + k];        // broadcast
      if (lane == k) mypiv = dk;
      lastd = dk;
      float sk = T[trLane + k] * __builtin_amdgcn_rcpf(dk);
      for (int b = k + 1; b < m; b++) {
        float abk = T[((b * (b + 1)) >> 1) + k];     // broadcast
        if (lane >= b) T[trLane + b] -= sk * abk;
      }
      __syncthreads();
    }
  }
  double vv = (lane < m) ? log((double)mypiv) : 0.0;
  for (int off = 32; off > 0; off >>= 1) vv += __shfl_down(vv, off, 64);
  if (lane == 0) {
    double logB = vv;
    double logA = logB - log((double)lastd);
    double l = (double)P;
    nodescore[task] = ctab[P]
                    + 0.5 * (2050.0 + l) * logA
                    - 0.5 * (2051.0 + l) * logB;
  }
}

// fused A-construction + grad dot + kmat; logpw (softmax weights) computed
// INLINE per block (identical op order to the old k_logpw -> bitwise-same w;
// kills one tiny latency-bound launch + gap).
// blocks 0..2047: grad_u; 2048..4095: grad_v; 4096..5119: Kmat (z0-only).
__global__ void k_grad(double* ws, const float* z) {
  const float* probs = (const float*)(ws + PROBS_OFF);
  const u64* grow = (const u64*)(ws + GROW_OFF);
  const u64* gcol = (const u64*)(ws + GCOL_OFF);
  const double* ns = ws + NS_OFF;
  float* gf = (float*)(ws + GF_OFF);
  const float LOGIT = -2.6903717578966254f;  // log(4/63)-log1p(-4/63)
  int bb = blockIdx.x;
  int k = threadIdx.x;
  __shared__ float acc[64];
  __shared__ double part[64];
  __shared__ double wsh[16];
  if (bb < 4096) {
    int p = (bb < 2048) ? (bb >> 6) : ((bb - 2048) >> 6);
    // ---- inline softmax weights (replaces k_logpw; same arithmetic) ----
    {
      int s = k & 15, c = k >> 4;          // 4 chunks x 16 samples
      double a2 = 0.0;
      for (int j2 = c * 16; j2 < (c + 1) * 16; j2++)
        a2 += ns[(p * 16 + s) * 64 + j2];
      part[k] = a2;
      __syncthreads();
      if (k < 16) part[k] = part[k] + part[k + 16] + part[k + 32] + part[k + 48];
      __syncthreads();
      if (k == 0) {
        double m2 = part[0];
        for (int s2 = 1; s2 < 16; s2++) m2 = fmax(m2, part[s2]);
        double e[16], sum = 0.0;
        for (int s2 = 0; s2 < 16; s2++) { e[s2] = exp(part[s2] - m2); sum += e[s2]; }
        for (int s2 = 0; s2 < 16; s2++) wsh[s2] = e[s2] / sum;
      }
      __syncthreads();
    }
    if (bb < 2048) {
      int i = bb & 63;
      float gb = 0.f, wsum = 0.f;
      for (int s = 0; s < 16; s++) {
        float wv = (float)wsh[s];
        wsum += wv;
        gb += wv * (float)((grow[(p * 16 + s) * 64 + i] >> k) & 1ull);
      }
      float pr = probs[(p * 64 + i) * 64 + k];   // coalesced
      float od = (i == k) ? 0.f : 1.f;
      acc[k] = (0.2f * (gb - pr * wsum) + 0.2f * pr * (1.f - pr) * LOGIT) * od;
      __syncthreads();
      float s = 0.f;
      for (int j = 0; j < 64; j++)
        s += acc[j] * z[((p * 64 + j) * 64 + k) * 2 + 1];
      s -= 64.f * z[((p * 64 + i) * 64 + k) * 2 + 0];
      gf[p * 8192 + (i * 64 + k) * 2 + 0] = s;
    } else {
      int j = (bb - 2048) & 63;
      float gb = 0.f, wsum = 0.f;
      for (int s = 0; s < 16; s++) {
        float wv = (float)wsh[s];
        wsum += wv;
        gb += wv * (float)((gcol[(p * 16 + s) * 64 + j] >> k) & 1ull);
      }
      float pr = probs[(p * 64 + k) * 64 + j];   // one 64-lane gather
      float od = (k == j) ? 0.f : 1.f;
      acc[k] = (0.2f * (gb - pr * wsum) + 0.2f * pr * (1.f - pr) * LOGIT) * od;
      __syncthreads();
      float s = 0.f;
      for (int i = 0; i < 64; i++)
        s += acc[i] * z[((p * 64 + i) * 64 + k) * 2 + 0];
      s -= 64.f * z[((p * 64 + j) * 64 + k) * 2 + 1];
      gf[p * 8192 + (j * 64 + k) * 2 + 1] = s;
    }
  } else {
    float* Km = (float*)(ws + KM_OFF);
    int b = bb - 4096;
    int a = b >> 5, b2 = b & 31;
    float accf = 0.f;
    for (int d0 = k; d0 < 8192; d0 += 64) {
      float diff = z[a * 8192 + d0] - z[b2 * 8192 + d0];
      accf += diff * diff;
    }
    for (int off = 32; off > 0; off >>= 1) accf += __shfl_down(accf, off, 64);
    if (k == 0) Km[a * 32 + b2] = expf(-accf / 5.0f);
  }
}

__global__ void k_znew(const float* z, double* ws, float* out) {
  const float* Km = (const float*)(ws + KM_OFF);
  const float* gf = (const float*)(ws + GF_OFF);
  float* zn = (float*)(ws + ZN_OFF);
  int gid = blockIdx.x * 64 + threadIdx.x;
  int p = gid >> 13, t = gid & 8191;
  float zp = z[p * 8192 + t];
  float accg = 0.f, accz = 0.f, ks = 0.f;
  for (int b = 0; b < 32; b++) {
    float kv = Km[p * 32 + b];
    accg += kv * gf[b * 8192 + t];
    accz += kv * z[b * 8192 + t];
    ks += kv;
  }
  float rep = -0.4f * (accz - zp * ks);
  float v = zp + 0.005f * ((accg + rep) / 32.f);
  zn[p * 8192 + t] = v;
  out[O_ZN + p * 8192 + t] = v;
}

__global__ __launch_bounds__(64) void k_s2col(double* ws, float* out) {
  const float* zn = (const float*)(ws + ZN_OFF);
  u64* grow2 = (u64*)(ws + NS_OFF);
  int b = blockIdx.x; int p = b >> 6, i = b & 63;
  int j = threadIdx.x;
  __shared__ float V[64 * 65];
  __shared__ float us[64];
  int k = j;
  us[k] = zn[p * 8192 + (i * 64 + k) * 2 + 0];
  for (int jj = 0; jj < 64; jj++)
    V[jj * 65 + k] = zn[p * 8192 + (jj * 64 + k) * 2 + 1];
  __syncthreads();
  float s = 0.f;
  for (int kk = 0; kk < 64; kk++)
    s += us[kk] * V[j * 65 + kk];
  bool bit = (i != j) && (s > 0.0f);
  out[O_GH + (p * 64 + i) * 64 + j] = bit ? 1.0f : 0.0f;
  u64 m = __ballot(bit);
  if (j == 0) grow2[p * 64 + i] = m;    // row masks; k_chol<true> transposes
}

// encoder/decoder MLP; also writes log_p (fused reduction).
__global__ __launch_bounds__(256) void k_mlp(double* ws, float* out, const double* ns2,
    const float* ew0, const float* eb0, const float* ew1, const float* eb1,
    const float* ew2, const float* eb2,
    const float* mw0, const float* mb0, const float* mw1, const float* mb1,
    const float* lw0, const float* lb0, const float* lw1, const float* lb1,
    const float* dw0, const float* db0, const float* dw1, const float* db1,
    const float* dw2, const float* db2) {
  int p = blockIdx.x, t = threadIdx.x;
  int w = t >> 6, lane = t & 63;
  const u64* grow2 = (const u64*)(ws + NS_OFF);
  const u32* keys = (const u32*)(ws + KEYS_OFF);
  __shared__ float pt[4][64];
  __shared__ float e0p[4][20];
  __shared__ float h0[20], h1[64], h2[64], hm[64], hl[64];
  __shared__ float qmu[64], qlv[64], qz[64], h3[10], h4[128];

  // ---- logp reduction (wave 0) ----
  if (w == 0) {
    double vv = ns2[p * 64 + lane];
    for (int off = 32; off > 0; off >>= 1) vv += __shfl_down(vv, off, 64);
    if (lane == 0) out[O_LOGP + p] = (float)vv;
  }

  // ---- e0: h0[20] = relu(eb0 + sum over set bits of ew0 rows) ----
  {
    int i = t >> 2;
    int jb = (t & 3) * 16;
    u32 m16 = (u32)((grow2[p * 64 + i] >> jb) & 0xFFFFull);
    float acc[20];
#pragma unroll
    for (int o = 0; o < 20; o++) acc[o] = 0.f;
    const float4* wb = (const float4*)(ew0 + (size_t)(t * 16) * 20);
#pragma unroll
    for (int q = 0; q < 16; q++) {
      float mq = (float)((m16 >> q) & 1u);
      float4 r0 = wb[q * 5 + 0], r1 = wb[q * 5 + 1], r2 = wb[q * 5 + 2];
      float4 r3 = wb[q * 5 + 3], r4 = wb[q * 5 + 4];
      acc[0]  += mq * r0.x; acc[1]  += mq * r0.y; acc[2]  += mq * r0.z; acc[3]  += mq * r0.w;
      acc[4]  += mq * r1.x; acc[5]  += mq * r1.y; acc[6]  += mq * r1.z; acc[7]  += mq * r1.w;
      acc[8]  += mq * r2.x; acc[9]  += mq * r2.y; acc[10] += mq * r2.z; acc[11] += mq * r2.w;
      acc[12] += mq * r3.x; acc[13] += mq * r3.y; acc[14] += mq * r3.z; acc[15] += mq * r3.w;
      acc[16] += mq * r4.x; acc[17] += mq * r4.y; acc[18] += mq * r4.z; acc[19] += mq * r4.w;
    }
#pragma unroll
    for (int o = 0; o < 20; o++) {
      float v = acc[o];
      for (int off = 32; off > 0; off >>= 1) v += __shfl_down(v, off, 64);
      if (lane == 0) e0p[w][o] = v;
    }
  }
  __syncthreads();
  if (t < 20)
    h0[t] = fmaxf(eb0[t] + e0p[0][t] + e0p[1][t] + e0p[2][t] + e0p[3][t], 0.f);
  __syncthreads();

  // ---- h1[64] = relu(eb1 + h0 @ ew1), fan-in 20 split 5/wave ----
  {
    float s = 0.f;
#pragma unroll
    for (int q = 0; q < 5; q++) s += h0[w * 5 + q] * ew1[(w * 5 + q) * 64 + lane];
    pt[w][lane] = s;
  }
  __syncthreads();
  if (w == 0)
    h1[lane] = fmaxf(eb1[lane] + pt[0][lane] + pt[1][lane] + pt[2][lane] + pt[3][lane], 0.f);
  __syncthreads();

  // ---- h2[64] = relu(eb2 + h1 @ ew2), fan-in 64 split 16/wave ----
  {
    float s = 0.f;
#pragma unroll
    for (int q = 0; q < 16; q++) s += h1[w * 16 + q] * ew2[(w * 16 + q) * 64 + lane];
    pt[w][lane] = s;
  }
  __syncthreads();
  if (w == 0)
    h2[lane] = fmaxf(eb2[lane] + pt[0][lane] + pt[1][lane] + pt[2][lane] + pt[3][lane], 0.f);
  __syncthreads();

  // ---- hm/hl in parallel: waves 0,1 -> hm; waves 2,3 -> hl ----
  {
    const float* W = (w < 2) ? mw0 : lw0;
    int qb = (w & 1) * 32;
    float s = 0.f;
#pragma unroll
    for (int q = 0; q < 32; q++) s += h2[qb + q] * W[(qb + q) * 64 + lane];
    pt[w][lane] = s;
  }
  __syncthreads();
  if (w == 0) hm[lane] = fmaxf(mb0[lane] + pt[0][lane] + pt[1][lane], 0.f);
  if (w == 1) hl[lane] = fmaxf(lb0[lane] + pt[2][lane] + pt[3][lane], 0.f);
  __syncthreads();

  // ---- qmu/qlv in parallel (no relu) ----
  {
    const float* W = (w < 2) ? mw1 : lw1;
    const float* src = (w < 2) ? hm : hl;
    int qb = (w & 1) * 32;
    float s = 0.f;
#pragma unroll
    for (int q = 0; q < 32; q++) s += src[qb + q] * W[(qb + q) * 64 + lane];
    pt[w][lane] = s;
  }
  __syncthreads();
  if (w == 0) qmu[lane] = mb1[lane] + pt[0][lane] + pt[1][lane];
  if (w == 1) qlv[lane] = lb1[lane] + pt[2][lane] + pt[3][lane];
  __syncthreads();

  // ---- reparameterize (wave 0) + output qz/qmu/qlv ----
  if (w == 0) {
    u32 o0, o1;
    tf2x32(keys[2], keys[3], 0u, (u32)(p * 64 + lane), o0, o1);
    u32 bits = o0 ^ o1;
    float f = __uint_as_float((bits >> 9) | 0x3f800000u) - 1.0f;
    float LOF = __uint_as_float(0xBF7FFFFFu);
    float uu = fmaxf(LOF, f * 2.0f + LOF);
    float eps = (float)(1.4142135623730951 * d_erfinv((double)uu));
    float qzv = qmu[lane] + eps * expf(0.5f * qlv[lane]);
    qz[lane] = qzv;
    out[O_QZ  + p * 64 + lane] = qzv;
    out[O_QMU + p * 64 + lane] = qmu[lane];
    out[O_QLV + p * 64 + lane] = qlv[lane];
  }
  __syncthreads();

  // ---- d0: h3[10] = relu(db0 + qz @ dw0), fan-in 64 split 16/wave ----
  {
    float s = 0.f;
    if (lane < 10) {
#pragma unroll
      for (int q = 0; q < 16; q++) s += qz[w * 16 + q] * dw0[(w * 16 + q) * 10 + lane];
    }
    pt[w][lane] = s;
  }
  __syncthreads();
  if (w == 0 && lane < 10)
    h3[lane] = fmaxf(db0[lane] + pt[0][lane] + pt[1][lane] + pt[2][lane] + pt[3][lane], 0.f);
  __syncthreads();

  // ---- d1: h4[128] = relu(db1 + h3 @ dw1) ----
  {
    int o = (w >> 1) * 64 + lane;
    int qb = (w & 1) * 5;
    float s = 0.f;
#pragma unroll
    for (int q = 0; q < 5; q++) s += h3[qb + q] * dw1[(qb + q) * 128 + o];
    pt[w][lane] = s;
  }
  __syncthreads();
  if (w == 0) h4[lane]      = fmaxf(db1[lane]      + pt[0][lane] + pt[1][lane], 0.f);
  if (w == 1) h4[64 + lane] = fmaxf(db1[64 + lane] + pt[2][lane] + pt[3][lane], 0.f);
  __syncthreads();

  // ---- d2: recons[128] = db2 + h4 @ dw2 ----
  {
    int o = (w >> 1) * 64 + lane;
    int qb = (w & 1) * 64;
    float s = 0.f;
#pragma unroll
    for (int q = 0; q < 64; q++) s += h4[qb + q] * dw2[(qb + q) * 128 + o];
    pt[w][lane] = s;
  }
  __syncthreads();
  if (w == 0) out[O_REC + p * 128 + lane]      = db2[lane]      + pt[0][lane] + pt[1][lane];
  if (w == 1) out[O_REC + p * 128 + 64 + lane] = db2[64 + lane] + pt[2][lane] + pt[3][lane];
}

extern "C" void kernel_launch(void* const* d_in, const int* in_sizes, int n_in,
                              void* d_out, int out_size, void* d_ws, size_t ws_size,
                              hipStream_t stream) {
  (void)in_sizes; (void)n_in; (void)out_size; (void)ws_size;
  const float* z_gt = (const float*)d_in[0];
  const float* z0   = (const float*)d_in[1];
  const float* ew0 = (const float*)d_in[2];  const float* eb0 = (const float*)d_in[3];
  const float* ew1 = (const float*)d_in[4];  const float* eb1 = (const float*)d_in[5];
  const float* ew2 = (const float*)d_in[6];  const float* eb2 = (const float*)d_in[7];
  const float* mw0 = (const float*)d_in[8];  const float* mb0 = (const float*)d_in[9];
  const float* mw1 = (const float*)d_in[10]; const float* mb1 = (const float*)d_in[11];
  const float* lw0 = (const float*)d_in[12]; const float* lb0 = (const float*)d_in[13];
  const float* lw1 = (const float*)d_in[14]; const float* lb1 = (const float*)d_in[15];
  const float* dw0 = (const float*)d_in[16]; const float* db0 = (const float*)d_in[17];
  const float* dw1 = (const float*)d_in[18]; const float* db1 = (const float*)d_in[19];
  const float* dw2 = (const float*)d_in[20]; const float* db2 = (const float*)d_in[21];
  const int* seed = (const int*)d_in[22];
  double* ws = (double*)d_ws;
  float* out = (float*)d_out;
  const float* Rf = (const float*)(ws + R_OFF);
  const u32* wl = (const u32*)(ws + GF_OFF);  // tier worklists (chol phase only;
                                              // region is reused by k_grad later)

  k_init<<<320, 512, 0, stream>>>(z_gt, z0, ws, seed);   // R + setup + probs
  k_sample<<<C_P * C_S, 64, 0, stream>>>(ws);
  k_chol_all<<<NBLK_ALL, 256, 0, stream>>>(Rf, ws + CTAB_OFF,
      (const u64*)(ws + GCOL_OFF), ws + NS_OFF, wl);
  k_grad<<<2 * C_P * C_D + C_P * C_P, 64, 0, stream>>>(ws, z0);  // logpw fused
  k_znew<<<(C_P * 8192) / 64, 64, 0, stream>>>(z0, ws, out);
  k_s2col<<<C_P * C_D, 64, 0, stream>>>(ws, out);
  k_chol<true><<<C_P * C_D, 64, 0, stream>>>(Rf, ws + CTAB_OFF,
      (const u64*)(ws + NS_OFF), ws + NS2_OFF);
  k_mlp<<<C_P, 256, 0, stream>>>(ws, out, ws + NS2_OFF,
      ew0, eb0, ew1, eb1, ew2, eb2,
      mw0, mb0, mw1, mb1, lw0, lb0, lw1, lb1,
      dw0, db0, dw1, db1, dw2, db2);
}